// Round 6
// baseline (518.225 us; speedup 1.0000x reference)
//
#include <hip/hip_runtime.h>

#define DD 8
#define HH 256
#define CH 8192          // edges per chunk in coarse/partition kernels
#define PAYBITS 17       // N <= 131072
#define PAYMASK 0x1FFFF

// ============================ CSR construction ==============================
// Bucketed counting sort: coarse bucket = node >> 9 (512 ids/bucket),
// fine bin = node & 511. No global atomics on node-sized arrays.

__global__ void k_coarse(const int* __restrict__ src, const int* __restrict__ dst,
                         int* __restrict__ gHistIn, int* __restrict__ gHistOut,
                         int NB, int E) {
    __shared__ int hIn[256], hOut[256];
    if (threadIdx.x < 256) { hIn[threadIdx.x] = 0; hOut[threadIdx.x] = 0; }
    __syncthreads();
    int lo = blockIdx.x * CH;
    int hi = min(lo + CH, E);
    for (int i = lo + threadIdx.x; i < hi; i += blockDim.x) {
        atomicAdd(&hIn[dst[i] >> 9], 1);
        atomicAdd(&hOut[src[i] >> 9], 1);
    }
    __syncthreads();
    if (threadIdx.x < NB) {
        int ci = hIn[threadIdx.x], co = hOut[threadIdx.x];
        if (ci) atomicAdd(&gHistIn[threadIdx.x], ci);
        if (co) atomicAdd(&gHistOut[threadIdx.x], co);
    }
}

__global__ void k_cscan(const int* __restrict__ gHistIn, const int* __restrict__ gHistOut,
                        int* __restrict__ cStartIn, int* __restrict__ cStartOut,
                        int* __restrict__ cCurIn, int* __restrict__ cCurOut,
                        int NB, int E) {
    __shared__ int s[256];
#pragma unroll
    for (int dir = 0; dir < 2; dir++) {
        const int* gh = dir ? gHistOut : gHistIn;
        int* cs = dir ? cStartOut : cStartIn;
        int* cc = dir ? cCurOut : cCurIn;
        int v = (threadIdx.x < NB) ? gh[threadIdx.x] : 0;
        s[threadIdx.x] = v;
        __syncthreads();
        for (int off = 1; off < 256; off <<= 1) {
            int t = (threadIdx.x >= off) ? s[threadIdx.x - off] : 0;
            __syncthreads();
            s[threadIdx.x] += t;
            __syncthreads();
        }
        if (threadIdx.x < NB) {
            int ex = s[threadIdx.x] - v;
            cs[threadIdx.x] = ex;
            cc[threadIdx.x] = ex;
        }
        if (threadIdx.x == 0) cs[NB] = E;
        __syncthreads();
    }
}

__global__ void k_partition(const int* __restrict__ key, const int* __restrict__ pay,
                            int* __restrict__ cCur, int* __restrict__ P,
                            int NB, int E) {
    __shared__ int h[256];
    if (threadIdx.x < 256) h[threadIdx.x] = 0;
    __syncthreads();
    int lo = blockIdx.x * CH;
    int hi = min(lo + CH, E);
    for (int i = lo + threadIdx.x; i < hi; i += blockDim.x)
        atomicAdd(&h[key[i] >> 9], 1);
    __syncthreads();
    if (threadIdx.x < NB) {
        int c = h[threadIdx.x];
        h[threadIdx.x] = c ? atomicAdd(&cCur[threadIdx.x], c) : 0;
    }
    __syncthreads();
    for (int i = lo + threadIdx.x; i < hi; i += blockDim.x) {
        int k = key[i];
        int pos = atomicAdd(&h[k >> 9], 1);
        P[pos] = ((k & 511) << PAYBITS) | pay[i];
    }
}

__launch_bounds__(512)
__global__ void k_fine(const int* __restrict__ cStart, const int* __restrict__ P,
                       int* __restrict__ start, int* __restrict__ csr, int N) {
    __shared__ int cnt[512], scn[512];
    int b = blockIdx.x;
    int lo = cStart[b], hi = cStart[b + 1];
    cnt[threadIdx.x] = 0;
    __syncthreads();
    for (int i = lo + threadIdx.x; i < hi; i += 512)
        atomicAdd(&cnt[P[i] >> PAYBITS], 1);
    __syncthreads();
    int own = cnt[threadIdx.x];
    scn[threadIdx.x] = own;
    __syncthreads();
    for (int off = 1; off < 512; off <<= 1) {
        int t = (threadIdx.x >= off) ? scn[threadIdx.x - off] : 0;
        __syncthreads();
        scn[threadIdx.x] += t;
        __syncthreads();
    }
    int base = lo + scn[threadIdx.x] - own;
    int node = (b << 9) + threadIdx.x;
    if (node < N) start[node] = base;
    cnt[threadIdx.x] = base;   // reuse as cursor
    __syncthreads();
    for (int i = lo + threadIdx.x; i < hi; i += 512) {
        int p = P[i];
        int pos = atomicAdd(&cnt[p >> PAYBITS], 1);
        csr[pos] = p & PAYMASK;
    }
}

// ====== weight interleave: W12[j*16+d] = W1[d][j], W12[j*16+8+d] = W2[j][d] =
__global__ void k_wt(const float* __restrict__ W1, const float* __restrict__ W2,
                     float* __restrict__ W12) {
    int i = blockIdx.x * blockDim.x + threadIdx.x;   // 2048 threads
    if (i < HH * DD) {
        int j = i >> 3, d = i & 7;
        W12[j * 16 + d]     = W1[d * HH + j];
        W12[j * 16 + 8 + d] = W2[j * DD + d];
    }
}

// ===================== per-node prep (norms, masses, dHdP) ==================
// hmd layout: hmd[v*16 + 2d] = h_d (filled by k_h_agg), hmd[v*16+2d+1] = m_d.
__global__ void k_prep(const float* __restrict__ q, const float* __restrict__ p,
                       const float* __restrict__ M,
                       int* __restrict__ start_in, int* __restrict__ start_out,
                       float* __restrict__ a, float* __restrict__ b,
                       float* __restrict__ hmd, float* __restrict__ qn,
                       float* __restrict__ out, int N, int E) {
    int v = blockIdx.x * blockDim.x + threadIdx.x;
    if (blockIdx.x == 0 && threadIdx.x == 0) { start_in[N] = E; start_out[N] = E; }
    if (v >= N) return;
    int ei1 = (v + 1 < N) ? start_in[v + 1]  : E;
    int eo1 = (v + 1 < N) ? start_out[v + 1] : E;
    float din  = (float)(ei1 - start_in[v]);
    float dout = (float)(eo1 - start_out[v]);
    float av = 1.0f / sqrtf(dout > 0.f ? dout : 1.f);   // norm_src
    float bv = 1.0f / sqrtf(din  > 0.f ? din  : 1.f);   // norm_dst
    a[v] = av; b[v] = bv;
#pragma unroll
    for (int d = 0; d < DD; d++) {
        float m = M[(size_t)v * DD * DD + d * (DD + 1)];
        hmd[(size_t)v * 16 + 2 * d + 1] = m;
        qn[(size_t)v * DD + d] = av * q[(size_t)v * DD + d];
        out[(size_t)v * 2 * DD + DD + d] = p[(size_t)v * DD + d] / m;  // dHdP
    }
}

// ============ fused gather + MLP forward: 8 threads per node ================
// Lane l gathers agg component l, shfl-broadcast -> z[8]; then lane l handles
// hidden units j=8c+l, unroll-2 with split fma chains; butterfly reduce y.
__launch_bounds__(256)
__global__ void k_mlp_fwd(const int* __restrict__ start, const int* __restrict__ csr,
                          const float* __restrict__ qn, const float* __restrict__ a,
                          const float* __restrict__ b,
                          const float* __restrict__ W12, const float* __restrict__ b1,
                          float* __restrict__ z1, float* __restrict__ ya, int N) {
    int t = blockIdx.x * blockDim.x + threadIdx.x;
    int v = t >> 3, l = t & 7;
    if (v >= N) return;
    // gather component l over in-CSR
    int e0 = start[v], e1 = start[v + 1];
    float s = 0.f;
    int e = e0;
    for (; e + 3 < e1; e += 4) {
        int u0 = csr[e], u1 = csr[e + 1], u2 = csr[e + 2], u3 = csr[e + 3];
        float x0 = qn[(size_t)u0 * DD + l], x1 = qn[(size_t)u1 * DD + l];
        float x2 = qn[(size_t)u2 * DD + l], x3 = qn[(size_t)u3 * DD + l];
        s += (x0 + x1) + (x2 + x3);
    }
    for (; e < e1; e++) s += qn[(size_t)csr[e] * DD + l];
    float zl = b[v] * s;
    z1[(size_t)v * DD + l] = zl;
    float z[DD];
#pragma unroll
    for (int k = 0; k < DD; k++) z[k] = __shfl(zl, k, 8);

    float acc[DD] = {0.f, 0.f, 0.f, 0.f, 0.f, 0.f, 0.f, 0.f};
    for (int c = 0; c < HH / DD; c += 2) {
        int j0 = (c << 3) | l, j1 = j0 + 8;
        const float4* w0 = (const float4*)(W12 + (size_t)j0 * 16);
        const float4* w1 = (const float4*)(W12 + (size_t)j1 * 16);
        float4 wa0 = w0[0], wb0 = w0[1], va0 = w0[2], vb0 = w0[3];
        float4 wa1 = w1[0], wb1 = w1[1], va1 = w1[2], vb1 = w1[3];
        float ua0 = fmaf(z[1], wa0.y, fmaf(z[0], wa0.x, b1[j0]));
        ua0 = fmaf(z[3], wa0.w, fmaf(z[2], wa0.z, ua0));
        float ub0 = fmaf(z[5], wb0.y, z[4] * wb0.x);
        ub0 = fmaf(z[7], wb0.w, fmaf(z[6], wb0.z, ub0));
        float ua1 = fmaf(z[1], wa1.y, fmaf(z[0], wa1.x, b1[j1]));
        ua1 = fmaf(z[3], wa1.w, fmaf(z[2], wa1.z, ua1));
        float ub1 = fmaf(z[5], wb1.y, z[4] * wb1.x);
        ub1 = fmaf(z[7], wb1.w, fmaf(z[6], wb1.z, ub1));
        float h0 = fmaxf(ua0 + ub0, 0.f);
        float h1 = fmaxf(ua1 + ub1, 0.f);
        acc[0] = fmaf(h0, va0.x, acc[0]); acc[1] = fmaf(h0, va0.y, acc[1]);
        acc[2] = fmaf(h0, va0.z, acc[2]); acc[3] = fmaf(h0, va0.w, acc[3]);
        acc[4] = fmaf(h0, vb0.x, acc[4]); acc[5] = fmaf(h0, vb0.y, acc[5]);
        acc[6] = fmaf(h0, vb0.z, acc[6]); acc[7] = fmaf(h0, vb0.w, acc[7]);
        acc[0] = fmaf(h1, va1.x, acc[0]); acc[1] = fmaf(h1, va1.y, acc[1]);
        acc[2] = fmaf(h1, va1.z, acc[2]); acc[3] = fmaf(h1, va1.w, acc[3]);
        acc[4] = fmaf(h1, vb1.x, acc[4]); acc[5] = fmaf(h1, vb1.y, acc[5]);
        acc[6] = fmaf(h1, vb1.z, acc[6]); acc[7] = fmaf(h1, vb1.w, acc[7]);
    }
#pragma unroll
    for (int m = 1; m < 8; m <<= 1)
#pragma unroll
        for (int k = 0; k < DD; k++) acc[k] += __shfl_xor(acc[k], m);
    float yl = acc[0];
#pragma unroll
    for (int k = 1; k < DD; k++) yl = (l == k) ? acc[k] : yl;
    ya[(size_t)v * DD + l] = a[v] * yl;
}

// h = b*AggIn(ya) + b2 + q, into hmd paired slots (v*16 + 2d)
__global__ void k_h_agg(const int* __restrict__ start, const int* __restrict__ csr,
                        const float* __restrict__ ya, const float* __restrict__ b,
                        const float* __restrict__ q, const float* __restrict__ b2,
                        float* __restrict__ hmd, int N) {
    int t = blockIdx.x * blockDim.x + threadIdx.x;
    int v = t >> 3, d = t & 7;
    if (v >= N) return;
    int e0 = start[v], e1 = start[v + 1];
    float s = 0.f;
    int e = e0;
    for (; e + 3 < e1; e += 4) {
        int u0 = csr[e], u1 = csr[e + 1], u2 = csr[e + 2], u3 = csr[e + 3];
        float x0 = ya[(size_t)u0 * DD + d], x1 = ya[(size_t)u1 * DD + d];
        float x2 = ya[(size_t)u2 * DD + d], x3 = ya[(size_t)u3 * DD + d];
        s += (x0 + x1) + (x2 + x3);
    }
    for (; e < e1; e++) s += ya[(size_t)csr[e] * DD + d];
    hmd[(size_t)v * 16 + 2 * d] = fmaf(b[v], s, b2[d] + q[(size_t)v * DD + d]);
}

// gravity gradient wrt h, symmetric per-node form, paired float2 hmd reads
__global__ void k_gh(const int* __restrict__ start_in, const int* __restrict__ csr_in,
                     const int* __restrict__ start_out, const int* __restrict__ csr_out,
                     const float* __restrict__ hmd,
                     const float* __restrict__ b, const float* __restrict__ grav,
                     float* __restrict__ gh, float* __restrict__ bgh, int N) {
    int t = blockIdx.x * blockDim.x + threadIdx.x;
    int v = t >> 3, d = t & 7;
    if (v >= N) return;
    float2 self = *(const float2*)(hmd + (size_t)v * 16 + 2 * d);
    float hv = self.x, mv = self.y;
    float coef = -0.5f * grav[0];
    float acc = 0.f;
#pragma unroll
    for (int dir = 0; dir < 2; dir++) {
        const int* start = dir ? start_out : start_in;
        const int* csr   = dir ? csr_out   : csr_in;
        int e1 = start[v + 1];
        int e = start[v];
        for (; e + 3 < e1; e += 4) {
            int u0 = csr[e], u1 = csr[e + 1], u2 = csr[e + 2], u3 = csr[e + 3];
            float2 p0 = *(const float2*)(hmd + (size_t)u0 * 16 + 2 * d);
            float2 p1 = *(const float2*)(hmd + (size_t)u1 * 16 + 2 * d);
            float2 p2 = *(const float2*)(hmd + (size_t)u2 * 16 + 2 * d);
            float2 p3 = *(const float2*)(hmd + (size_t)u3 * 16 + 2 * d);
            float d0 = hv - p0.x, d1 = hv - p1.x, d2 = hv - p2.x, d3 = hv - p3.x;
            float e20 = d0 * d0, e21 = d1 * d1, e22 = d2 * d2, e23 = d3 * d3;
            float S0 = mv * p0.y, S1 = mv * p1.y, S2 = mv * p2.y, S3 = mv * p3.y;
            e20 += __shfl_xor(e20, 1); S0 += __shfl_xor(S0, 1);
            e21 += __shfl_xor(e21, 1); S1 += __shfl_xor(S1, 1);
            e22 += __shfl_xor(e22, 1); S2 += __shfl_xor(S2, 1);
            e23 += __shfl_xor(e23, 1); S3 += __shfl_xor(S3, 1);
            e20 += __shfl_xor(e20, 2); S0 += __shfl_xor(S0, 2);
            e21 += __shfl_xor(e21, 2); S1 += __shfl_xor(S1, 2);
            e22 += __shfl_xor(e22, 2); S2 += __shfl_xor(S2, 2);
            e23 += __shfl_xor(e23, 2); S3 += __shfl_xor(S3, 2);
            e20 += __shfl_xor(e20, 4); S0 += __shfl_xor(S0, 4);
            e21 += __shfl_xor(e21, 4); S1 += __shfl_xor(S1, 4);
            e22 += __shfl_xor(e22, 4); S2 += __shfl_xor(S2, 4);
            e23 += __shfl_xor(e23, 4); S3 += __shfl_xor(S3, 4);
            float c0 = coef * S0 / (e20 * sqrtf(e20));
            float c1 = coef * S1 / (e21 * sqrtf(e21));
            float c2 = coef * S2 / (e22 * sqrtf(e22));
            float c3 = coef * S3 / (e23 * sqrtf(e23));
            acc = fmaf(c0, d0, acc); acc = fmaf(c1, d1, acc);
            acc = fmaf(c2, d2, acc); acc = fmaf(c3, d3, acc);
        }
        for (; e < e1; e++) {
            int u = csr[e];
            float2 pu = *(const float2*)(hmd + (size_t)u * 16 + 2 * d);
            float dif = hv - pu.x;
            float e2 = dif * dif;
            float S  = mv * pu.y;
            e2 += __shfl_xor(e2, 1); S += __shfl_xor(S, 1);
            e2 += __shfl_xor(e2, 2); S += __shfl_xor(S, 2);
            e2 += __shfl_xor(e2, 4); S += __shfl_xor(S, 4);
            float c = coef * S / (e2 * sqrtf(e2));
            acc = fmaf(c, dif, acc);
        }
    }
    gh[(size_t)v * DD + d] = acc;
    bgh[(size_t)v * DD + d] = b[v] * acc;
}

// ============ fused gather + MLP backward: 8 threads per node ===============
__launch_bounds__(256)
__global__ void k_mlp_bwd(const int* __restrict__ start, const int* __restrict__ csr,
                          const float* __restrict__ bgh, const float* __restrict__ z1,
                          const float* __restrict__ a, const float* __restrict__ b,
                          const float* __restrict__ W12, const float* __restrict__ b1,
                          float* __restrict__ gz1b, int N) {
    int t = blockIdx.x * blockDim.x + threadIdx.x;
    int v = t >> 3, l = t & 7;
    if (v >= N) return;
    // gather gq component l over out-CSR
    int e0 = start[v], e1 = start[v + 1];
    float s = 0.f;
    int e = e0;
    for (; e + 3 < e1; e += 4) {
        int u0 = csr[e], u1 = csr[e + 1], u2 = csr[e + 2], u3 = csr[e + 3];
        float x0 = bgh[(size_t)u0 * DD + l], x1 = bgh[(size_t)u1 * DD + l];
        float x2 = bgh[(size_t)u2 * DD + l], x3 = bgh[(size_t)u3 * DD + l];
        s += (x0 + x1) + (x2 + x3);
    }
    for (; e < e1; e++) s += bgh[(size_t)csr[e] * DD + l];
    float gq[DD];
#pragma unroll
    for (int k = 0; k < DD; k++) gq[k] = __shfl(s, k, 8);
    float zl = z1[(size_t)v * DD + l];
    float z[DD];
#pragma unroll
    for (int k = 0; k < DD; k++) z[k] = __shfl(zl, k, 8);

    float av = a[v];
    float gz[DD] = {0.f, 0.f, 0.f, 0.f, 0.f, 0.f, 0.f, 0.f};
    for (int c = 0; c < HH / DD; c += 2) {
        int j0 = (c << 3) | l, j1 = j0 + 8;
        const float4* w0 = (const float4*)(W12 + (size_t)j0 * 16);
        const float4* w1 = (const float4*)(W12 + (size_t)j1 * 16);
        float4 wa0 = w0[0], wb0 = w0[1], va0 = w0[2], vb0 = w0[3];
        float4 wa1 = w1[0], wb1 = w1[1], va1 = w1[2], vb1 = w1[3];
        float ua0 = fmaf(z[1], wa0.y, fmaf(z[0], wa0.x, b1[j0]));
        ua0 = fmaf(z[3], wa0.w, fmaf(z[2], wa0.z, ua0));
        float ub0 = fmaf(z[5], wb0.y, z[4] * wb0.x);
        ub0 = fmaf(z[7], wb0.w, fmaf(z[6], wb0.z, ub0));
        float ua1 = fmaf(z[1], wa1.y, fmaf(z[0], wa1.x, b1[j1]));
        ua1 = fmaf(z[3], wa1.w, fmaf(z[2], wa1.z, ua1));
        float ub1 = fmaf(z[5], wb1.y, z[4] * wb1.x);
        ub1 = fmaf(z[7], wb1.w, fmaf(z[6], wb1.z, ub1));
        float u0 = ua0 + ub0, u1 = ua1 + ub1;
        float ga0 = fmaf(gq[1], va0.y, gq[0] * va0.x);
        ga0 = fmaf(gq[3], va0.w, fmaf(gq[2], va0.z, ga0));
        float gb0 = fmaf(gq[5], vb0.y, gq[4] * vb0.x);
        gb0 = fmaf(gq[7], vb0.w, fmaf(gq[6], vb0.z, gb0));
        float ga1 = fmaf(gq[1], va1.y, gq[0] * va1.x);
        ga1 = fmaf(gq[3], va1.w, fmaf(gq[2], va1.z, ga1));
        float gb1 = fmaf(gq[5], vb1.y, gq[4] * vb1.x);
        gb1 = fmaf(gq[7], vb1.w, fmaf(gq[6], vb1.z, gb1));
        float g0 = (u0 > 0.f) ? av * (ga0 + gb0) : 0.f;
        float g1 = (u1 > 0.f) ? av * (ga1 + gb1) : 0.f;
        gz[0] = fmaf(g0, wa0.x, gz[0]); gz[1] = fmaf(g0, wa0.y, gz[1]);
        gz[2] = fmaf(g0, wa0.z, gz[2]); gz[3] = fmaf(g0, wa0.w, gz[3]);
        gz[4] = fmaf(g0, wb0.x, gz[4]); gz[5] = fmaf(g0, wb0.y, gz[5]);
        gz[6] = fmaf(g0, wb0.z, gz[6]); gz[7] = fmaf(g0, wb0.w, gz[7]);
        gz[0] = fmaf(g1, wa1.x, gz[0]); gz[1] = fmaf(g1, wa1.y, gz[1]);
        gz[2] = fmaf(g1, wa1.z, gz[2]); gz[3] = fmaf(g1, wa1.w, gz[3]);
        gz[4] = fmaf(g1, wb1.x, gz[4]); gz[5] = fmaf(g1, wb1.y, gz[5]);
        gz[6] = fmaf(g1, wb1.z, gz[6]); gz[7] = fmaf(g1, wb1.w, gz[7]);
    }
#pragma unroll
    for (int m = 1; m < 8; m <<= 1)
#pragma unroll
        for (int k = 0; k < DD; k++) gz[k] += __shfl_xor(gz[k], m);
    float gl = gz[0];
#pragma unroll
    for (int k = 1; k < DD; k++) gl = (l == k) ? gz[k] : gl;
    gz1b[(size_t)v * DD + l] = b[v] * gl;
}

__global__ void k_out_agg(const int* __restrict__ start, const int* __restrict__ csr,
                          const float* __restrict__ gz1b, const float* __restrict__ gh,
                          const float* __restrict__ a, float* __restrict__ out, int N) {
    int t = blockIdx.x * blockDim.x + threadIdx.x;
    int v = t >> 3, d = t & 7;
    if (v >= N) return;
    int e0 = start[v], e1 = start[v + 1];
    float s = 0.f;
    int e = e0;
    for (; e + 3 < e1; e += 4) {
        int u0 = csr[e], u1 = csr[e + 1], u2 = csr[e + 2], u3 = csr[e + 3];
        float x0 = gz1b[(size_t)u0 * DD + d], x1 = gz1b[(size_t)u1 * DD + d];
        float x2 = gz1b[(size_t)u2 * DD + d], x3 = gz1b[(size_t)u3 * DD + d];
        s += (x0 + x1) + (x2 + x3);
    }
    for (; e < e1; e++) s += gz1b[(size_t)csr[e] * DD + d];
    out[(size_t)v * 2 * DD + d] = fmaf(a[v], s, gh[(size_t)v * DD + d]);
}

// ============================== launch =====================================

extern "C" void kernel_launch(void* const* d_in, const int* in_sizes, int n_in,
                              void* d_out, int out_size, void* d_ws, size_t ws_size,
                              hipStream_t stream) {
    const float* q    = (const float*)d_in[0];
    const float* p    = (const float*)d_in[1];
    const float* M    = (const float*)d_in[2];
    const int*   src  = (const int*)d_in[3];
    const int*   dst  = (const int*)d_in[4];
    const float* W1   = (const float*)d_in[5];
    const float* b1   = (const float*)d_in[6];
    const float* W2   = (const float*)d_in[7];
    const float* b2   = (const float*)d_in[8];
    const float* grav = (const float*)d_in[9];
    float* out = (float*)d_out;

    int N = in_sizes[0] / DD;
    int E = in_sizes[3];
    size_t n = (size_t)N;
    int NB = (N + 511) >> 9;   // coarse buckets (<=256 for N<=131072)

    // ---- float region (58N floats) ----
    float* ws   = (float*)d_ws;
    float* a_   = ws;             // N
    float* b_   = ws + n;         // N
    float* qn   = ws + 2  * n;    // 8N
    float* z1   = ws + 10 * n;    // 8N  (stored by fwd, read by bwd)
    float* ya   = ws + 18 * n;    // 8N  (reused as gz1b)
    float* hmd  = ws + 26 * n;    // 16N (pairs: h at 2d, md at 2d+1)
    float* gh   = ws + 42 * n;    // 8N
    float* bgh  = ws + 50 * n;    // 8N
    float* gz1b = ya;

    // ---- int region ----
    int* iw        = (int*)(ws + 58 * n);
    int* csr_in    = iw;                       // E
    int* csr_out   = iw + (size_t)E;           // E
    int* start_in  = iw + 2 * (size_t)E;       // N+1
    int* start_out = start_in + n + 1;         // N+1
    int* gHistIn   = start_out + n + 1;        // 256
    int* gHistOut  = gHistIn + 256;            // 256
    int* cStartIn  = gHistOut + 256;           // NB+1
    int* cStartOut = cStartIn + NB + 1;        // NB+1
    int* cCurIn    = cStartOut + NB + 1;       // NB
    int* cCurOut   = cCurIn + NB;              // NB
    int* iwEnd     = cCurOut + NB;
    float* W12     = (float*)iwEnd;            // 4096 floats (16KB)
    // partition scratch (E ints): alias gh/bgh float region (dead during CSR build)
    int* P = (E <= 16 * (long long)n) ? (int*)(ws + 42 * n) : (int*)(W12 + HH * 16);

    hipMemsetAsync(gHistIn, 0, 512 * sizeof(int), stream);

    const int tb = 256;
    int gbN = (N + tb - 1) / tb;
    int gb8 = (int)((8 * n + tb - 1) / tb);
    int gbC = (E + CH - 1) / CH;

    // CSR build (bucketed counting sort, both directions; P reused)
    k_coarse   <<<gbC, tb, 0, stream>>>(src, dst, gHistIn, gHistOut, NB, E);
    k_wt       <<<8, tb, 0, stream>>>(W1, W2, W12);
    k_cscan    <<<1, 256, 0, stream>>>(gHistIn, gHistOut, cStartIn, cStartOut,
                                       cCurIn, cCurOut, NB, E);
    k_partition<<<gbC, tb, 0, stream>>>(dst, src, cCurIn, P, NB, E);
    k_fine     <<<NB, 512, 0, stream>>>(cStartIn, P, start_in, csr_in, N);
    k_partition<<<gbC, tb, 0, stream>>>(src, dst, cCurOut, P, NB, E);
    k_fine     <<<NB, 512, 0, stream>>>(cStartOut, P, start_out, csr_out, N);
    k_prep     <<<gbN, tb, 0, stream>>>(q, p, M, start_in, start_out,
                                        a_, b_, hmd, qn, out, N, E);

    // forward (fused gather+MLP): z1 = b ⊙ AggIn(a⊙q); ya = a ⊙ (relu(z1@W1+b1)@W2)
    k_mlp_fwd  <<<gb8, tb, 0, stream>>>(start_in, csr_in, qn, a_, b_,
                                        W12, b1, z1, ya, N);
    // h = b ⊙ AggIn(ya) + b2 + q  (into hmd paired slots)
    k_h_agg    <<<gb8, tb, 0, stream>>>(start_in, csr_in, ya, b_, q, b2, hmd, N);
    // gravity gradient (symmetric per-node, paired float2 loads)
    k_gh       <<<gb8, tb, 0, stream>>>(start_in, csr_in, start_out, csr_out,
                                        hmd, b_, grav, gh, bgh, N);
    // backward (fused gather+MLP): gq2 = AggOut(bgh); gz1b = b ⊙ ((a⊙(gq2@W2^T)⊙relu')@W1^T)
    k_mlp_bwd  <<<gb8, tb, 0, stream>>>(start_out, csr_out, bgh, z1, a_, b_,
                                        W12, b1, gz1b, N);
    // dHdQ = gh + a ⊙ AggOut(gz1b)
    k_out_agg  <<<gb8, tb, 0, stream>>>(start_out, csr_out, gz1b, gh, a_, out, N);
}

// Round 7
// 372.672 us; speedup vs baseline: 1.3906x; 1.3906x over previous
//
#include <hip/hip_runtime.h>

#define DD 8
#define HH 256
#define CH 8192          // edges per chunk in coarse/partition kernels
#define PAYBITS 17       // N <= 131072
#define PAYMASK 0x1FFFF
#define WPITCH 20        // LDS/global weight row pitch (floats): conflict-free

// ============================ CSR construction ==============================
// Bucketed counting sort: coarse bucket = node >> 9, fine bin = node & 511.

__global__ void k_coarse(const int* __restrict__ src, const int* __restrict__ dst,
                         int* __restrict__ gHistIn, int* __restrict__ gHistOut,
                         int NB, int E) {
    __shared__ int hIn[256], hOut[256];
    if (threadIdx.x < 256) { hIn[threadIdx.x] = 0; hOut[threadIdx.x] = 0; }
    __syncthreads();
    int lo = blockIdx.x * CH;
    int hi = min(lo + CH, E);
    for (int i = lo + threadIdx.x; i < hi; i += blockDim.x) {
        atomicAdd(&hIn[dst[i] >> 9], 1);
        atomicAdd(&hOut[src[i] >> 9], 1);
    }
    __syncthreads();
    if (threadIdx.x < NB) {
        int ci = hIn[threadIdx.x], co = hOut[threadIdx.x];
        if (ci) atomicAdd(&gHistIn[threadIdx.x], ci);
        if (co) atomicAdd(&gHistOut[threadIdx.x], co);
    }
}

__global__ void k_cscan(const int* __restrict__ gHistIn, const int* __restrict__ gHistOut,
                        int* __restrict__ cStartIn, int* __restrict__ cStartOut,
                        int* __restrict__ cCurIn, int* __restrict__ cCurOut,
                        int NB, int E) {
    __shared__ int s[256];
#pragma unroll
    for (int dir = 0; dir < 2; dir++) {
        const int* gh = dir ? gHistOut : gHistIn;
        int* cs = dir ? cStartOut : cStartIn;
        int* cc = dir ? cCurOut : cCurIn;
        int v = (threadIdx.x < NB) ? gh[threadIdx.x] : 0;
        s[threadIdx.x] = v;
        __syncthreads();
        for (int off = 1; off < 256; off <<= 1) {
            int t = (threadIdx.x >= off) ? s[threadIdx.x - off] : 0;
            __syncthreads();
            s[threadIdx.x] += t;
            __syncthreads();
        }
        if (threadIdx.x < NB) {
            int ex = s[threadIdx.x] - v;
            cs[threadIdx.x] = ex;
            cc[threadIdx.x] = ex;
        }
        if (threadIdx.x == 0) cs[NB] = E;
        __syncthreads();
    }
}

// both directions in one launch: dir = blockIdx.y (0: key=dst pay=src -> in)
__global__ void k_part2(const int* __restrict__ src, const int* __restrict__ dst,
                        int* __restrict__ cCurIn, int* __restrict__ cCurOut,
                        int* __restrict__ P_in, int* __restrict__ P_out,
                        int NB, int E) {
    int dir = blockIdx.y;
    const int* key = dir ? src : dst;
    const int* pay = dir ? dst : src;
    int* cCur = dir ? cCurOut : cCurIn;
    int* P    = dir ? P_out   : P_in;
    __shared__ int h[256];
    if (threadIdx.x < 256) h[threadIdx.x] = 0;
    __syncthreads();
    int lo = blockIdx.x * CH;
    int hi = min(lo + CH, E);
    for (int i = lo + threadIdx.x; i < hi; i += blockDim.x)
        atomicAdd(&h[key[i] >> 9], 1);
    __syncthreads();
    if (threadIdx.x < NB) {
        int c = h[threadIdx.x];
        h[threadIdx.x] = c ? atomicAdd(&cCur[threadIdx.x], c) : 0;
    }
    __syncthreads();
    for (int i = lo + threadIdx.x; i < hi; i += blockDim.x) {
        int k = key[i];
        int pos = atomicAdd(&h[k >> 9], 1);
        P[pos] = ((k & 511) << PAYBITS) | pay[i];
    }
}

__launch_bounds__(512)
__global__ void k_fine2(const int* __restrict__ cStartIn, const int* __restrict__ cStartOut,
                        const int* __restrict__ P_in, const int* __restrict__ P_out,
                        int* __restrict__ start_in, int* __restrict__ start_out,
                        int* __restrict__ csr_in, int* __restrict__ csr_out, int N) {
    int dir = blockIdx.y;
    const int* cStart = dir ? cStartOut : cStartIn;
    const int* P      = dir ? P_out     : P_in;
    int* start        = dir ? start_out : start_in;
    int* csr          = dir ? csr_out   : csr_in;
    __shared__ int cnt[512], scn[512];
    int b = blockIdx.x;
    int lo = cStart[b], hi = cStart[b + 1];
    cnt[threadIdx.x] = 0;
    __syncthreads();
    for (int i = lo + threadIdx.x; i < hi; i += 512)
        atomicAdd(&cnt[P[i] >> PAYBITS], 1);
    __syncthreads();
    int own = cnt[threadIdx.x];
    scn[threadIdx.x] = own;
    __syncthreads();
    for (int off = 1; off < 512; off <<= 1) {
        int t = (threadIdx.x >= off) ? scn[threadIdx.x - off] : 0;
        __syncthreads();
        scn[threadIdx.x] += t;
        __syncthreads();
    }
    int base = lo + scn[threadIdx.x] - own;
    int node = (b << 9) + threadIdx.x;
    if (node < N) start[node] = base;
    cnt[threadIdx.x] = base;   // reuse as cursor
    __syncthreads();
    for (int i = lo + threadIdx.x; i < hi; i += 512) {
        int p = P[i];
        int pos = atomicAdd(&cnt[p >> PAYBITS], 1);
        csr[pos] = p & PAYMASK;
    }
}

// ==== weight pack (padded pitch 20): row j = {W1[:,j] (8), W2[j,:] (8), pad} =
__global__ void k_wt(const float* __restrict__ W1, const float* __restrict__ W2,
                     float* __restrict__ W12p) {
    int i = blockIdx.x * blockDim.x + threadIdx.x;
    if (i < HH * DD) {
        int j = i >> 3, d = i & 7;
        W12p[j * WPITCH + d]     = W1[d * HH + j];
        W12p[j * WPITCH + 8 + d] = W2[j * DD + d];
    }
}

// ===================== per-node prep (norms, masses, dHdP) ==================
// hmd layout: hmd[v*16 + 2d] = h_d (filled later), hmd[v*16 + 2d+1] = m_d.
__global__ void k_prep(const float* __restrict__ q, const float* __restrict__ p,
                       const float* __restrict__ M,
                       int* __restrict__ start_in, int* __restrict__ start_out,
                       float* __restrict__ a, float* __restrict__ b,
                       float* __restrict__ hmd, float* __restrict__ qn,
                       float* __restrict__ out, int N, int E) {
    int v = blockIdx.x * blockDim.x + threadIdx.x;
    if (blockIdx.x == 0 && threadIdx.x == 0) { start_in[N] = E; start_out[N] = E; }
    if (v >= N) return;
    int ei1 = (v + 1 < N) ? start_in[v + 1]  : E;
    int eo1 = (v + 1 < N) ? start_out[v + 1] : E;
    float din  = (float)(ei1 - start_in[v]);
    float dout = (float)(eo1 - start_out[v]);
    float av = 1.0f / sqrtf(dout > 0.f ? dout : 1.f);   // norm_src
    float bv = 1.0f / sqrtf(din  > 0.f ? din  : 1.f);   // norm_dst
    a[v] = av; b[v] = bv;
#pragma unroll
    for (int d = 0; d < DD; d++) {
        float m = M[(size_t)v * DD * DD + d * (DD + 1)];
        hmd[(size_t)v * 16 + 2 * d + 1] = m;
        qn[(size_t)v * DD + d] = av * q[(size_t)v * DD + d];
        out[(size_t)v * 2 * DD + DD + d] = p[(size_t)v * DD + d] / m;  // dHdP
    }
}

// ============== gathers: 16 lanes/node (2 halves split the edge list) =======

__global__ void k_agg16(const int* __restrict__ start, const int* __restrict__ csr,
                        const float* __restrict__ x, float* __restrict__ y, int N) {
    int t = blockIdx.x * blockDim.x + threadIdx.x;
    int v = t >> 4, sub = (t >> 3) & 1, d = t & 7;
    if (v >= N) return;
    int e1 = start[v + 1];
    float s = 0.f;
    int e = start[v] + sub;
    for (; e + 6 < e1; e += 8) {
        int u0 = csr[e], u1 = csr[e + 2], u2 = csr[e + 4], u3 = csr[e + 6];
        float x0 = x[(size_t)u0 * DD + d], x1 = x[(size_t)u1 * DD + d];
        float x2 = x[(size_t)u2 * DD + d], x3 = x[(size_t)u3 * DD + d];
        s += (x0 + x1) + (x2 + x3);
    }
    for (; e < e1; e += 2) s += x[(size_t)csr[e] * DD + d];
    s += __shfl_xor(s, 8);
    if (!sub) y[(size_t)v * DD + d] = s;
}

// h = b*AggIn(ya) + b2 + q, into hmd paired slots
__global__ void k_h_agg16(const int* __restrict__ start, const int* __restrict__ csr,
                          const float* __restrict__ ya, const float* __restrict__ b,
                          const float* __restrict__ q, const float* __restrict__ b2,
                          float* __restrict__ hmd, int N) {
    int t = blockIdx.x * blockDim.x + threadIdx.x;
    int v = t >> 4, sub = (t >> 3) & 1, d = t & 7;
    if (v >= N) return;
    int e1 = start[v + 1];
    float s = 0.f;
    int e = start[v] + sub;
    for (; e + 6 < e1; e += 8) {
        int u0 = csr[e], u1 = csr[e + 2], u2 = csr[e + 4], u3 = csr[e + 6];
        float x0 = ya[(size_t)u0 * DD + d], x1 = ya[(size_t)u1 * DD + d];
        float x2 = ya[(size_t)u2 * DD + d], x3 = ya[(size_t)u3 * DD + d];
        s += (x0 + x1) + (x2 + x3);
    }
    for (; e < e1; e += 2) s += ya[(size_t)csr[e] * DD + d];
    s += __shfl_xor(s, 8);
    if (!sub)
        hmd[(size_t)v * 16 + 2 * d] = fmaf(b[v], s, b2[d] + q[(size_t)v * DD + d]);
}

// out[:, :D] = gh + a * AggOut(gz1b)
__global__ void k_out_agg16(const int* __restrict__ start, const int* __restrict__ csr,
                            const float* __restrict__ gz1b, const float* __restrict__ gh,
                            const float* __restrict__ a, float* __restrict__ out, int N) {
    int t = blockIdx.x * blockDim.x + threadIdx.x;
    int v = t >> 4, sub = (t >> 3) & 1, d = t & 7;
    if (v >= N) return;
    int e1 = start[v + 1];
    float s = 0.f;
    int e = start[v] + sub;
    for (; e + 6 < e1; e += 8) {
        int u0 = csr[e], u1 = csr[e + 2], u2 = csr[e + 4], u3 = csr[e + 6];
        float x0 = gz1b[(size_t)u0 * DD + d], x1 = gz1b[(size_t)u1 * DD + d];
        float x2 = gz1b[(size_t)u2 * DD + d], x3 = gz1b[(size_t)u3 * DD + d];
        s += (x0 + x1) + (x2 + x3);
    }
    for (; e < e1; e += 2) s += gz1b[(size_t)csr[e] * DD + d];
    s += __shfl_xor(s, 8);
    if (!sub)
        out[(size_t)v * 2 * DD + d] = fmaf(a[v], s, gh[(size_t)v * DD + d]);
}

// gravity gradient: 16 lanes/node, half 0 walks in-CSR, half 1 walks out-CSR
__global__ void k_gh16(const int* __restrict__ start_in, const int* __restrict__ csr_in,
                       const int* __restrict__ start_out, const int* __restrict__ csr_out,
                       const float* __restrict__ hmd,
                       const float* __restrict__ b, const float* __restrict__ grav,
                       float* __restrict__ gh, float* __restrict__ bgh, int N) {
    int t = blockIdx.x * blockDim.x + threadIdx.x;
    int v = t >> 4, dir = (t >> 3) & 1, d = t & 7;
    if (v >= N) return;
    float2 self = *(const float2*)(hmd + (size_t)v * 16 + 2 * d);
    float hv = self.x, mv = self.y;
    float coef = -0.5f * grav[0];
    float acc = 0.f;
    const int* start = dir ? start_out : start_in;
    const int* csr   = dir ? csr_out   : csr_in;
    int e1 = start[v + 1];
    int e = start[v];
    for (; e + 3 < e1; e += 4) {
        int u0 = csr[e], u1 = csr[e + 1], u2 = csr[e + 2], u3 = csr[e + 3];
        float2 p0 = *(const float2*)(hmd + (size_t)u0 * 16 + 2 * d);
        float2 p1 = *(const float2*)(hmd + (size_t)u1 * 16 + 2 * d);
        float2 p2 = *(const float2*)(hmd + (size_t)u2 * 16 + 2 * d);
        float2 p3 = *(const float2*)(hmd + (size_t)u3 * 16 + 2 * d);
        float d0 = hv - p0.x, d1 = hv - p1.x, d2 = hv - p2.x, d3 = hv - p3.x;
        float e20 = d0 * d0, e21 = d1 * d1, e22 = d2 * d2, e23 = d3 * d3;
        float S0 = mv * p0.y, S1 = mv * p1.y, S2 = mv * p2.y, S3 = mv * p3.y;
        e20 += __shfl_xor(e20, 1); S0 += __shfl_xor(S0, 1);
        e21 += __shfl_xor(e21, 1); S1 += __shfl_xor(S1, 1);
        e22 += __shfl_xor(e22, 1); S2 += __shfl_xor(S2, 1);
        e23 += __shfl_xor(e23, 1); S3 += __shfl_xor(S3, 1);
        e20 += __shfl_xor(e20, 2); S0 += __shfl_xor(S0, 2);
        e21 += __shfl_xor(e21, 2); S1 += __shfl_xor(S1, 2);
        e22 += __shfl_xor(e22, 2); S2 += __shfl_xor(S2, 2);
        e23 += __shfl_xor(e23, 2); S3 += __shfl_xor(S3, 2);
        e20 += __shfl_xor(e20, 4); S0 += __shfl_xor(S0, 4);
        e21 += __shfl_xor(e21, 4); S1 += __shfl_xor(S1, 4);
        e22 += __shfl_xor(e22, 4); S2 += __shfl_xor(S2, 4);
        e23 += __shfl_xor(e23, 4); S3 += __shfl_xor(S3, 4);
        float c0 = coef * S0 / (e20 * sqrtf(e20));
        float c1 = coef * S1 / (e21 * sqrtf(e21));
        float c2 = coef * S2 / (e22 * sqrtf(e22));
        float c3 = coef * S3 / (e23 * sqrtf(e23));
        acc = fmaf(c0, d0, acc); acc = fmaf(c1, d1, acc);
        acc = fmaf(c2, d2, acc); acc = fmaf(c3, d3, acc);
    }
    for (; e < e1; e++) {
        int u = csr[e];
        float2 pu = *(const float2*)(hmd + (size_t)u * 16 + 2 * d);
        float dif = hv - pu.x;
        float e2 = dif * dif;
        float S  = mv * pu.y;
        e2 += __shfl_xor(e2, 1); S += __shfl_xor(S, 1);
        e2 += __shfl_xor(e2, 2); S += __shfl_xor(S, 2);
        e2 += __shfl_xor(e2, 4); S += __shfl_xor(S, 4);
        float c = coef * S / (e2 * sqrtf(e2));
        acc = fmaf(c, dif, acc);
    }
    acc += __shfl_xor(acc, 8);   // combine the two direction halves
    if (!dir) {
        gh[(size_t)v * DD + d] = acc;
        bgh[(size_t)v * DD + d] = b[v] * acc;
    }
}

// ============== MLP kernels: 8 threads/node, LDS weights (pitch 20) =========
// Lane l handles hidden units j=8c+l. LDS row starts (20j)%32 are disjoint
// 4-bank spans across the 8 lanes -> conflict-free ds_read_b128.

__launch_bounds__(256)
__global__ void k_mlp_fwd(const float* __restrict__ agg1, const float* __restrict__ a,
                          const float* __restrict__ b,
                          const float* __restrict__ W12p, const float* __restrict__ b1,
                          float* __restrict__ ya, int N) {
    __shared__ float sW[HH * WPITCH];
    __shared__ float sb1[HH];
    for (int i = threadIdx.x; i < HH * WPITCH; i += 256) sW[i] = W12p[i];
    for (int i = threadIdx.x; i < HH; i += 256) sb1[i] = b1[i];
    __syncthreads();
    int t = blockIdx.x * 256 + threadIdx.x;
    int v = t >> 3, l = t & 7;
    if (v >= N) return;
    float zl = b[v] * agg1[(size_t)v * DD + l];
    float z[DD];
#pragma unroll
    for (int k = 0; k < DD; k++) z[k] = __shfl(zl, k, 8);
    float acc[DD] = {0.f, 0.f, 0.f, 0.f, 0.f, 0.f, 0.f, 0.f};
    for (int c = 0; c < HH / DD; c += 2) {
        int j0 = (c << 3) | l, j1 = j0 + 8;
        const float4* w0 = (const float4*)(sW + j0 * WPITCH);
        const float4* w1 = (const float4*)(sW + j1 * WPITCH);
        float4 wa0 = w0[0], wb0 = w0[1], va0 = w0[2], vb0 = w0[3];
        float4 wa1 = w1[0], wb1 = w1[1], va1 = w1[2], vb1 = w1[3];
        float ua0 = fmaf(z[1], wa0.y, fmaf(z[0], wa0.x, sb1[j0]));
        ua0 = fmaf(z[3], wa0.w, fmaf(z[2], wa0.z, ua0));
        float ub0 = fmaf(z[5], wb0.y, z[4] * wb0.x);
        ub0 = fmaf(z[7], wb0.w, fmaf(z[6], wb0.z, ub0));
        float ua1 = fmaf(z[1], wa1.y, fmaf(z[0], wa1.x, sb1[j1]));
        ua1 = fmaf(z[3], wa1.w, fmaf(z[2], wa1.z, ua1));
        float ub1 = fmaf(z[5], wb1.y, z[4] * wb1.x);
        ub1 = fmaf(z[7], wb1.w, fmaf(z[6], wb1.z, ub1));
        float h0 = fmaxf(ua0 + ub0, 0.f);
        float h1 = fmaxf(ua1 + ub1, 0.f);
        acc[0] = fmaf(h0, va0.x, acc[0]); acc[1] = fmaf(h0, va0.y, acc[1]);
        acc[2] = fmaf(h0, va0.z, acc[2]); acc[3] = fmaf(h0, va0.w, acc[3]);
        acc[4] = fmaf(h0, vb0.x, acc[4]); acc[5] = fmaf(h0, vb0.y, acc[5]);
        acc[6] = fmaf(h0, vb0.z, acc[6]); acc[7] = fmaf(h0, vb0.w, acc[7]);
        acc[0] = fmaf(h1, va1.x, acc[0]); acc[1] = fmaf(h1, va1.y, acc[1]);
        acc[2] = fmaf(h1, va1.z, acc[2]); acc[3] = fmaf(h1, va1.w, acc[3]);
        acc[4] = fmaf(h1, vb1.x, acc[4]); acc[5] = fmaf(h1, vb1.y, acc[5]);
        acc[6] = fmaf(h1, vb1.z, acc[6]); acc[7] = fmaf(h1, vb1.w, acc[7]);
    }
#pragma unroll
    for (int m = 1; m < 8; m <<= 1)
#pragma unroll
        for (int k = 0; k < DD; k++) acc[k] += __shfl_xor(acc[k], m);
    float yl = acc[0];
#pragma unroll
    for (int k = 1; k < DD; k++) yl = (l == k) ? acc[k] : yl;
    ya[(size_t)v * DD + l] = a[v] * yl;
}

__launch_bounds__(256)
__global__ void k_mlp_bwd(const float* __restrict__ gq2, const float* __restrict__ agg1,
                          const float* __restrict__ a, const float* __restrict__ b,
                          const float* __restrict__ W12p, const float* __restrict__ b1,
                          float* __restrict__ gz1b, int N) {
    __shared__ float sW[HH * WPITCH];
    __shared__ float sb1[HH];
    for (int i = threadIdx.x; i < HH * WPITCH; i += 256) sW[i] = W12p[i];
    for (int i = threadIdx.x; i < HH; i += 256) sb1[i] = b1[i];
    __syncthreads();
    int t = blockIdx.x * 256 + threadIdx.x;
    int v = t >> 3, l = t & 7;
    if (v >= N) return;
    float bv = b[v], av = a[v];
    float zl = bv * agg1[(size_t)v * DD + l];
    float gl = gq2[(size_t)v * DD + l];
    float z[DD], gq[DD];
#pragma unroll
    for (int k = 0; k < DD; k++) { z[k] = __shfl(zl, k, 8); gq[k] = __shfl(gl, k, 8); }
    float gz[DD] = {0.f, 0.f, 0.f, 0.f, 0.f, 0.f, 0.f, 0.f};
    for (int c = 0; c < HH / DD; c += 2) {
        int j0 = (c << 3) | l, j1 = j0 + 8;
        const float4* w0 = (const float4*)(sW + j0 * WPITCH);
        const float4* w1 = (const float4*)(sW + j1 * WPITCH);
        float4 wa0 = w0[0], wb0 = w0[1], va0 = w0[2], vb0 = w0[3];
        float4 wa1 = w1[0], wb1 = w1[1], va1 = w1[2], vb1 = w1[3];
        float ua0 = fmaf(z[1], wa0.y, fmaf(z[0], wa0.x, sb1[j0]));
        ua0 = fmaf(z[3], wa0.w, fmaf(z[2], wa0.z, ua0));
        float ub0 = fmaf(z[5], wb0.y, z[4] * wb0.x);
        ub0 = fmaf(z[7], wb0.w, fmaf(z[6], wb0.z, ub0));
        float ua1 = fmaf(z[1], wa1.y, fmaf(z[0], wa1.x, sb1[j1]));
        ua1 = fmaf(z[3], wa1.w, fmaf(z[2], wa1.z, ua1));
        float ub1 = fmaf(z[5], wb1.y, z[4] * wb1.x);
        ub1 = fmaf(z[7], wb1.w, fmaf(z[6], wb1.z, ub1));
        float u0 = ua0 + ub0, u1 = ua1 + ub1;
        float ga0 = fmaf(gq[1], va0.y, gq[0] * va0.x);
        ga0 = fmaf(gq[3], va0.w, fmaf(gq[2], va0.z, ga0));
        float gb0 = fmaf(gq[5], vb0.y, gq[4] * vb0.x);
        gb0 = fmaf(gq[7], vb0.w, fmaf(gq[6], vb0.z, gb0));
        float ga1 = fmaf(gq[1], va1.y, gq[0] * va1.x);
        ga1 = fmaf(gq[3], va1.w, fmaf(gq[2], va1.z, ga1));
        float gb1 = fmaf(gq[5], vb1.y, gq[4] * vb1.x);
        gb1 = fmaf(gq[7], vb1.w, fmaf(gq[6], vb1.z, gb1));
        float g0 = (u0 > 0.f) ? av * (ga0 + gb0) : 0.f;
        float g1 = (u1 > 0.f) ? av * (ga1 + gb1) : 0.f;
        gz[0] = fmaf(g0, wa0.x, gz[0]); gz[1] = fmaf(g0, wa0.y, gz[1]);
        gz[2] = fmaf(g0, wa0.z, gz[2]); gz[3] = fmaf(g0, wa0.w, gz[3]);
        gz[4] = fmaf(g0, wb0.x, gz[4]); gz[5] = fmaf(g0, wb0.y, gz[5]);
        gz[6] = fmaf(g0, wb0.z, gz[6]); gz[7] = fmaf(g0, wb0.w, gz[7]);
        gz[0] = fmaf(g1, wa1.x, gz[0]); gz[1] = fmaf(g1, wa1.y, gz[1]);
        gz[2] = fmaf(g1, wa1.z, gz[2]); gz[3] = fmaf(g1, wa1.w, gz[3]);
        gz[4] = fmaf(g1, wb1.x, gz[4]); gz[5] = fmaf(g1, wb1.y, gz[5]);
        gz[6] = fmaf(g1, wb1.z, gz[6]); gz[7] = fmaf(g1, wb1.w, gz[7]);
    }
#pragma unroll
    for (int m = 1; m < 8; m <<= 1)
#pragma unroll
        for (int k = 0; k < DD; k++) gz[k] += __shfl_xor(gz[k], m);
    float out_l = gz[0];
#pragma unroll
    for (int k = 1; k < DD; k++) out_l = (l == k) ? gz[k] : out_l;
    gz1b[(size_t)v * DD + l] = bv * out_l;
}

// ============================== launch =====================================

extern "C" void kernel_launch(void* const* d_in, const int* in_sizes, int n_in,
                              void* d_out, int out_size, void* d_ws, size_t ws_size,
                              hipStream_t stream) {
    const float* q    = (const float*)d_in[0];
    const float* p    = (const float*)d_in[1];
    const float* M    = (const float*)d_in[2];
    const int*   src  = (const int*)d_in[3];
    const int*   dst  = (const int*)d_in[4];
    const float* W1   = (const float*)d_in[5];
    const float* b1   = (const float*)d_in[6];
    const float* W2   = (const float*)d_in[7];
    const float* b2   = (const float*)d_in[8];
    const float* grav = (const float*)d_in[9];
    float* out = (float*)d_out;

    int N = in_sizes[0] / DD;
    int E = in_sizes[3];
    size_t n = (size_t)N;
    int NB = (N + 511) >> 9;

    // ---- float region (58N floats) ----
    float* ws   = (float*)d_ws;
    float* a_   = ws;             // N
    float* b_   = ws + n;         // N
    float* qn   = ws + 2  * n;    // 8N  (reused as gq2 after fwd)
    float* agg1 = ws + 10 * n;    // 8N  (live through bwd: z recompute)
    float* ya   = ws + 18 * n;    // 8N  (reused as gz1b)
    float* hmd  = ws + 26 * n;    // 16N (pairs: h at 2d, md at 2d+1)
    float* gh   = ws + 42 * n;    // 8N
    float* bgh  = ws + 50 * n;    // 8N
    float* gq2  = qn;
    float* gz1b = ya;

    // ---- int region ----
    int* iw        = (int*)(ws + 58 * n);
    int* csr_in    = iw;                       // E
    int* csr_out   = iw + (size_t)E;           // E
    int* start_in  = iw + 2 * (size_t)E;       // N+1
    int* start_out = start_in + n + 1;         // N+1
    int* gHistIn   = start_out + n + 1;        // 256
    int* gHistOut  = gHistIn + 256;            // 256
    int* cStartIn  = gHistOut + 256;           // NB+1
    int* cStartOut = cStartIn + NB + 1;        // NB+1
    int* cCurIn    = cStartOut + NB + 1;       // NB
    int* cCurOut   = cCurIn + NB;              // NB
    int* iwEnd     = cCurOut + NB;
    float* W12p    = (float*)iwEnd;            // HH*WPITCH = 5120 floats
    int* intAfter  = (int*)(W12p + HH * WPITCH);
    // partition scratch: both dirs alias the float region (dead during build)
    int* P_in  = (E <= 16 * (long long)n) ? (int*)ws            : intAfter;
    int* P_out = (E <= 16 * (long long)n) ? (int*)(ws + 16 * n) : intAfter + E;

    hipMemsetAsync(gHistIn, 0, 512 * sizeof(int), stream);

    const int tb = 256;
    int gbN  = (N + tb - 1) / tb;
    int gb8  = (int)((8 * n + tb - 1) / tb);
    int gb16 = (int)((16 * n + tb - 1) / tb);
    int gbC  = (E + CH - 1) / CH;

    // CSR build
    k_coarse <<<gbC, tb, 0, stream>>>(src, dst, gHistIn, gHistOut, NB, E);
    k_wt     <<<8, tb, 0, stream>>>(W1, W2, W12p);
    k_cscan  <<<1, 256, 0, stream>>>(gHistIn, gHistOut, cStartIn, cStartOut,
                                     cCurIn, cCurOut, NB, E);
    k_part2  <<<dim3(gbC, 2), tb, 0, stream>>>(src, dst, cCurIn, cCurOut,
                                               P_in, P_out, NB, E);
    k_fine2  <<<dim3(NB, 2), 512, 0, stream>>>(cStartIn, cStartOut, P_in, P_out,
                                               start_in, start_out, csr_in, csr_out, N);
    k_prep   <<<gbN, tb, 0, stream>>>(q, p, M, start_in, start_out,
                                      a_, b_, hmd, qn, out, N, E);

    // forward: agg1 = AggIn(a⊙q); ya = a ⊙ (relu((b⊙agg1)@W1+b1)@W2)
    k_agg16  <<<gb16, tb, 0, stream>>>(start_in, csr_in, qn, agg1, N);
    k_mlp_fwd<<<gb8, tb, 0, stream>>>(agg1, a_, b_, W12p, b1, ya, N);
    // h = b ⊙ AggIn(ya) + b2 + q
    k_h_agg16<<<gb16, tb, 0, stream>>>(start_in, csr_in, ya, b_, q, b2, hmd, N);
    // gravity gradient (two direction halves per node)
    k_gh16   <<<gb16, tb, 0, stream>>>(start_in, csr_in, start_out, csr_out,
                                       hmd, b_, grav, gh, bgh, N);
    // gq2 = AggOut(bgh); gz1b = b ⊙ ((a⊙(gq2@W2^T) ⊙ relu'(u)) @ W1^T)
    k_agg16  <<<gb16, tb, 0, stream>>>(start_out, csr_out, bgh, gq2, N);
    k_mlp_bwd<<<gb8, tb, 0, stream>>>(gq2, agg1, a_, b_, W12p, b1, gz1b, N);
    // dHdQ = gh + a ⊙ AggOut(gz1b)
    k_out_agg16<<<gb16, tb, 0, stream>>>(start_out, csr_out, gz1b, gh, a_, out, N);
}

// Round 8
// 370.377 us; speedup vs baseline: 1.3992x; 1.0062x over previous
//
#include <hip/hip_runtime.h>

#define DD 8
#define HH 256
#define CH 8192          // edges per chunk in coarse/partition kernels
#define PAYBITS 17       // N <= 131072
#define PAYMASK 0x1FFFF
#define WPITCH 20        // LDS weight row pitch (floats): conflict-free

// ============================ CSR construction ==============================
// Bucketed counting sort: coarse bucket = node >> 9, fine bin = node & 511.

__global__ void k_coarse(const int* __restrict__ src, const int* __restrict__ dst,
                         int* __restrict__ gHistIn, int* __restrict__ gHistOut,
                         int NB, int E) {
    __shared__ int hIn[256], hOut[256];
    if (threadIdx.x < 256) { hIn[threadIdx.x] = 0; hOut[threadIdx.x] = 0; }
    __syncthreads();
    int lo = blockIdx.x * CH;
    int hi = min(lo + CH, E);
    for (int i = lo + threadIdx.x; i < hi; i += blockDim.x) {
        atomicAdd(&hIn[dst[i] >> 9], 1);
        atomicAdd(&hOut[src[i] >> 9], 1);
    }
    __syncthreads();
    if (threadIdx.x < NB) {
        int ci = hIn[threadIdx.x], co = hOut[threadIdx.x];
        if (ci) atomicAdd(&gHistIn[threadIdx.x], ci);
        if (co) atomicAdd(&gHistOut[threadIdx.x], co);
    }
}

__global__ void k_cscan(const int* __restrict__ gHistIn, const int* __restrict__ gHistOut,
                        int* __restrict__ cStartIn, int* __restrict__ cStartOut,
                        int* __restrict__ cCurIn, int* __restrict__ cCurOut,
                        int NB, int E) {
    __shared__ int s[256];
#pragma unroll
    for (int dir = 0; dir < 2; dir++) {
        const int* gh = dir ? gHistOut : gHistIn;
        int* cs = dir ? cStartOut : cStartIn;
        int* cc = dir ? cCurOut : cCurIn;
        int v = (threadIdx.x < NB) ? gh[threadIdx.x] : 0;
        s[threadIdx.x] = v;
        __syncthreads();
        for (int off = 1; off < 256; off <<= 1) {
            int t = (threadIdx.x >= off) ? s[threadIdx.x - off] : 0;
            __syncthreads();
            s[threadIdx.x] += t;
            __syncthreads();
        }
        if (threadIdx.x < NB) {
            int ex = s[threadIdx.x] - v;
            cs[threadIdx.x] = ex;
            cc[threadIdx.x] = ex;
        }
        if (threadIdx.x == 0) cs[NB] = E;
        __syncthreads();
    }
}

// both directions in one launch: dir = blockIdx.y (0: key=dst pay=src -> in)
__global__ void k_part2(const int* __restrict__ src, const int* __restrict__ dst,
                        int* __restrict__ cCurIn, int* __restrict__ cCurOut,
                        int* __restrict__ P_in, int* __restrict__ P_out,
                        int NB, int E) {
    int dir = blockIdx.y;
    const int* key = dir ? src : dst;
    const int* pay = dir ? dst : src;
    int* cCur = dir ? cCurOut : cCurIn;
    int* P    = dir ? P_out   : P_in;
    __shared__ int h[256];
    if (threadIdx.x < 256) h[threadIdx.x] = 0;
    __syncthreads();
    int lo = blockIdx.x * CH;
    int hi = min(lo + CH, E);
    for (int i = lo + threadIdx.x; i < hi; i += blockDim.x)
        atomicAdd(&h[key[i] >> 9], 1);
    __syncthreads();
    if (threadIdx.x < NB) {
        int c = h[threadIdx.x];
        h[threadIdx.x] = c ? atomicAdd(&cCur[threadIdx.x], c) : 0;
    }
    __syncthreads();
    for (int i = lo + threadIdx.x; i < hi; i += blockDim.x) {
        int k = key[i];
        int pos = atomicAdd(&h[k >> 9], 1);
        P[pos] = ((k & 511) << PAYBITS) | pay[i];
    }
}

__launch_bounds__(512)
__global__ void k_fine2(const int* __restrict__ cStartIn, const int* __restrict__ cStartOut,
                        const int* __restrict__ P_in, const int* __restrict__ P_out,
                        int* __restrict__ start_in, int* __restrict__ start_out,
                        int* __restrict__ csr_in, int* __restrict__ csr_out, int N) {
    int dir = blockIdx.y;
    const int* cStart = dir ? cStartOut : cStartIn;
    const int* P      = dir ? P_out     : P_in;
    int* start        = dir ? start_out : start_in;
    int* csr          = dir ? csr_out   : csr_in;
    __shared__ int cnt[512], scn[512];
    int b = blockIdx.x;
    int lo = cStart[b], hi = cStart[b + 1];
    cnt[threadIdx.x] = 0;
    __syncthreads();
    for (int i = lo + threadIdx.x; i < hi; i += 512)
        atomicAdd(&cnt[P[i] >> PAYBITS], 1);
    __syncthreads();
    int own = cnt[threadIdx.x];
    scn[threadIdx.x] = own;
    __syncthreads();
    for (int off = 1; off < 512; off <<= 1) {
        int t = (threadIdx.x >= off) ? scn[threadIdx.x - off] : 0;
        __syncthreads();
        scn[threadIdx.x] += t;
        __syncthreads();
    }
    int base = lo + scn[threadIdx.x] - own;
    int node = (b << 9) + threadIdx.x;
    if (node < N) start[node] = base;
    cnt[threadIdx.x] = base;   // reuse as cursor
    __syncthreads();
    for (int i = lo + threadIdx.x; i < hi; i += 512) {
        int p = P[i];
        int pos = atomicAdd(&cnt[p >> PAYBITS], 1);
        csr[pos] = p & PAYMASK;
    }
}

// ==== weight pack (padded pitch 20): row j = {W1[:,j] (8), W2[j,:] (8), pad} =
__global__ void k_wt(const float* __restrict__ W1, const float* __restrict__ W2,
                     float* __restrict__ W12p) {
    int i = blockIdx.x * blockDim.x + threadIdx.x;
    if (i < HH * DD) {
        int j = i >> 3, d = i & 7;
        W12p[j * WPITCH + d]     = W1[d * HH + j];
        W12p[j * WPITCH + 8 + d] = W2[j * DD + d];
    }
}

// ===================== per-node prep (norms, masses, dHdP) ==================
__global__ void k_prep(const float* __restrict__ q, const float* __restrict__ p,
                       const float* __restrict__ M,
                       int* __restrict__ start_in, int* __restrict__ start_out,
                       float* __restrict__ a, float* __restrict__ b,
                       float* __restrict__ hmd, float* __restrict__ qn,
                       float* __restrict__ out, int N, int E) {
    int v = blockIdx.x * blockDim.x + threadIdx.x;
    if (blockIdx.x == 0 && threadIdx.x == 0) { start_in[N] = E; start_out[N] = E; }
    if (v >= N) return;
    int ei1 = (v + 1 < N) ? start_in[v + 1]  : E;
    int eo1 = (v + 1 < N) ? start_out[v + 1] : E;
    float din  = (float)(ei1 - start_in[v]);
    float dout = (float)(eo1 - start_out[v]);
    float av = 1.0f / sqrtf(dout > 0.f ? dout : 1.f);   // norm_src
    float bv = 1.0f / sqrtf(din  > 0.f ? din  : 1.f);   // norm_dst
    a[v] = av; b[v] = bv;
#pragma unroll
    for (int d = 0; d < DD; d++) {
        float m = M[(size_t)v * DD * DD + d * (DD + 1)];
        hmd[(size_t)v * 16 + 2 * d + 1] = m;
        qn[(size_t)v * DD + d] = av * q[(size_t)v * DD + d];
        out[(size_t)v * 2 * DD + DD + d] = p[(size_t)v * DD + d] / m;  // dHdP
    }
}

// ========== fused gather + MLP forward: 16 lanes/node, LDS weights ==========
// Phase 1: two 8-lane halves split the in-CSR edge list (stride 2).
// Phase 2: lane l16 handles hidden units j = 16c + l16 (c=0..15).
__launch_bounds__(256)
__global__ void k_fwd(const int* __restrict__ start, const int* __restrict__ csr,
                      const float* __restrict__ qn, const float* __restrict__ a,
                      const float* __restrict__ b,
                      const float* __restrict__ W12p, const float* __restrict__ b1,
                      float* __restrict__ agg1, float* __restrict__ ya, int N) {
    __shared__ float sW[HH * WPITCH];
    __shared__ float sb1[HH];
    for (int i = threadIdx.x; i < HH * WPITCH; i += 256) sW[i] = W12p[i];
    for (int i = threadIdx.x; i < HH; i += 256) sb1[i] = b1[i];
    __syncthreads();
    int t = blockIdx.x * 256 + threadIdx.x;
    int v = t >> 4, l16 = t & 15, sub = (t >> 3) & 1, d = t & 7;
    if (v >= N) return;
    // gather component d over in-CSR (half 'sub' takes every other edge)
    int e1 = start[v + 1];
    float s = 0.f;
    int e = start[v] + sub;
    for (; e + 6 < e1; e += 8) {
        int u0 = csr[e], u1 = csr[e + 2], u2 = csr[e + 4], u3 = csr[e + 6];
        float x0 = qn[(size_t)u0 * DD + d], x1 = qn[(size_t)u1 * DD + d];
        float x2 = qn[(size_t)u2 * DD + d], x3 = qn[(size_t)u3 * DD + d];
        s += (x0 + x1) + (x2 + x3);
    }
    for (; e < e1; e += 2) s += qn[(size_t)csr[e] * DD + d];
    s += __shfl_xor(s, 8);
    if (!sub) agg1[(size_t)v * DD + d] = s;   // saved for backward z-recompute
    float zl = b[v] * s;
    float z[DD];
#pragma unroll
    for (int k = 0; k < DD; k++) z[k] = __shfl(zl, k, 16);
    float acc[DD] = {0.f, 0.f, 0.f, 0.f, 0.f, 0.f, 0.f, 0.f};
    for (int c = 0; c < HH / 16; c += 2) {
        int j0 = (c << 4) | l16, j1 = j0 + 16;
        const float4* w0 = (const float4*)(sW + j0 * WPITCH);
        const float4* w1 = (const float4*)(sW + j1 * WPITCH);
        float4 wa0 = w0[0], wb0 = w0[1], va0 = w0[2], vb0 = w0[3];
        float4 wa1 = w1[0], wb1 = w1[1], va1 = w1[2], vb1 = w1[3];
        float ua0 = fmaf(z[1], wa0.y, fmaf(z[0], wa0.x, sb1[j0]));
        ua0 = fmaf(z[3], wa0.w, fmaf(z[2], wa0.z, ua0));
        float ub0 = fmaf(z[5], wb0.y, z[4] * wb0.x);
        ub0 = fmaf(z[7], wb0.w, fmaf(z[6], wb0.z, ub0));
        float ua1 = fmaf(z[1], wa1.y, fmaf(z[0], wa1.x, sb1[j1]));
        ua1 = fmaf(z[3], wa1.w, fmaf(z[2], wa1.z, ua1));
        float ub1 = fmaf(z[5], wb1.y, z[4] * wb1.x);
        ub1 = fmaf(z[7], wb1.w, fmaf(z[6], wb1.z, ub1));
        float h0 = fmaxf(ua0 + ub0, 0.f);
        float h1 = fmaxf(ua1 + ub1, 0.f);
        acc[0] = fmaf(h0, va0.x, acc[0]); acc[1] = fmaf(h0, va0.y, acc[1]);
        acc[2] = fmaf(h0, va0.z, acc[2]); acc[3] = fmaf(h0, va0.w, acc[3]);
        acc[4] = fmaf(h0, vb0.x, acc[4]); acc[5] = fmaf(h0, vb0.y, acc[5]);
        acc[6] = fmaf(h0, vb0.z, acc[6]); acc[7] = fmaf(h0, vb0.w, acc[7]);
        acc[0] = fmaf(h1, va1.x, acc[0]); acc[1] = fmaf(h1, va1.y, acc[1]);
        acc[2] = fmaf(h1, va1.z, acc[2]); acc[3] = fmaf(h1, va1.w, acc[3]);
        acc[4] = fmaf(h1, vb1.x, acc[4]); acc[5] = fmaf(h1, vb1.y, acc[5]);
        acc[6] = fmaf(h1, vb1.z, acc[6]); acc[7] = fmaf(h1, vb1.w, acc[7]);
    }
#pragma unroll
    for (int m = 1; m < 16; m <<= 1)
#pragma unroll
        for (int k = 0; k < DD; k++) acc[k] += __shfl_xor(acc[k], m);
    float yl = acc[0];
#pragma unroll
    for (int k = 1; k < DD; k++) yl = (d == k) ? acc[k] : yl;
    if (!sub) ya[(size_t)v * DD + d] = a[v] * yl;
}

// h = b*AggIn(ya) + b2 + q, into hmd paired slots
__global__ void k_h_agg16(const int* __restrict__ start, const int* __restrict__ csr,
                          const float* __restrict__ ya, const float* __restrict__ b,
                          const float* __restrict__ q, const float* __restrict__ b2,
                          float* __restrict__ hmd, int N) {
    int t = blockIdx.x * blockDim.x + threadIdx.x;
    int v = t >> 4, sub = (t >> 3) & 1, d = t & 7;
    if (v >= N) return;
    int e1 = start[v + 1];
    float s = 0.f;
    int e = start[v] + sub;
    for (; e + 6 < e1; e += 8) {
        int u0 = csr[e], u1 = csr[e + 2], u2 = csr[e + 4], u3 = csr[e + 6];
        float x0 = ya[(size_t)u0 * DD + d], x1 = ya[(size_t)u1 * DD + d];
        float x2 = ya[(size_t)u2 * DD + d], x3 = ya[(size_t)u3 * DD + d];
        s += (x0 + x1) + (x2 + x3);
    }
    for (; e < e1; e += 2) s += ya[(size_t)csr[e] * DD + d];
    s += __shfl_xor(s, 8);
    if (!sub)
        hmd[(size_t)v * 16 + 2 * d] = fmaf(b[v], s, b2[d] + q[(size_t)v * DD + d]);
}

// gravity gradient: 16 lanes/node, half 0 walks in-CSR, half 1 walks out-CSR.
// c = coef*S*rsqrt(e2)^3 replaces sqrt+divide.
__global__ void k_gh16(const int* __restrict__ start_in, const int* __restrict__ csr_in,
                       const int* __restrict__ start_out, const int* __restrict__ csr_out,
                       const float* __restrict__ hmd,
                       const float* __restrict__ b, const float* __restrict__ grav,
                       float* __restrict__ gh, float* __restrict__ bgh, int N) {
    int t = blockIdx.x * blockDim.x + threadIdx.x;
    int v = t >> 4, dir = (t >> 3) & 1, d = t & 7;
    if (v >= N) return;
    float2 self = *(const float2*)(hmd + (size_t)v * 16 + 2 * d);
    float hv = self.x, mv = self.y;
    float coef = -0.5f * grav[0];
    float acc = 0.f;
    const int* start = dir ? start_out : start_in;
    const int* csr   = dir ? csr_out   : csr_in;
    int e1 = start[v + 1];
    int e = start[v];
    for (; e + 3 < e1; e += 4) {
        int u0 = csr[e], u1 = csr[e + 1], u2 = csr[e + 2], u3 = csr[e + 3];
        float2 p0 = *(const float2*)(hmd + (size_t)u0 * 16 + 2 * d);
        float2 p1 = *(const float2*)(hmd + (size_t)u1 * 16 + 2 * d);
        float2 p2 = *(const float2*)(hmd + (size_t)u2 * 16 + 2 * d);
        float2 p3 = *(const float2*)(hmd + (size_t)u3 * 16 + 2 * d);
        float d0 = hv - p0.x, d1 = hv - p1.x, d2 = hv - p2.x, d3 = hv - p3.x;
        float e20 = d0 * d0, e21 = d1 * d1, e22 = d2 * d2, e23 = d3 * d3;
        float S0 = mv * p0.y, S1 = mv * p1.y, S2 = mv * p2.y, S3 = mv * p3.y;
        e20 += __shfl_xor(e20, 1); S0 += __shfl_xor(S0, 1);
        e21 += __shfl_xor(e21, 1); S1 += __shfl_xor(S1, 1);
        e22 += __shfl_xor(e22, 1); S2 += __shfl_xor(S2, 1);
        e23 += __shfl_xor(e23, 1); S3 += __shfl_xor(S3, 1);
        e20 += __shfl_xor(e20, 2); S0 += __shfl_xor(S0, 2);
        e21 += __shfl_xor(e21, 2); S1 += __shfl_xor(S1, 2);
        e22 += __shfl_xor(e22, 2); S2 += __shfl_xor(S2, 2);
        e23 += __shfl_xor(e23, 2); S3 += __shfl_xor(S3, 2);
        e20 += __shfl_xor(e20, 4); S0 += __shfl_xor(S0, 4);
        e21 += __shfl_xor(e21, 4); S1 += __shfl_xor(S1, 4);
        e22 += __shfl_xor(e22, 4); S2 += __shfl_xor(S2, 4);
        e23 += __shfl_xor(e23, 4); S3 += __shfl_xor(S3, 4);
        float r0 = rsqrtf(e20), r1 = rsqrtf(e21), r2 = rsqrtf(e22), r3 = rsqrtf(e23);
        float c0 = coef * S0 * r0 * r0 * r0;
        float c1 = coef * S1 * r1 * r1 * r1;
        float c2 = coef * S2 * r2 * r2 * r2;
        float c3 = coef * S3 * r3 * r3 * r3;
        acc = fmaf(c0, d0, acc); acc = fmaf(c1, d1, acc);
        acc = fmaf(c2, d2, acc); acc = fmaf(c3, d3, acc);
    }
    for (; e < e1; e++) {
        int u = csr[e];
        float2 pu = *(const float2*)(hmd + (size_t)u * 16 + 2 * d);
        float dif = hv - pu.x;
        float e2 = dif * dif;
        float S  = mv * pu.y;
        e2 += __shfl_xor(e2, 1); S += __shfl_xor(S, 1);
        e2 += __shfl_xor(e2, 2); S += __shfl_xor(S, 2);
        e2 += __shfl_xor(e2, 4); S += __shfl_xor(S, 4);
        float r = rsqrtf(e2);
        acc = fmaf(coef * S * r * r * r, dif, acc);
    }
    acc += __shfl_xor(acc, 8);   // combine the two direction halves
    if (!dir) {
        gh[(size_t)v * DD + d] = acc;
        bgh[(size_t)v * DD + d] = b[v] * acc;
    }
}

// ========== fused gather + MLP backward: 16 lanes/node, LDS weights =========
__launch_bounds__(256)
__global__ void k_bwd(const int* __restrict__ start, const int* __restrict__ csr,
                      const float* __restrict__ bgh, const float* __restrict__ agg1,
                      const float* __restrict__ a, const float* __restrict__ b,
                      const float* __restrict__ W12p, const float* __restrict__ b1,
                      float* __restrict__ gz1b, int N) {
    __shared__ float sW[HH * WPITCH];
    __shared__ float sb1[HH];
    for (int i = threadIdx.x; i < HH * WPITCH; i += 256) sW[i] = W12p[i];
    for (int i = threadIdx.x; i < HH; i += 256) sb1[i] = b1[i];
    __syncthreads();
    int t = blockIdx.x * 256 + threadIdx.x;
    int v = t >> 4, l16 = t & 15, sub = (t >> 3) & 1, d = t & 7;
    if (v >= N) return;
    // gather gq component d over out-CSR
    int e1 = start[v + 1];
    float s = 0.f;
    int e = start[v] + sub;
    for (; e + 6 < e1; e += 8) {
        int u0 = csr[e], u1 = csr[e + 2], u2 = csr[e + 4], u3 = csr[e + 6];
        float x0 = bgh[(size_t)u0 * DD + d], x1 = bgh[(size_t)u1 * DD + d];
        float x2 = bgh[(size_t)u2 * DD + d], x3 = bgh[(size_t)u3 * DD + d];
        s += (x0 + x1) + (x2 + x3);
    }
    for (; e < e1; e += 2) s += bgh[(size_t)csr[e] * DD + d];
    s += __shfl_xor(s, 8);
    float bv = b[v], av = a[v];
    float zl = bv * agg1[(size_t)v * DD + d];
    float z[DD], gq[DD];
#pragma unroll
    for (int k = 0; k < DD; k++) { z[k] = __shfl(zl, k, 16); gq[k] = __shfl(s, k, 16); }
    float gz[DD] = {0.f, 0.f, 0.f, 0.f, 0.f, 0.f, 0.f, 0.f};
    for (int c = 0; c < HH / 16; c += 2) {
        int j0 = (c << 4) | l16, j1 = j0 + 16;
        const float4* w0 = (const float4*)(sW + j0 * WPITCH);
        const float4* w1 = (const float4*)(sW + j1 * WPITCH);
        float4 wa0 = w0[0], wb0 = w0[1], va0 = w0[2], vb0 = w0[3];
        float4 wa1 = w1[0], wb1 = w1[1], va1 = w1[2], vb1 = w1[3];
        float ua0 = fmaf(z[1], wa0.y, fmaf(z[0], wa0.x, sb1[j0]));
        ua0 = fmaf(z[3], wa0.w, fmaf(z[2], wa0.z, ua0));
        float ub0 = fmaf(z[5], wb0.y, z[4] * wb0.x);
        ub0 = fmaf(z[7], wb0.w, fmaf(z[6], wb0.z, ub0));
        float ua1 = fmaf(z[1], wa1.y, fmaf(z[0], wa1.x, sb1[j1]));
        ua1 = fmaf(z[3], wa1.w, fmaf(z[2], wa1.z, ua1));
        float ub1 = fmaf(z[5], wb1.y, z[4] * wb1.x);
        ub1 = fmaf(z[7], wb1.w, fmaf(z[6], wb1.z, ub1));
        float u0 = ua0 + ub0, u1 = ua1 + ub1;
        float ga0 = fmaf(gq[1], va0.y, gq[0] * va0.x);
        ga0 = fmaf(gq[3], va0.w, fmaf(gq[2], va0.z, ga0));
        float gb0 = fmaf(gq[5], vb0.y, gq[4] * vb0.x);
        gb0 = fmaf(gq[7], vb0.w, fmaf(gq[6], vb0.z, gb0));
        float ga1 = fmaf(gq[1], va1.y, gq[0] * va1.x);
        ga1 = fmaf(gq[3], va1.w, fmaf(gq[2], va1.z, ga1));
        float gb1 = fmaf(gq[5], vb1.y, gq[4] * vb1.x);
        gb1 = fmaf(gq[7], vb1.w, fmaf(gq[6], vb1.z, gb1));
        float g0 = (u0 > 0.f) ? av * (ga0 + gb0) : 0.f;
        float g1 = (u1 > 0.f) ? av * (ga1 + gb1) : 0.f;
        gz[0] = fmaf(g0, wa0.x, gz[0]); gz[1] = fmaf(g0, wa0.y, gz[1]);
        gz[2] = fmaf(g0, wa0.z, gz[2]); gz[3] = fmaf(g0, wa0.w, gz[3]);
        gz[4] = fmaf(g0, wb0.x, gz[4]); gz[5] = fmaf(g0, wb0.y, gz[5]);
        gz[6] = fmaf(g0, wb0.z, gz[6]); gz[7] = fmaf(g0, wb0.w, gz[7]);
        gz[0] = fmaf(g1, wa1.x, gz[0]); gz[1] = fmaf(g1, wa1.y, gz[1]);
        gz[2] = fmaf(g1, wa1.z, gz[2]); gz[3] = fmaf(g1, wa1.w, gz[3]);
        gz[4] = fmaf(g1, wb1.x, gz[4]); gz[5] = fmaf(g1, wb1.y, gz[5]);
        gz[6] = fmaf(g1, wb1.z, gz[6]); gz[7] = fmaf(g1, wb1.w, gz[7]);
    }
#pragma unroll
    for (int m = 1; m < 16; m <<= 1)
#pragma unroll
        for (int k = 0; k < DD; k++) gz[k] += __shfl_xor(gz[k], m);
    float out_l = gz[0];
#pragma unroll
    for (int k = 1; k < DD; k++) out_l = (d == k) ? gz[k] : out_l;
    if (!sub) gz1b[(size_t)v * DD + d] = bv * out_l;
}

// out[:, :D] = gh + a * AggOut(gz1b)
__global__ void k_out_agg16(const int* __restrict__ start, const int* __restrict__ csr,
                            const float* __restrict__ gz1b, const float* __restrict__ gh,
                            const float* __restrict__ a, float* __restrict__ out, int N) {
    int t = blockIdx.x * blockDim.x + threadIdx.x;
    int v = t >> 4, sub = (t >> 3) & 1, d = t & 7;
    if (v >= N) return;
    int e1 = start[v + 1];
    float s = 0.f;
    int e = start[v] + sub;
    for (; e + 6 < e1; e += 8) {
        int u0 = csr[e], u1 = csr[e + 2], u2 = csr[e + 4], u3 = csr[e + 6];
        float x0 = gz1b[(size_t)u0 * DD + d], x1 = gz1b[(size_t)u1 * DD + d];
        float x2 = gz1b[(size_t)u2 * DD + d], x3 = gz1b[(size_t)u3 * DD + d];
        s += (x0 + x1) + (x2 + x3);
    }
    for (; e < e1; e += 2) s += gz1b[(size_t)csr[e] * DD + d];
    s += __shfl_xor(s, 8);
    if (!sub)
        out[(size_t)v * 2 * DD + d] = fmaf(a[v], s, gh[(size_t)v * DD + d]);
}

// ============================== launch =====================================

extern "C" void kernel_launch(void* const* d_in, const int* in_sizes, int n_in,
                              void* d_out, int out_size, void* d_ws, size_t ws_size,
                              hipStream_t stream) {
    const float* q    = (const float*)d_in[0];
    const float* p    = (const float*)d_in[1];
    const float* M    = (const float*)d_in[2];
    const int*   src  = (const int*)d_in[3];
    const int*   dst  = (const int*)d_in[4];
    const float* W1   = (const float*)d_in[5];
    const float* b1   = (const float*)d_in[6];
    const float* W2   = (const float*)d_in[7];
    const float* b2   = (const float*)d_in[8];
    const float* grav = (const float*)d_in[9];
    float* out = (float*)d_out;

    int N = in_sizes[0] / DD;
    int E = in_sizes[3];
    size_t n = (size_t)N;
    int NB = (N + 511) >> 9;

    // ---- float region (58N floats) ----
    float* ws   = (float*)d_ws;
    float* a_   = ws;             // N
    float* b_   = ws + n;         // N
    float* qn   = ws + 2  * n;    // 8N
    float* agg1 = ws + 10 * n;    // 8N  (stored by fwd, read by bwd)
    float* ya   = ws + 18 * n;    // 8N  (reused as gz1b)
    float* hmd  = ws + 26 * n;    // 16N (pairs: h at 2d, md at 2d+1)
    float* gh   = ws + 42 * n;    // 8N
    float* bgh  = ws + 50 * n;    // 8N
    float* gz1b = ya;

    // ---- int region ----
    int* iw        = (int*)(ws + 58 * n);
    int* csr_in    = iw;                       // E
    int* csr_out   = iw + (size_t)E;           // E
    int* start_in  = iw + 2 * (size_t)E;       // N+1
    int* start_out = start_in + n + 1;         // N+1
    int* gHistIn   = start_out + n + 1;        // 256
    int* gHistOut  = gHistIn + 256;            // 256
    int* cStartIn  = gHistOut + 256;           // NB+1
    int* cStartOut = cStartIn + NB + 1;        // NB+1
    int* cCurIn    = cStartOut + NB + 1;       // NB
    int* cCurOut   = cCurIn + NB;              // NB
    int* iwEnd     = cCurOut + NB;
    float* W12p    = (float*)iwEnd;            // HH*WPITCH = 5120 floats
    int* intAfter  = (int*)(W12p + HH * WPITCH);
    // partition scratch: both dirs alias the float region (dead during build)
    int* P_in  = (E <= 16 * (long long)n) ? (int*)ws            : intAfter;
    int* P_out = (E <= 16 * (long long)n) ? (int*)(ws + 16 * n) : intAfter + E;

    hipMemsetAsync(gHistIn, 0, 512 * sizeof(int), stream);

    const int tb = 256;
    int gbN  = (N + tb - 1) / tb;
    int gb16 = (int)((16 * n + tb - 1) / tb);
    int gbC  = (E + CH - 1) / CH;

    // CSR build
    k_coarse <<<gbC, tb, 0, stream>>>(src, dst, gHistIn, gHistOut, NB, E);
    k_wt     <<<8, tb, 0, stream>>>(W1, W2, W12p);
    k_cscan  <<<1, 256, 0, stream>>>(gHistIn, gHistOut, cStartIn, cStartOut,
                                     cCurIn, cCurOut, NB, E);
    k_part2  <<<dim3(gbC, 2), tb, 0, stream>>>(src, dst, cCurIn, cCurOut,
                                               P_in, P_out, NB, E);
    k_fine2  <<<dim3(NB, 2), 512, 0, stream>>>(cStartIn, cStartOut, P_in, P_out,
                                               start_in, start_out, csr_in, csr_out, N);
    k_prep   <<<gbN, tb, 0, stream>>>(q, p, M, start_in, start_out,
                                      a_, b_, hmd, qn, out, N, E);

    // forward (fused gather+MLP): agg1 = AggIn(a⊙q); ya = a⊙(relu((b⊙agg1)@W1+b1)@W2)
    k_fwd    <<<gb16, tb, 0, stream>>>(start_in, csr_in, qn, a_, b_,
                                       W12p, b1, agg1, ya, N);
    // h = b ⊙ AggIn(ya) + b2 + q
    k_h_agg16<<<gb16, tb, 0, stream>>>(start_in, csr_in, ya, b_, q, b2, hmd, N);
    // gravity gradient (two direction halves per node, rsqrt path)
    k_gh16   <<<gb16, tb, 0, stream>>>(start_in, csr_in, start_out, csr_out,
                                       hmd, b_, grav, gh, bgh, N);
    // backward (fused gather+MLP): gq2 = AggOut(bgh); gz1b = b⊙((a⊙(gq2@W2^T)⊙relu')@W1^T)
    k_bwd    <<<gb16, tb, 0, stream>>>(start_out, csr_out, bgh, agg1, a_, b_,
                                       W12p, b1, gz1b, N);
    // dHdQ = gh + a ⊙ AggOut(gz1b)
    k_out_agg16<<<gb16, tb, 0, stream>>>(start_out, csr_out, gz1b, gh, a_, out, N);
}

// Round 9
// 370.308 us; speedup vs baseline: 1.3994x; 1.0002x over previous
//
#include <hip/hip_runtime.h>

#define DD 8
#define HH 256
#define CH 8192          // edges per chunk in coarse/partition kernels
#define PAYBITS 17       // N <= 131072
#define PAYMASK 0x1FFFF
#define WPITCH 20        // LDS weight row pitch (floats): conflict-free

// ============================ CSR construction ==============================
// Bucketed counting sort: coarse bucket = node >> 9, fine bin = node & 511.

__global__ void k_coarse(const int* __restrict__ src, const int* __restrict__ dst,
                         int* __restrict__ gHistIn, int* __restrict__ gHistOut,
                         int NB, int E) {
    __shared__ int hIn[256], hOut[256];
    if (threadIdx.x < 256) { hIn[threadIdx.x] = 0; hOut[threadIdx.x] = 0; }
    __syncthreads();
    int lo = blockIdx.x * CH;
    int hi = min(lo + CH, E);
    for (int i = lo + threadIdx.x; i < hi; i += blockDim.x) {
        atomicAdd(&hIn[dst[i] >> 9], 1);
        atomicAdd(&hOut[src[i] >> 9], 1);
    }
    __syncthreads();
    if (threadIdx.x < NB) {
        int ci = hIn[threadIdx.x], co = hOut[threadIdx.x];
        if (ci) atomicAdd(&gHistIn[threadIdx.x], ci);
        if (co) atomicAdd(&gHistOut[threadIdx.x], co);
    }
}

__global__ void k_cscan(const int* __restrict__ gHistIn, const int* __restrict__ gHistOut,
                        int* __restrict__ cStartIn, int* __restrict__ cStartOut,
                        int* __restrict__ cCurIn, int* __restrict__ cCurOut,
                        int NB, int E) {
    __shared__ int s[256];
#pragma unroll
    for (int dir = 0; dir < 2; dir++) {
        const int* gh = dir ? gHistOut : gHistIn;
        int* cs = dir ? cStartOut : cStartIn;
        int* cc = dir ? cCurOut : cCurIn;
        int v = (threadIdx.x < NB) ? gh[threadIdx.x] : 0;
        s[threadIdx.x] = v;
        __syncthreads();
        for (int off = 1; off < 256; off <<= 1) {
            int t = (threadIdx.x >= off) ? s[threadIdx.x - off] : 0;
            __syncthreads();
            s[threadIdx.x] += t;
            __syncthreads();
        }
        if (threadIdx.x < NB) {
            int ex = s[threadIdx.x] - v;
            cs[threadIdx.x] = ex;
            cc[threadIdx.x] = ex;
        }
        if (threadIdx.x == 0) cs[NB] = E;
        __syncthreads();
    }
}

// both directions in one launch: dir = blockIdx.y (0: key=dst pay=src -> in)
__global__ void k_part2(const int* __restrict__ src, const int* __restrict__ dst,
                        int* __restrict__ cCurIn, int* __restrict__ cCurOut,
                        int* __restrict__ P_in, int* __restrict__ P_out,
                        int NB, int E) {
    int dir = blockIdx.y;
    const int* key = dir ? src : dst;
    const int* pay = dir ? dst : src;
    int* cCur = dir ? cCurOut : cCurIn;
    int* P    = dir ? P_out   : P_in;
    __shared__ int h[256];
    if (threadIdx.x < 256) h[threadIdx.x] = 0;
    __syncthreads();
    int lo = blockIdx.x * CH;
    int hi = min(lo + CH, E);
    for (int i = lo + threadIdx.x; i < hi; i += blockDim.x)
        atomicAdd(&h[key[i] >> 9], 1);
    __syncthreads();
    if (threadIdx.x < NB) {
        int c = h[threadIdx.x];
        h[threadIdx.x] = c ? atomicAdd(&cCur[threadIdx.x], c) : 0;
    }
    __syncthreads();
    for (int i = lo + threadIdx.x; i < hi; i += blockDim.x) {
        int k = key[i];
        int pos = atomicAdd(&h[k >> 9], 1);
        P[pos] = ((k & 511) << PAYBITS) | pay[i];
    }
}

__launch_bounds__(512)
__global__ void k_fine2(const int* __restrict__ cStartIn, const int* __restrict__ cStartOut,
                        const int* __restrict__ P_in, const int* __restrict__ P_out,
                        int* __restrict__ start_in, int* __restrict__ start_out,
                        int* __restrict__ csr_in, int* __restrict__ csr_out, int N) {
    int dir = blockIdx.y;
    const int* cStart = dir ? cStartOut : cStartIn;
    const int* P      = dir ? P_out     : P_in;
    int* start        = dir ? start_out : start_in;
    int* csr          = dir ? csr_out   : csr_in;
    __shared__ int cnt[512], scn[512];
    int b = blockIdx.x;
    int lo = cStart[b], hi = cStart[b + 1];
    cnt[threadIdx.x] = 0;
    __syncthreads();
    for (int i = lo + threadIdx.x; i < hi; i += 512)
        atomicAdd(&cnt[P[i] >> PAYBITS], 1);
    __syncthreads();
    int own = cnt[threadIdx.x];
    scn[threadIdx.x] = own;
    __syncthreads();
    for (int off = 1; off < 512; off <<= 1) {
        int t = (threadIdx.x >= off) ? scn[threadIdx.x - off] : 0;
        __syncthreads();
        scn[threadIdx.x] += t;
        __syncthreads();
    }
    int base = lo + scn[threadIdx.x] - own;
    int node = (b << 9) + threadIdx.x;
    if (node < N) start[node] = base;
    cnt[threadIdx.x] = base;   // reuse as cursor
    __syncthreads();
    for (int i = lo + threadIdx.x; i < hi; i += 512) {
        int p = P[i];
        int pos = atomicAdd(&cnt[p >> PAYBITS], 1);
        csr[pos] = p & PAYMASK;
    }
}

// ========== per-node prep (norms, masses, dHdP) + weight pack ===============
__global__ void k_prep(const float* __restrict__ q, const float* __restrict__ p,
                       const float* __restrict__ M,
                       const float* __restrict__ W1, const float* __restrict__ W2,
                       float* __restrict__ W12p,
                       int* __restrict__ start_in, int* __restrict__ start_out,
                       float* __restrict__ a, float* __restrict__ b,
                       float* __restrict__ hmd, float* __restrict__ qn,
                       float* __restrict__ out, int N, int E) {
    int t = blockIdx.x * blockDim.x + threadIdx.x;
    if (t == 0) { start_in[N] = E; start_out[N] = E; }
    if (t < HH * DD) {                      // fold of former k_wt
        int j = t >> 3, dd = t & 7;
        W12p[j * WPITCH + dd]     = W1[dd * HH + j];
        W12p[j * WPITCH + 8 + dd] = W2[j * DD + dd];
    }
    int v = t;
    if (v >= N) return;
    int ei1 = (v + 1 < N) ? start_in[v + 1]  : E;
    int eo1 = (v + 1 < N) ? start_out[v + 1] : E;
    float din  = (float)(ei1 - start_in[v]);
    float dout = (float)(eo1 - start_out[v]);
    float av = 1.0f / sqrtf(dout > 0.f ? dout : 1.f);   // norm_src
    float bv = 1.0f / sqrtf(din  > 0.f ? din  : 1.f);   // norm_dst
    a[v] = av; b[v] = bv;
#pragma unroll
    for (int d = 0; d < DD; d++) {
        float m = M[(size_t)v * DD * DD + d * (DD + 1)];
        hmd[(size_t)v * 16 + 2 * d + 1] = m;
        qn[(size_t)v * DD + d] = av * q[(size_t)v * DD + d];
        out[(size_t)v * 2 * DD + DD + d] = p[(size_t)v * DD + d] / m;  // dHdP
    }
}

// ---- deep-unrolled gather helper: sum x[csr[lo..hi)][d], 8 outstanding -----
static __device__ __forceinline__
float gather_sum(const int* __restrict__ csr, const float* __restrict__ x,
                 int lo, int hi, int d) {
    float s = 0.f;
    int e = lo;
    for (; e + 7 < hi; e += 8) {
        int u[8];
#pragma unroll
        for (int i = 0; i < 8; i++) u[i] = csr[e + i];
        float xv[8];
#pragma unroll
        for (int i = 0; i < 8; i++) xv[i] = x[(size_t)u[i] * DD + d];
        s += ((xv[0] + xv[1]) + (xv[2] + xv[3])) + ((xv[4] + xv[5]) + (xv[6] + xv[7]));
    }
    for (; e + 3 < hi; e += 4) {
        int u0 = csr[e], u1 = csr[e + 1], u2 = csr[e + 2], u3 = csr[e + 3];
        s += (x[(size_t)u0 * DD + d] + x[(size_t)u1 * DD + d])
           + (x[(size_t)u2 * DD + d] + x[(size_t)u3 * DD + d]);
    }
    for (; e < hi; e++) s += x[(size_t)csr[e] * DD + d];
    return s;
}

// ========== fused gather + MLP forward: 16 lanes/node, LDS weights ==========
__launch_bounds__(256)
__global__ void k_fwd(const int* __restrict__ start, const int* __restrict__ csr,
                      const float* __restrict__ qn, const float* __restrict__ a,
                      const float* __restrict__ b,
                      const float* __restrict__ W12p, const float* __restrict__ b1,
                      float* __restrict__ agg1, float* __restrict__ ya, int N) {
    __shared__ float sW[HH * WPITCH];
    __shared__ float sb1[HH];
    for (int i = threadIdx.x; i < HH * WPITCH; i += 256) sW[i] = W12p[i];
    for (int i = threadIdx.x; i < HH; i += 256) sb1[i] = b1[i];
    __syncthreads();
    int t = blockIdx.x * 256 + threadIdx.x;
    int v = t >> 4, l16 = t & 15, sub = (t >> 3) & 1, d = t & 7;
    if (v >= N) return;
    int e0 = start[v], e1 = start[v + 1];
    int mid = e0 + ((e1 - e0) >> 1);
    float s = gather_sum(csr, qn, sub ? mid : e0, sub ? e1 : mid, d);
    s += __shfl_xor(s, 8);
    if (!sub) agg1[(size_t)v * DD + d] = s;   // saved for backward z-recompute
    float zl = b[v] * s;
    float z[DD];
#pragma unroll
    for (int k = 0; k < DD; k++) z[k] = __shfl(zl, k, 16);
    float acc[DD] = {0.f, 0.f, 0.f, 0.f, 0.f, 0.f, 0.f, 0.f};
    for (int c = 0; c < HH / 16; c += 2) {
        int j0 = (c << 4) | l16, j1 = j0 + 16;
        const float4* w0 = (const float4*)(sW + j0 * WPITCH);
        const float4* w1 = (const float4*)(sW + j1 * WPITCH);
        float4 wa0 = w0[0], wb0 = w0[1], va0 = w0[2], vb0 = w0[3];
        float4 wa1 = w1[0], wb1 = w1[1], va1 = w1[2], vb1 = w1[3];
        float ua0 = fmaf(z[1], wa0.y, fmaf(z[0], wa0.x, sb1[j0]));
        ua0 = fmaf(z[3], wa0.w, fmaf(z[2], wa0.z, ua0));
        float ub0 = fmaf(z[5], wb0.y, z[4] * wb0.x);
        ub0 = fmaf(z[7], wb0.w, fmaf(z[6], wb0.z, ub0));
        float ua1 = fmaf(z[1], wa1.y, fmaf(z[0], wa1.x, sb1[j1]));
        ua1 = fmaf(z[3], wa1.w, fmaf(z[2], wa1.z, ua1));
        float ub1 = fmaf(z[5], wb1.y, z[4] * wb1.x);
        ub1 = fmaf(z[7], wb1.w, fmaf(z[6], wb1.z, ub1));
        float h0 = fmaxf(ua0 + ub0, 0.f);
        float h1 = fmaxf(ua1 + ub1, 0.f);
        acc[0] = fmaf(h0, va0.x, acc[0]); acc[1] = fmaf(h0, va0.y, acc[1]);
        acc[2] = fmaf(h0, va0.z, acc[2]); acc[3] = fmaf(h0, va0.w, acc[3]);
        acc[4] = fmaf(h0, vb0.x, acc[4]); acc[5] = fmaf(h0, vb0.y, acc[5]);
        acc[6] = fmaf(h0, vb0.z, acc[6]); acc[7] = fmaf(h0, vb0.w, acc[7]);
        acc[0] = fmaf(h1, va1.x, acc[0]); acc[1] = fmaf(h1, va1.y, acc[1]);
        acc[2] = fmaf(h1, va1.z, acc[2]); acc[3] = fmaf(h1, va1.w, acc[3]);
        acc[4] = fmaf(h1, vb1.x, acc[4]); acc[5] = fmaf(h1, vb1.y, acc[5]);
        acc[6] = fmaf(h1, vb1.z, acc[6]); acc[7] = fmaf(h1, vb1.w, acc[7]);
    }
#pragma unroll
    for (int m = 1; m < 16; m <<= 1)
#pragma unroll
        for (int k = 0; k < DD; k++) acc[k] += __shfl_xor(acc[k], m);
    float yl = acc[0];
#pragma unroll
    for (int k = 1; k < DD; k++) yl = (d == k) ? acc[k] : yl;
    if (!sub) ya[(size_t)v * DD + d] = a[v] * yl;
}

// h = b*AggIn(ya) + b2 + q, into hmd paired slots
__global__ void k_h_agg16(const int* __restrict__ start, const int* __restrict__ csr,
                          const float* __restrict__ ya, const float* __restrict__ b,
                          const float* __restrict__ q, const float* __restrict__ b2,
                          float* __restrict__ hmd, int N) {
    int t = blockIdx.x * blockDim.x + threadIdx.x;
    int v = t >> 4, sub = (t >> 3) & 1, d = t & 7;
    if (v >= N) return;
    int e0 = start[v], e1 = start[v + 1];
    int mid = e0 + ((e1 - e0) >> 1);
    float s = gather_sum(csr, ya, sub ? mid : e0, sub ? e1 : mid, d);
    s += __shfl_xor(s, 8);
    if (!sub)
        hmd[(size_t)v * 16 + 2 * d] = fmaf(b[v], s, b2[d] + q[(size_t)v * DD + d]);
}

// gravity gradient: 16 lanes/node (dir halves), unroll-8, rsqrt path
__global__ void k_gh16(const int* __restrict__ start_in, const int* __restrict__ csr_in,
                       const int* __restrict__ start_out, const int* __restrict__ csr_out,
                       const float* __restrict__ hmd,
                       const float* __restrict__ b, const float* __restrict__ grav,
                       float* __restrict__ gh, float* __restrict__ bgh, int N) {
    int t = blockIdx.x * blockDim.x + threadIdx.x;
    int v = t >> 4, dir = (t >> 3) & 1, d = t & 7;
    if (v >= N) return;
    float2 self = *(const float2*)(hmd + (size_t)v * 16 + 2 * d);
    float hv = self.x, mv = self.y;
    float coef = -0.5f * grav[0];
    float acc = 0.f;
    const int* start = dir ? start_out : start_in;
    const int* csr   = dir ? csr_out   : csr_in;
    int e1 = start[v + 1];
    int e = start[v];
    for (; e + 7 < e1; e += 8) {
        int u[8];
#pragma unroll
        for (int i = 0; i < 8; i++) u[i] = csr[e + i];
        float2 pp[8];
#pragma unroll
        for (int i = 0; i < 8; i++)
            pp[i] = *(const float2*)(hmd + (size_t)u[i] * 16 + 2 * d);
        float df[8], ee[8], SS[8];
#pragma unroll
        for (int i = 0; i < 8; i++) {
            df[i] = hv - pp[i].x;
            ee[i] = df[i] * df[i];
            SS[i] = mv * pp[i].y;
        }
#pragma unroll
        for (int m = 1; m < 8; m <<= 1)
#pragma unroll
            for (int i = 0; i < 8; i++) {
                ee[i] += __shfl_xor(ee[i], m);
                SS[i] += __shfl_xor(SS[i], m);
            }
#pragma unroll
        for (int i = 0; i < 8; i++) {
            float r = rsqrtf(ee[i]);
            acc = fmaf(coef * SS[i] * r * r * r, df[i], acc);
        }
    }
    for (; e + 3 < e1; e += 4) {
        int u[4];
#pragma unroll
        for (int i = 0; i < 4; i++) u[i] = csr[e + i];
        float2 pp[4];
#pragma unroll
        for (int i = 0; i < 4; i++)
            pp[i] = *(const float2*)(hmd + (size_t)u[i] * 16 + 2 * d);
        float df[4], ee[4], SS[4];
#pragma unroll
        for (int i = 0; i < 4; i++) {
            df[i] = hv - pp[i].x;
            ee[i] = df[i] * df[i];
            SS[i] = mv * pp[i].y;
        }
#pragma unroll
        for (int m = 1; m < 8; m <<= 1)
#pragma unroll
            for (int i = 0; i < 4; i++) {
                ee[i] += __shfl_xor(ee[i], m);
                SS[i] += __shfl_xor(SS[i], m);
            }
#pragma unroll
        for (int i = 0; i < 4; i++) {
            float r = rsqrtf(ee[i]);
            acc = fmaf(coef * SS[i] * r * r * r, df[i], acc);
        }
    }
    for (; e < e1; e++) {
        int u = csr[e];
        float2 pu = *(const float2*)(hmd + (size_t)u * 16 + 2 * d);
        float dif = hv - pu.x;
        float e2 = dif * dif;
        float S  = mv * pu.y;
        e2 += __shfl_xor(e2, 1); S += __shfl_xor(S, 1);
        e2 += __shfl_xor(e2, 2); S += __shfl_xor(S, 2);
        e2 += __shfl_xor(e2, 4); S += __shfl_xor(S, 4);
        float r = rsqrtf(e2);
        acc = fmaf(coef * S * r * r * r, dif, acc);
    }
    acc += __shfl_xor(acc, 8);   // combine the two direction halves
    if (!dir) {
        gh[(size_t)v * DD + d] = acc;
        bgh[(size_t)v * DD + d] = b[v] * acc;
    }
}

// ========== fused gather + MLP backward: 16 lanes/node, LDS weights =========
__launch_bounds__(256)
__global__ void k_bwd(const int* __restrict__ start, const int* __restrict__ csr,
                      const float* __restrict__ bgh, const float* __restrict__ agg1,
                      const float* __restrict__ a, const float* __restrict__ b,
                      const float* __restrict__ W12p, const float* __restrict__ b1,
                      float* __restrict__ gz1b, int N) {
    __shared__ float sW[HH * WPITCH];
    __shared__ float sb1[HH];
    for (int i = threadIdx.x; i < HH * WPITCH; i += 256) sW[i] = W12p[i];
    for (int i = threadIdx.x; i < HH; i += 256) sb1[i] = b1[i];
    __syncthreads();
    int t = blockIdx.x * 256 + threadIdx.x;
    int v = t >> 4, l16 = t & 15, sub = (t >> 3) & 1, d = t & 7;
    if (v >= N) return;
    int e0 = start[v], e1 = start[v + 1];
    int mid = e0 + ((e1 - e0) >> 1);
    float s = gather_sum(csr, bgh, sub ? mid : e0, sub ? e1 : mid, d);
    s += __shfl_xor(s, 8);
    float bv = b[v], av = a[v];
    float zl = bv * agg1[(size_t)v * DD + d];
    float z[DD], gq[DD];
#pragma unroll
    for (int k = 0; k < DD; k++) { z[k] = __shfl(zl, k, 16); gq[k] = __shfl(s, k, 16); }
    float gz[DD] = {0.f, 0.f, 0.f, 0.f, 0.f, 0.f, 0.f, 0.f};
    for (int c = 0; c < HH / 16; c += 2) {
        int j0 = (c << 4) | l16, j1 = j0 + 16;
        const float4* w0 = (const float4*)(sW + j0 * WPITCH);
        const float4* w1 = (const float4*)(sW + j1 * WPITCH);
        float4 wa0 = w0[0], wb0 = w0[1], va0 = w0[2], vb0 = w0[3];
        float4 wa1 = w1[0], wb1 = w1[1], va1 = w1[2], vb1 = w1[3];
        float ua0 = fmaf(z[1], wa0.y, fmaf(z[0], wa0.x, sb1[j0]));
        ua0 = fmaf(z[3], wa0.w, fmaf(z[2], wa0.z, ua0));
        float ub0 = fmaf(z[5], wb0.y, z[4] * wb0.x);
        ub0 = fmaf(z[7], wb0.w, fmaf(z[6], wb0.z, ub0));
        float ua1 = fmaf(z[1], wa1.y, fmaf(z[0], wa1.x, sb1[j1]));
        ua1 = fmaf(z[3], wa1.w, fmaf(z[2], wa1.z, ua1));
        float ub1 = fmaf(z[5], wb1.y, z[4] * wb1.x);
        ub1 = fmaf(z[7], wb1.w, fmaf(z[6], wb1.z, ub1));
        float u0 = ua0 + ub0, u1 = ua1 + ub1;
        float ga0 = fmaf(gq[1], va0.y, gq[0] * va0.x);
        ga0 = fmaf(gq[3], va0.w, fmaf(gq[2], va0.z, ga0));
        float gb0 = fmaf(gq[5], vb0.y, gq[4] * vb0.x);
        gb0 = fmaf(gq[7], vb0.w, fmaf(gq[6], vb0.z, gb0));
        float ga1 = fmaf(gq[1], va1.y, gq[0] * va1.x);
        ga1 = fmaf(gq[3], va1.w, fmaf(gq[2], va1.z, ga1));
        float gb1 = fmaf(gq[5], vb1.y, gq[4] * vb1.x);
        gb1 = fmaf(gq[7], vb1.w, fmaf(gq[6], vb1.z, gb1));
        float g0 = (u0 > 0.f) ? av * (ga0 + gb0) : 0.f;
        float g1 = (u1 > 0.f) ? av * (ga1 + gb1) : 0.f;
        gz[0] = fmaf(g0, wa0.x, gz[0]); gz[1] = fmaf(g0, wa0.y, gz[1]);
        gz[2] = fmaf(g0, wa0.z, gz[2]); gz[3] = fmaf(g0, wa0.w, gz[3]);
        gz[4] = fmaf(g0, wb0.x, gz[4]); gz[5] = fmaf(g0, wb0.y, gz[5]);
        gz[6] = fmaf(g0, wb0.z, gz[6]); gz[7] = fmaf(g0, wb0.w, gz[7]);
        gz[0] = fmaf(g1, wa1.x, gz[0]); gz[1] = fmaf(g1, wa1.y, gz[1]);
        gz[2] = fmaf(g1, wa1.z, gz[2]); gz[3] = fmaf(g1, wa1.w, gz[3]);
        gz[4] = fmaf(g1, wb1.x, gz[4]); gz[5] = fmaf(g1, wb1.y, gz[5]);
        gz[6] = fmaf(g1, wb1.z, gz[6]); gz[7] = fmaf(g1, wb1.w, gz[7]);
    }
#pragma unroll
    for (int m = 1; m < 16; m <<= 1)
#pragma unroll
        for (int k = 0; k < DD; k++) gz[k] += __shfl_xor(gz[k], m);
    float out_l = gz[0];
#pragma unroll
    for (int k = 1; k < DD; k++) out_l = (d == k) ? gz[k] : out_l;
    if (!sub) gz1b[(size_t)v * DD + d] = bv * out_l;
}

// out[:, :D] = gh + a * AggOut(gz1b)
__global__ void k_out_agg16(const int* __restrict__ start, const int* __restrict__ csr,
                            const float* __restrict__ gz1b, const float* __restrict__ gh,
                            const float* __restrict__ a, float* __restrict__ out, int N) {
    int t = blockIdx.x * blockDim.x + threadIdx.x;
    int v = t >> 4, sub = (t >> 3) & 1, d = t & 7;
    if (v >= N) return;
    int e0 = start[v], e1 = start[v + 1];
    int mid = e0 + ((e1 - e0) >> 1);
    float s = gather_sum(csr, gz1b, sub ? mid : e0, sub ? e1 : mid, d);
    s += __shfl_xor(s, 8);
    if (!sub)
        out[(size_t)v * 2 * DD + d] = fmaf(a[v], s, gh[(size_t)v * DD + d]);
}

// ============================== launch =====================================

extern "C" void kernel_launch(void* const* d_in, const int* in_sizes, int n_in,
                              void* d_out, int out_size, void* d_ws, size_t ws_size,
                              hipStream_t stream) {
    const float* q    = (const float*)d_in[0];
    const float* p    = (const float*)d_in[1];
    const float* M    = (const float*)d_in[2];
    const int*   src  = (const int*)d_in[3];
    const int*   dst  = (const int*)d_in[4];
    const float* W1   = (const float*)d_in[5];
    const float* b1   = (const float*)d_in[6];
    const float* W2   = (const float*)d_in[7];
    const float* b2   = (const float*)d_in[8];
    const float* grav = (const float*)d_in[9];
    float* out = (float*)d_out;

    int N = in_sizes[0] / DD;
    int E = in_sizes[3];
    size_t n = (size_t)N;
    int NB = (N + 511) >> 9;

    // ---- float region (58N floats) ----
    float* ws   = (float*)d_ws;
    float* a_   = ws;             // N
    float* b_   = ws + n;         // N
    float* qn   = ws + 2  * n;    // 8N
    float* agg1 = ws + 10 * n;    // 8N  (stored by fwd, read by bwd)
    float* ya   = ws + 18 * n;    // 8N  (reused as gz1b)
    float* hmd  = ws + 26 * n;    // 16N (pairs: h at 2d, md at 2d+1)
    float* gh   = ws + 42 * n;    // 8N
    float* bgh  = ws + 50 * n;    // 8N
    float* gz1b = ya;

    // ---- int region ----
    int* iw        = (int*)(ws + 58 * n);
    int* csr_in    = iw;                       // E
    int* csr_out   = iw + (size_t)E;           // E
    int* start_in  = iw + 2 * (size_t)E;       // N+1
    int* start_out = start_in + n + 1;         // N+1
    int* gHistIn   = start_out + n + 1;        // 256
    int* gHistOut  = gHistIn + 256;            // 256
    int* cStartIn  = gHistOut + 256;           // NB+1
    int* cStartOut = cStartIn + NB + 1;        // NB+1
    int* cCurIn    = cStartOut + NB + 1;       // NB
    int* cCurOut   = cCurIn + NB;              // NB
    int* iwEnd     = cCurOut + NB;
    float* W12p    = (float*)iwEnd;            // HH*WPITCH = 5120 floats
    int* intAfter  = (int*)(W12p + HH * WPITCH);
    // partition scratch: both dirs alias the float region (dead during build)
    int* P_in  = (E <= 16 * (long long)n) ? (int*)ws            : intAfter;
    int* P_out = (E <= 16 * (long long)n) ? (int*)(ws + 16 * n) : intAfter + E;

    hipMemsetAsync(gHistIn, 0, 512 * sizeof(int), stream);

    const int tb = 256;
    int gbN  = (N + tb - 1) / tb;
    int gb16 = (int)((16 * n + tb - 1) / tb);
    int gbC  = (E + CH - 1) / CH;

    // CSR build
    k_coarse <<<gbC, tb, 0, stream>>>(src, dst, gHistIn, gHistOut, NB, E);
    k_cscan  <<<1, 256, 0, stream>>>(gHistIn, gHistOut, cStartIn, cStartOut,
                                     cCurIn, cCurOut, NB, E);
    k_part2  <<<dim3(gbC, 2), tb, 0, stream>>>(src, dst, cCurIn, cCurOut,
                                               P_in, P_out, NB, E);
    k_fine2  <<<dim3(NB, 2), 512, 0, stream>>>(cStartIn, cStartOut, P_in, P_out,
                                               start_in, start_out, csr_in, csr_out, N);
    k_prep   <<<gbN, tb, 0, stream>>>(q, p, M, W1, W2, W12p, start_in, start_out,
                                      a_, b_, hmd, qn, out, N, E);

    // forward (fused gather+MLP): agg1 = AggIn(a⊙q); ya = a⊙(relu((b⊙agg1)@W1+b1)@W2)
    k_fwd    <<<gb16, tb, 0, stream>>>(start_in, csr_in, qn, a_, b_,
                                       W12p, b1, agg1, ya, N);
    // h = b ⊙ AggIn(ya) + b2 + q
    k_h_agg16<<<gb16, tb, 0, stream>>>(start_in, csr_in, ya, b_, q, b2, hmd, N);
    // gravity gradient (two direction halves per node, rsqrt, unroll-8)
    k_gh16   <<<gb16, tb, 0, stream>>>(start_in, csr_in, start_out, csr_out,
                                       hmd, b_, grav, gh, bgh, N);
    // backward (fused gather+MLP): gq2 = AggOut(bgh); gz1b = b⊙((a⊙(gq2@W2^T)⊙relu')@W1^T)
    k_bwd    <<<gb16, tb, 0, stream>>>(start_out, csr_out, bgh, agg1, a_, b_,
                                       W12p, b1, gz1b, N);
    // dHdQ = gh + a ⊙ AggOut(gz1b)
    k_out_agg16<<<gb16, tb, 0, stream>>>(start_out, csr_out, gz1b, gh, a_, out, N);
}

// Round 10
// 354.727 us; speedup vs baseline: 1.4609x; 1.0439x over previous
//
#include <hip/hip_runtime.h>
#include <hip/hip_fp16.h>

#define DD 8
#define HH 256
#define CH 8192          // edges per chunk in coarse/partition kernels
#define PAYBITS 17       // N <= 131072
#define PAYMASK 0x1FFFF
#define WPITCH 20        // LDS weight row pitch (floats): conflict-free

// ============================ CSR construction ==============================
// Bucketed counting sort: coarse bucket = node >> 9, fine bin = node & 511.

__global__ void k_coarse(const int* __restrict__ src, const int* __restrict__ dst,
                         int* __restrict__ gHistIn, int* __restrict__ gHistOut,
                         int NB, int E) {
    __shared__ int hIn[256], hOut[256];
    if (threadIdx.x < 256) { hIn[threadIdx.x] = 0; hOut[threadIdx.x] = 0; }
    __syncthreads();
    int lo = blockIdx.x * CH;
    int hi = min(lo + CH, E);
    for (int i = lo + threadIdx.x; i < hi; i += blockDim.x) {
        atomicAdd(&hIn[dst[i] >> 9], 1);
        atomicAdd(&hOut[src[i] >> 9], 1);
    }
    __syncthreads();
    if (threadIdx.x < NB) {
        int ci = hIn[threadIdx.x], co = hOut[threadIdx.x];
        if (ci) atomicAdd(&gHistIn[threadIdx.x], ci);
        if (co) atomicAdd(&gHistOut[threadIdx.x], co);
    }
}

__global__ void k_cscan(const int* __restrict__ gHistIn, const int* __restrict__ gHistOut,
                        int* __restrict__ cStartIn, int* __restrict__ cStartOut,
                        int* __restrict__ cCurIn, int* __restrict__ cCurOut,
                        int NB, int E) {
    __shared__ int s[256];
#pragma unroll
    for (int dir = 0; dir < 2; dir++) {
        const int* gh = dir ? gHistOut : gHistIn;
        int* cs = dir ? cStartOut : cStartIn;
        int* cc = dir ? cCurOut : cCurIn;
        int v = (threadIdx.x < NB) ? gh[threadIdx.x] : 0;
        s[threadIdx.x] = v;
        __syncthreads();
        for (int off = 1; off < 256; off <<= 1) {
            int t = (threadIdx.x >= off) ? s[threadIdx.x - off] : 0;
            __syncthreads();
            s[threadIdx.x] += t;
            __syncthreads();
        }
        if (threadIdx.x < NB) {
            int ex = s[threadIdx.x] - v;
            cs[threadIdx.x] = ex;
            cc[threadIdx.x] = ex;
        }
        if (threadIdx.x == 0) cs[NB] = E;
        __syncthreads();
    }
}

// both directions in one launch: dir = blockIdx.y (0: key=dst pay=src -> in)
__global__ void k_part2(const int* __restrict__ src, const int* __restrict__ dst,
                        int* __restrict__ cCurIn, int* __restrict__ cCurOut,
                        int* __restrict__ P_in, int* __restrict__ P_out,
                        int NB, int E) {
    int dir = blockIdx.y;
    const int* key = dir ? src : dst;
    const int* pay = dir ? dst : src;
    int* cCur = dir ? cCurOut : cCurIn;
    int* P    = dir ? P_out   : P_in;
    __shared__ int h[256];
    if (threadIdx.x < 256) h[threadIdx.x] = 0;
    __syncthreads();
    int lo = blockIdx.x * CH;
    int hi = min(lo + CH, E);
    for (int i = lo + threadIdx.x; i < hi; i += blockDim.x)
        atomicAdd(&h[key[i] >> 9], 1);
    __syncthreads();
    if (threadIdx.x < NB) {
        int c = h[threadIdx.x];
        h[threadIdx.x] = c ? atomicAdd(&cCur[threadIdx.x], c) : 0;
    }
    __syncthreads();
    for (int i = lo + threadIdx.x; i < hi; i += blockDim.x) {
        int k = key[i];
        int pos = atomicAdd(&h[k >> 9], 1);
        P[pos] = ((k & 511) << PAYBITS) | pay[i];
    }
}

__launch_bounds__(512)
__global__ void k_fine2(const int* __restrict__ cStartIn, const int* __restrict__ cStartOut,
                        const int* __restrict__ P_in, const int* __restrict__ P_out,
                        int* __restrict__ start_in, int* __restrict__ start_out,
                        int* __restrict__ csr_in, int* __restrict__ csr_out, int N) {
    int dir = blockIdx.y;
    const int* cStart = dir ? cStartOut : cStartIn;
    const int* P      = dir ? P_out     : P_in;
    int* start        = dir ? start_out : start_in;
    int* csr          = dir ? csr_out   : csr_in;
    __shared__ int cnt[512], scn[512];
    int b = blockIdx.x;
    int lo = cStart[b], hi = cStart[b + 1];
    cnt[threadIdx.x] = 0;
    __syncthreads();
    for (int i = lo + threadIdx.x; i < hi; i += 512)
        atomicAdd(&cnt[P[i] >> PAYBITS], 1);
    __syncthreads();
    int own = cnt[threadIdx.x];
    scn[threadIdx.x] = own;
    __syncthreads();
    for (int off = 1; off < 512; off <<= 1) {
        int t = (threadIdx.x >= off) ? scn[threadIdx.x - off] : 0;
        __syncthreads();
        scn[threadIdx.x] += t;
        __syncthreads();
    }
    int base = lo + scn[threadIdx.x] - own;
    int node = (b << 9) + threadIdx.x;
    if (node < N) start[node] = base;
    cnt[threadIdx.x] = base;   // reuse as cursor
    __syncthreads();
    for (int i = lo + threadIdx.x; i < hi; i += 512) {
        int p = P[i];
        int pos = atomicAdd(&cnt[p >> PAYBITS], 1);
        csr[pos] = p & PAYMASK;
    }
}

// ========== per-node prep (norms, masses, dHdP) + weight pack ===============
// hm[v*8+d] = __half2{h (filled later by k_h_agg), m}
__global__ void k_prep(const float* __restrict__ q, const float* __restrict__ p,
                       const float* __restrict__ M,
                       const float* __restrict__ W1, const float* __restrict__ W2,
                       float* __restrict__ W12p,
                       int* __restrict__ start_in, int* __restrict__ start_out,
                       float* __restrict__ a, float* __restrict__ b,
                       __half2* __restrict__ hm, float* __restrict__ qn,
                       float* __restrict__ out, int N, int E) {
    int t = blockIdx.x * blockDim.x + threadIdx.x;
    if (t == 0) { start_in[N] = E; start_out[N] = E; }
    if (t < HH * DD) {                      // weight pack
        int j = t >> 3, dd = t & 7;
        W12p[j * WPITCH + dd]     = W1[dd * HH + j];
        W12p[j * WPITCH + 8 + dd] = W2[j * DD + dd];
    }
    int v = t;
    if (v >= N) return;
    int ei1 = (v + 1 < N) ? start_in[v + 1]  : E;
    int eo1 = (v + 1 < N) ? start_out[v + 1] : E;
    float din  = (float)(ei1 - start_in[v]);
    float dout = (float)(eo1 - start_out[v]);
    float av = 1.0f / sqrtf(dout > 0.f ? dout : 1.f);   // norm_src
    float bv = 1.0f / sqrtf(din  > 0.f ? din  : 1.f);   // norm_dst
    a[v] = av; b[v] = bv;
#pragma unroll
    for (int d = 0; d < DD; d++) {
        float m = M[(size_t)v * DD * DD + d * (DD + 1)];
        __half2 hmv;
        hmv.x = __float2half(0.f);
        hmv.y = __float2half(m);
        hm[(size_t)v * DD + d] = hmv;
        qn[(size_t)v * DD + d] = av * q[(size_t)v * DD + d];
        out[(size_t)v * 2 * DD + DD + d] = p[(size_t)v * DD + d] / m;  // dHdP
    }
}

// ---- deep-unrolled gather helpers: sum x[csr[lo..hi)][d] -------------------
static __device__ __forceinline__
float gather_sum(const int* __restrict__ csr, const float* __restrict__ x,
                 int lo, int hi, int d) {
    float s = 0.f;
    int e = lo;
    for (; e + 7 < hi; e += 8) {
        int u[8];
#pragma unroll
        for (int i = 0; i < 8; i++) u[i] = csr[e + i];
        float xv[8];
#pragma unroll
        for (int i = 0; i < 8; i++) xv[i] = x[(size_t)u[i] * DD + d];
        s += ((xv[0] + xv[1]) + (xv[2] + xv[3])) + ((xv[4] + xv[5]) + (xv[6] + xv[7]));
    }
    for (; e + 3 < hi; e += 4) {
        int u0 = csr[e], u1 = csr[e + 1], u2 = csr[e + 2], u3 = csr[e + 3];
        s += (x[(size_t)u0 * DD + d] + x[(size_t)u1 * DD + d])
           + (x[(size_t)u2 * DD + d] + x[(size_t)u3 * DD + d]);
    }
    for (; e < hi; e++) s += x[(size_t)csr[e] * DD + d];
    return s;
}

static __device__ __forceinline__
float gather_sum_h(const int* __restrict__ csr, const __half* __restrict__ x,
                   int lo, int hi, int d) {
    float s = 0.f;
    int e = lo;
    for (; e + 7 < hi; e += 8) {
        int u[8];
#pragma unroll
        for (int i = 0; i < 8; i++) u[i] = csr[e + i];
        float xv[8];
#pragma unroll
        for (int i = 0; i < 8; i++) xv[i] = __half2float(x[(size_t)u[i] * DD + d]);
        s += ((xv[0] + xv[1]) + (xv[2] + xv[3])) + ((xv[4] + xv[5]) + (xv[6] + xv[7]));
    }
    for (; e + 3 < hi; e += 4) {
        int u0 = csr[e], u1 = csr[e + 1], u2 = csr[e + 2], u3 = csr[e + 3];
        s += (__half2float(x[(size_t)u0 * DD + d]) + __half2float(x[(size_t)u1 * DD + d]))
           + (__half2float(x[(size_t)u2 * DD + d]) + __half2float(x[(size_t)u3 * DD + d]));
    }
    for (; e < hi; e++) s += __half2float(x[(size_t)csr[e] * DD + d]);
    return s;
}

// ========== fused gather + MLP forward: 16 lanes/node, LDS weights ==========
__launch_bounds__(256)
__global__ void k_fwd(const int* __restrict__ start, const int* __restrict__ csr,
                      const float* __restrict__ qn, const float* __restrict__ a,
                      const float* __restrict__ b,
                      const float* __restrict__ W12p, const float* __restrict__ b1,
                      float* __restrict__ agg1, float* __restrict__ ya, int N) {
    __shared__ float sW[HH * WPITCH];
    __shared__ float sb1[HH];
    for (int i = threadIdx.x; i < HH * WPITCH; i += 256) sW[i] = W12p[i];
    for (int i = threadIdx.x; i < HH; i += 256) sb1[i] = b1[i];
    __syncthreads();
    int t = blockIdx.x * 256 + threadIdx.x;
    int v = t >> 4, l16 = t & 15, sub = (t >> 3) & 1, d = t & 7;
    if (v >= N) return;
    int e0 = start[v], e1 = start[v + 1];
    int mid = e0 + ((e1 - e0) >> 1);
    float s = gather_sum(csr, qn, sub ? mid : e0, sub ? e1 : mid, d);
    s += __shfl_xor(s, 8);
    if (!sub) agg1[(size_t)v * DD + d] = s;   // saved for backward z-recompute
    float zl = b[v] * s;
    float z[DD];
#pragma unroll
    for (int k = 0; k < DD; k++) z[k] = __shfl(zl, k, 16);
    float acc[DD] = {0.f, 0.f, 0.f, 0.f, 0.f, 0.f, 0.f, 0.f};
    for (int c = 0; c < HH / 16; c += 2) {
        int j0 = (c << 4) | l16, j1 = j0 + 16;
        const float4* w0 = (const float4*)(sW + j0 * WPITCH);
        const float4* w1 = (const float4*)(sW + j1 * WPITCH);
        float4 wa0 = w0[0], wb0 = w0[1], va0 = w0[2], vb0 = w0[3];
        float4 wa1 = w1[0], wb1 = w1[1], va1 = w1[2], vb1 = w1[3];
        float ua0 = fmaf(z[1], wa0.y, fmaf(z[0], wa0.x, sb1[j0]));
        ua0 = fmaf(z[3], wa0.w, fmaf(z[2], wa0.z, ua0));
        float ub0 = fmaf(z[5], wb0.y, z[4] * wb0.x);
        ub0 = fmaf(z[7], wb0.w, fmaf(z[6], wb0.z, ub0));
        float ua1 = fmaf(z[1], wa1.y, fmaf(z[0], wa1.x, sb1[j1]));
        ua1 = fmaf(z[3], wa1.w, fmaf(z[2], wa1.z, ua1));
        float ub1 = fmaf(z[5], wb1.y, z[4] * wb1.x);
        ub1 = fmaf(z[7], wb1.w, fmaf(z[6], wb1.z, ub1));
        float h0 = fmaxf(ua0 + ub0, 0.f);
        float h1 = fmaxf(ua1 + ub1, 0.f);
        acc[0] = fmaf(h0, va0.x, acc[0]); acc[1] = fmaf(h0, va0.y, acc[1]);
        acc[2] = fmaf(h0, va0.z, acc[2]); acc[3] = fmaf(h0, va0.w, acc[3]);
        acc[4] = fmaf(h0, vb0.x, acc[4]); acc[5] = fmaf(h0, vb0.y, acc[5]);
        acc[6] = fmaf(h0, vb0.z, acc[6]); acc[7] = fmaf(h0, vb0.w, acc[7]);
        acc[0] = fmaf(h1, va1.x, acc[0]); acc[1] = fmaf(h1, va1.y, acc[1]);
        acc[2] = fmaf(h1, va1.z, acc[2]); acc[3] = fmaf(h1, va1.w, acc[3]);
        acc[4] = fmaf(h1, vb1.x, acc[4]); acc[5] = fmaf(h1, vb1.y, acc[5]);
        acc[6] = fmaf(h1, vb1.z, acc[6]); acc[7] = fmaf(h1, vb1.w, acc[7]);
    }
#pragma unroll
    for (int m = 1; m < 16; m <<= 1)
#pragma unroll
        for (int k = 0; k < DD; k++) acc[k] += __shfl_xor(acc[k], m);
    float yl = acc[0];
#pragma unroll
    for (int k = 1; k < DD; k++) yl = (d == k) ? acc[k] : yl;
    if (!sub) ya[(size_t)v * DD + d] = a[v] * yl;
}

// h = b*AggIn(ya) + b2 + q, stored as the low half of hm[v*8+d]
__global__ void k_h_agg16(const int* __restrict__ start, const int* __restrict__ csr,
                          const float* __restrict__ ya, const float* __restrict__ b,
                          const float* __restrict__ q, const float* __restrict__ b2,
                          __half2* __restrict__ hm, int N) {
    int t = blockIdx.x * blockDim.x + threadIdx.x;
    int v = t >> 4, sub = (t >> 3) & 1, d = t & 7;
    if (v >= N) return;
    int e0 = start[v], e1 = start[v + 1];
    int mid = e0 + ((e1 - e0) >> 1);
    float s = gather_sum(csr, ya, sub ? mid : e0, sub ? e1 : mid, d);
    s += __shfl_xor(s, 8);
    if (!sub) {
        float hval = fmaf(b[v], s, b2[d] + q[(size_t)v * DD + d]);
        ((__half*)hm)[((size_t)v * DD + d) * 2] = __float2half(hval);  // .x slot
    }
}

// gravity gradient: 16 lanes/node (dir halves), unroll-4, rsqrt, __half2 hm
__global__ void k_gh16(const int* __restrict__ start_in, const int* __restrict__ csr_in,
                       const int* __restrict__ start_out, const int* __restrict__ csr_out,
                       const __half2* __restrict__ hm,
                       const float* __restrict__ b, const float* __restrict__ grav,
                       float* __restrict__ gh, __half* __restrict__ bgh, int N) {
    int t = blockIdx.x * blockDim.x + threadIdx.x;
    int v = t >> 4, dir = (t >> 3) & 1, d = t & 7;
    if (v >= N) return;
    __half2 self = hm[(size_t)v * DD + d];
    float hv = __low2float(self), mv = __high2float(self);
    float coef = -0.5f * grav[0];
    float acc = 0.f;
    const int* start = dir ? start_out : start_in;
    const int* csr   = dir ? csr_out   : csr_in;
    int e1 = start[v + 1];
    int e = start[v];
    for (; e + 3 < e1; e += 4) {
        int u0 = csr[e], u1 = csr[e + 1], u2 = csr[e + 2], u3 = csr[e + 3];
        __half2 q0 = hm[(size_t)u0 * DD + d];
        __half2 q1 = hm[(size_t)u1 * DD + d];
        __half2 q2 = hm[(size_t)u2 * DD + d];
        __half2 q3 = hm[(size_t)u3 * DD + d];
        float d0 = hv - __low2float(q0), d1 = hv - __low2float(q1);
        float d2 = hv - __low2float(q2), d3 = hv - __low2float(q3);
        float e20 = d0 * d0, e21 = d1 * d1, e22 = d2 * d2, e23 = d3 * d3;
        float S0 = mv * __high2float(q0), S1 = mv * __high2float(q1);
        float S2 = mv * __high2float(q2), S3 = mv * __high2float(q3);
        e20 += __shfl_xor(e20, 1); S0 += __shfl_xor(S0, 1);
        e21 += __shfl_xor(e21, 1); S1 += __shfl_xor(S1, 1);
        e22 += __shfl_xor(e22, 1); S2 += __shfl_xor(S2, 1);
        e23 += __shfl_xor(e23, 1); S3 += __shfl_xor(S3, 1);
        e20 += __shfl_xor(e20, 2); S0 += __shfl_xor(S0, 2);
        e21 += __shfl_xor(e21, 2); S1 += __shfl_xor(S1, 2);
        e22 += __shfl_xor(e22, 2); S2 += __shfl_xor(S2, 2);
        e23 += __shfl_xor(e23, 2); S3 += __shfl_xor(S3, 2);
        e20 += __shfl_xor(e20, 4); S0 += __shfl_xor(S0, 4);
        e21 += __shfl_xor(e21, 4); S1 += __shfl_xor(S1, 4);
        e22 += __shfl_xor(e22, 4); S2 += __shfl_xor(S2, 4);
        e23 += __shfl_xor(e23, 4); S3 += __shfl_xor(S3, 4);
        float r0 = rsqrtf(e20), r1 = rsqrtf(e21), r2 = rsqrtf(e22), r3 = rsqrtf(e23);
        float c0 = coef * S0 * r0 * r0 * r0;
        float c1 = coef * S1 * r1 * r1 * r1;
        float c2 = coef * S2 * r2 * r2 * r2;
        float c3 = coef * S3 * r3 * r3 * r3;
        acc = fmaf(c0, d0, acc); acc = fmaf(c1, d1, acc);
        acc = fmaf(c2, d2, acc); acc = fmaf(c3, d3, acc);
    }
    for (; e < e1; e++) {
        int u = csr[e];
        __half2 qu = hm[(size_t)u * DD + d];
        float dif = hv - __low2float(qu);
        float e2 = dif * dif;
        float S  = mv * __high2float(qu);
        e2 += __shfl_xor(e2, 1); S += __shfl_xor(S, 1);
        e2 += __shfl_xor(e2, 2); S += __shfl_xor(S, 2);
        e2 += __shfl_xor(e2, 4); S += __shfl_xor(S, 4);
        float r = rsqrtf(e2);
        acc = fmaf(coef * S * r * r * r, dif, acc);
    }
    acc += __shfl_xor(acc, 8);   // combine the two direction halves
    if (!dir) {
        gh[(size_t)v * DD + d] = acc;
        bgh[(size_t)v * DD + d] = __float2half(b[v] * acc);
    }
}

// ========== fused gather + MLP backward: 16 lanes/node, LDS weights =========
__launch_bounds__(256)
__global__ void k_bwd(const int* __restrict__ start, const int* __restrict__ csr,
                      const __half* __restrict__ bgh, const float* __restrict__ agg1,
                      const float* __restrict__ a, const float* __restrict__ b,
                      const float* __restrict__ W12p, const float* __restrict__ b1,
                      __half* __restrict__ gz1b, int N) {
    __shared__ float sW[HH * WPITCH];
    __shared__ float sb1[HH];
    for (int i = threadIdx.x; i < HH * WPITCH; i += 256) sW[i] = W12p[i];
    for (int i = threadIdx.x; i < HH; i += 256) sb1[i] = b1[i];
    __syncthreads();
    int t = blockIdx.x * 256 + threadIdx.x;
    int v = t >> 4, l16 = t & 15, sub = (t >> 3) & 1, d = t & 7;
    if (v >= N) return;
    int e0 = start[v], e1 = start[v + 1];
    int mid = e0 + ((e1 - e0) >> 1);
    float s = gather_sum_h(csr, bgh, sub ? mid : e0, sub ? e1 : mid, d);
    s += __shfl_xor(s, 8);
    float bv = b[v], av = a[v];
    float zl = bv * agg1[(size_t)v * DD + d];
    float z[DD], gq[DD];
#pragma unroll
    for (int k = 0; k < DD; k++) { z[k] = __shfl(zl, k, 16); gq[k] = __shfl(s, k, 16); }
    float gz[DD] = {0.f, 0.f, 0.f, 0.f, 0.f, 0.f, 0.f, 0.f};
    for (int c = 0; c < HH / 16; c += 2) {
        int j0 = (c << 4) | l16, j1 = j0 + 16;
        const float4* w0 = (const float4*)(sW + j0 * WPITCH);
        const float4* w1 = (const float4*)(sW + j1 * WPITCH);
        float4 wa0 = w0[0], wb0 = w0[1], va0 = w0[2], vb0 = w0[3];
        float4 wa1 = w1[0], wb1 = w1[1], va1 = w1[2], vb1 = w1[3];
        float ua0 = fmaf(z[1], wa0.y, fmaf(z[0], wa0.x, sb1[j0]));
        ua0 = fmaf(z[3], wa0.w, fmaf(z[2], wa0.z, ua0));
        float ub0 = fmaf(z[5], wb0.y, z[4] * wb0.x);
        ub0 = fmaf(z[7], wb0.w, fmaf(z[6], wb0.z, ub0));
        float ua1 = fmaf(z[1], wa1.y, fmaf(z[0], wa1.x, sb1[j1]));
        ua1 = fmaf(z[3], wa1.w, fmaf(z[2], wa1.z, ua1));
        float ub1 = fmaf(z[5], wb1.y, z[4] * wb1.x);
        ub1 = fmaf(z[7], wb1.w, fmaf(z[6], wb1.z, ub1));
        float u0 = ua0 + ub0, u1 = ua1 + ub1;
        float ga0 = fmaf(gq[1], va0.y, gq[0] * va0.x);
        ga0 = fmaf(gq[3], va0.w, fmaf(gq[2], va0.z, ga0));
        float gb0 = fmaf(gq[5], vb0.y, gq[4] * vb0.x);
        gb0 = fmaf(gq[7], vb0.w, fmaf(gq[6], vb0.z, gb0));
        float ga1 = fmaf(gq[1], va1.y, gq[0] * va1.x);
        ga1 = fmaf(gq[3], va1.w, fmaf(gq[2], va1.z, ga1));
        float gb1 = fmaf(gq[5], vb1.y, gq[4] * vb1.x);
        gb1 = fmaf(gq[7], vb1.w, fmaf(gq[6], vb1.z, gb1));
        float g0 = (u0 > 0.f) ? av * (ga0 + gb0) : 0.f;
        float g1 = (u1 > 0.f) ? av * (ga1 + gb1) : 0.f;
        gz[0] = fmaf(g0, wa0.x, gz[0]); gz[1] = fmaf(g0, wa0.y, gz[1]);
        gz[2] = fmaf(g0, wa0.z, gz[2]); gz[3] = fmaf(g0, wa0.w, gz[3]);
        gz[4] = fmaf(g0, wb0.x, gz[4]); gz[5] = fmaf(g0, wb0.y, gz[5]);
        gz[6] = fmaf(g0, wb0.z, gz[6]); gz[7] = fmaf(g0, wb0.w, gz[7]);
        gz[0] = fmaf(g1, wa1.x, gz[0]); gz[1] = fmaf(g1, wa1.y, gz[1]);
        gz[2] = fmaf(g1, wa1.z, gz[2]); gz[3] = fmaf(g1, wa1.w, gz[3]);
        gz[4] = fmaf(g1, wb1.x, gz[4]); gz[5] = fmaf(g1, wb1.y, gz[5]);
        gz[6] = fmaf(g1, wb1.z, gz[6]); gz[7] = fmaf(g1, wb1.w, gz[7]);
    }
#pragma unroll
    for (int m = 1; m < 16; m <<= 1)
#pragma unroll
        for (int k = 0; k < DD; k++) gz[k] += __shfl_xor(gz[k], m);
    float out_l = gz[0];
#pragma unroll
    for (int k = 1; k < DD; k++) out_l = (d == k) ? gz[k] : out_l;
    if (!sub) gz1b[(size_t)v * DD + d] = __float2half(bv * out_l);
}

// out[:, :D] = gh + a * AggOut(gz1b)
__global__ void k_out_agg16(const int* __restrict__ start, const int* __restrict__ csr,
                            const __half* __restrict__ gz1b, const float* __restrict__ gh,
                            const float* __restrict__ a, float* __restrict__ out, int N) {
    int t = blockIdx.x * blockDim.x + threadIdx.x;
    int v = t >> 4, sub = (t >> 3) & 1, d = t & 7;
    if (v >= N) return;
    int e0 = start[v], e1 = start[v + 1];
    int mid = e0 + ((e1 - e0) >> 1);
    float s = gather_sum_h(csr, gz1b, sub ? mid : e0, sub ? e1 : mid, d);
    s += __shfl_xor(s, 8);
    if (!sub)
        out[(size_t)v * 2 * DD + d] = fmaf(a[v], s, gh[(size_t)v * DD + d]);
}

// ============================== launch =====================================

extern "C" void kernel_launch(void* const* d_in, const int* in_sizes, int n_in,
                              void* d_out, int out_size, void* d_ws, size_t ws_size,
                              hipStream_t stream) {
    const float* q    = (const float*)d_in[0];
    const float* p    = (const float*)d_in[1];
    const float* M    = (const float*)d_in[2];
    const int*   src  = (const int*)d_in[3];
    const int*   dst  = (const int*)d_in[4];
    const float* W1   = (const float*)d_in[5];
    const float* b1   = (const float*)d_in[6];
    const float* W2   = (const float*)d_in[7];
    const float* b2   = (const float*)d_in[8];
    const float* grav = (const float*)d_in[9];
    float* out = (float*)d_out;

    int N = in_sizes[0] / DD;
    int E = in_sizes[3];
    size_t n = (size_t)N;
    int NB = (N + 511) >> 9;

    // ---- float region (50N 4-byte words) ----
    float*   ws   = (float*)d_ws;
    float*   a_   = ws;             // N
    float*   b_   = ws + n;         // N
    float*   qn   = ws + 2  * n;    // 8N f32
    float*   agg1 = ws + 10 * n;    // 8N f32 (stored by fwd, read by bwd)
    float*   ya   = ws + 18 * n;    // 8N f32
    float*   gh   = ws + 26 * n;    // 8N f32
    __half2* hm   = (__half2*)(ws + 34 * n);  // 8N half2 (8N words)
    __half*  bgh  = (__half*)(ws + 42 * n);   // 8N halfs (4N words)
    __half*  gz1b = (__half*)(ws + 46 * n);   // 8N halfs (4N words)

    // ---- int region ----
    int* iw        = (int*)(ws + 50 * n);
    int* csr_in    = iw;                       // E
    int* csr_out   = iw + (size_t)E;           // E
    int* start_in  = iw + 2 * (size_t)E;       // N+1
    int* start_out = start_in + n + 1;         // N+1
    int* gHistIn   = start_out + n + 1;        // 256
    int* gHistOut  = gHistIn + 256;            // 256
    int* cStartIn  = gHistOut + 256;           // NB+1
    int* cStartOut = cStartIn + NB + 1;        // NB+1
    int* cCurIn    = cStartOut + NB + 1;       // NB
    int* cCurOut   = cCurIn + NB;              // NB
    int* iwEnd     = cCurOut + NB;
    float* W12p    = (float*)iwEnd;            // HH*WPITCH = 5120 floats
    int* intAfter  = (int*)(W12p + HH * WPITCH);
    // partition scratch: both dirs alias the float region (dead during build)
    int* P_in  = (E <= 16 * (long long)n) ? (int*)ws            : intAfter;
    int* P_out = (E <= 16 * (long long)n) ? (int*)(ws + 16 * n) : intAfter + E;

    hipMemsetAsync(gHistIn, 0, 512 * sizeof(int), stream);

    const int tb = 256;
    int gbN  = (N + tb - 1) / tb;
    int gb16 = (int)((16 * n + tb - 1) / tb);
    int gbC  = (E + CH - 1) / CH;

    // CSR build
    k_coarse <<<gbC, tb, 0, stream>>>(src, dst, gHistIn, gHistOut, NB, E);
    k_cscan  <<<1, 256, 0, stream>>>(gHistIn, gHistOut, cStartIn, cStartOut,
                                     cCurIn, cCurOut, NB, E);
    k_part2  <<<dim3(gbC, 2), tb, 0, stream>>>(src, dst, cCurIn, cCurOut,
                                               P_in, P_out, NB, E);
    k_fine2  <<<dim3(NB, 2), 512, 0, stream>>>(cStartIn, cStartOut, P_in, P_out,
                                               start_in, start_out, csr_in, csr_out, N);
    k_prep   <<<gbN, tb, 0, stream>>>(q, p, M, W1, W2, W12p, start_in, start_out,
                                      a_, b_, hm, qn, out, N, E);

    // forward (fused gather+MLP): agg1 = AggIn(a⊙q); ya = a⊙(relu((b⊙agg1)@W1+b1)@W2)
    k_fwd    <<<gb16, tb, 0, stream>>>(start_in, csr_in, qn, a_, b_,
                                       W12p, b1, agg1, ya, N);
    // h = b ⊙ AggIn(ya) + b2 + q  -> low half of hm
    k_h_agg16<<<gb16, tb, 0, stream>>>(start_in, csr_in, ya, b_, q, b2, hm, N);
    // gravity gradient (two direction halves per node, rsqrt, half2 hm)
    k_gh16   <<<gb16, tb, 0, stream>>>(start_in, csr_in, start_out, csr_out,
                                       hm, b_, grav, gh, bgh, N);
    // backward (fused gather+MLP): gq2 = AggOut(bgh); gz1b = b⊙((a⊙(gq2@W2^T)⊙relu')@W1^T)
    k_bwd    <<<gb16, tb, 0, stream>>>(start_out, csr_out, bgh, agg1, a_, b_,
                                       W12p, b1, gz1b, N);
    // dHdQ = gh + a ⊙ AggOut(gz1b)
    k_out_agg16<<<gb16, tb, 0, stream>>>(start_out, csr_out, gz1b, gh, a_, out, N);
}

// Round 11
// 350.078 us; speedup vs baseline: 1.4803x; 1.0133x over previous
//
#include <hip/hip_runtime.h>
#include <hip/hip_fp16.h>

#define DD 8
#define HH 256
#define CH 8192          // edges per chunk in coarse/partition kernels
#define PAYBITS 17       // N <= 131072
#define PAYMASK 0x1FFFF
#define WPITCH 20        // LDS weight row pitch (floats): conflict-free

// ============================ CSR construction ==============================

__global__ void k_coarse(const int* __restrict__ src, const int* __restrict__ dst,
                         int* __restrict__ gHistIn, int* __restrict__ gHistOut,
                         int NB, int E) {
    __shared__ int hIn[256], hOut[256];
    if (threadIdx.x < 256) { hIn[threadIdx.x] = 0; hOut[threadIdx.x] = 0; }
    __syncthreads();
    int lo = blockIdx.x * CH;
    int hi = min(lo + CH, E);
    for (int i = lo + threadIdx.x; i < hi; i += blockDim.x) {
        atomicAdd(&hIn[dst[i] >> 9], 1);
        atomicAdd(&hOut[src[i] >> 9], 1);
    }
    __syncthreads();
    if (threadIdx.x < NB) {
        int ci = hIn[threadIdx.x], co = hOut[threadIdx.x];
        if (ci) atomicAdd(&gHistIn[threadIdx.x], ci);
        if (co) atomicAdd(&gHistOut[threadIdx.x], co);
    }
}

__global__ void k_cscan(const int* __restrict__ gHistIn, const int* __restrict__ gHistOut,
                        int* __restrict__ cStartIn, int* __restrict__ cStartOut,
                        int* __restrict__ cCurIn, int* __restrict__ cCurOut,
                        int NB, int E) {
    __shared__ int s[256];
#pragma unroll
    for (int dir = 0; dir < 2; dir++) {
        const int* gh = dir ? gHistOut : gHistIn;
        int* cs = dir ? cStartOut : cStartIn;
        int* cc = dir ? cCurOut : cCurIn;
        int v = (threadIdx.x < NB) ? gh[threadIdx.x] : 0;
        s[threadIdx.x] = v;
        __syncthreads();
        for (int off = 1; off < 256; off <<= 1) {
            int t = (threadIdx.x >= off) ? s[threadIdx.x - off] : 0;
            __syncthreads();
            s[threadIdx.x] += t;
            __syncthreads();
        }
        if (threadIdx.x < NB) {
            int ex = s[threadIdx.x] - v;
            cs[threadIdx.x] = ex;
            cc[threadIdx.x] = ex;
        }
        if (threadIdx.x == 0) cs[NB] = E;
        __syncthreads();
    }
}

__global__ void k_part2(const int* __restrict__ src, const int* __restrict__ dst,
                        int* __restrict__ cCurIn, int* __restrict__ cCurOut,
                        int* __restrict__ P_in, int* __restrict__ P_out,
                        int NB, int E) {
    int dir = blockIdx.y;
    const int* key = dir ? src : dst;
    const int* pay = dir ? dst : src;
    int* cCur = dir ? cCurOut : cCurIn;
    int* P    = dir ? P_out   : P_in;
    __shared__ int h[256];
    if (threadIdx.x < 256) h[threadIdx.x] = 0;
    __syncthreads();
    int lo = blockIdx.x * CH;
    int hi = min(lo + CH, E);
    for (int i = lo + threadIdx.x; i < hi; i += blockDim.x)
        atomicAdd(&h[key[i] >> 9], 1);
    __syncthreads();
    if (threadIdx.x < NB) {
        int c = h[threadIdx.x];
        h[threadIdx.x] = c ? atomicAdd(&cCur[threadIdx.x], c) : 0;
    }
    __syncthreads();
    for (int i = lo + threadIdx.x; i < hi; i += blockDim.x) {
        int k = key[i];
        int pos = atomicAdd(&h[k >> 9], 1);
        P[pos] = ((k & 511) << PAYBITS) | pay[i];
    }
}

__launch_bounds__(512)
__global__ void k_fine2(const int* __restrict__ cStartIn, const int* __restrict__ cStartOut,
                        const int* __restrict__ P_in, const int* __restrict__ P_out,
                        int* __restrict__ start_in, int* __restrict__ start_out,
                        int* __restrict__ csr_in, int* __restrict__ csr_out, int N) {
    int dir = blockIdx.y;
    const int* cStart = dir ? cStartOut : cStartIn;
    const int* P      = dir ? P_out     : P_in;
    int* start        = dir ? start_out : start_in;
    int* csr          = dir ? csr_out   : csr_in;
    __shared__ int cnt[512], scn[512];
    int b = blockIdx.x;
    int lo = cStart[b], hi = cStart[b + 1];
    cnt[threadIdx.x] = 0;
    __syncthreads();
    for (int i = lo + threadIdx.x; i < hi; i += 512)
        atomicAdd(&cnt[P[i] >> PAYBITS], 1);
    __syncthreads();
    int own = cnt[threadIdx.x];
    scn[threadIdx.x] = own;
    __syncthreads();
    for (int off = 1; off < 512; off <<= 1) {
        int t = (threadIdx.x >= off) ? scn[threadIdx.x - off] : 0;
        __syncthreads();
        scn[threadIdx.x] += t;
        __syncthreads();
    }
    int base = lo + scn[threadIdx.x] - own;
    int node = (b << 9) + threadIdx.x;
    if (node < N) start[node] = base;
    cnt[threadIdx.x] = base;   // reuse as cursor
    __syncthreads();
    for (int i = lo + threadIdx.x; i < hi; i += 512) {
        int p = P[i];
        int pos = atomicAdd(&cnt[p >> PAYBITS], 1);
        csr[pos] = p & PAYMASK;
    }
}

// ========== per-node prep (norms, masses, dHdP) + weight pack ===============
// hm[v*8+d] = __half2{h (filled later by k_h_node), m}
__global__ void k_prep(const float* __restrict__ q, const float* __restrict__ p,
                       const float* __restrict__ M,
                       const float* __restrict__ W1, const float* __restrict__ W2,
                       float* __restrict__ W12p,
                       int* __restrict__ start_in, int* __restrict__ start_out,
                       float* __restrict__ a, float* __restrict__ b,
                       __half2* __restrict__ hm, float* __restrict__ qn,
                       float* __restrict__ out, int N, int E) {
    int t = blockIdx.x * blockDim.x + threadIdx.x;
    if (t == 0) { start_in[N] = E; start_out[N] = E; }
    if (t < HH * DD) {                      // weight pack
        int j = t >> 3, dd = t & 7;
        W12p[j * WPITCH + dd]     = W1[dd * HH + j];
        W12p[j * WPITCH + 8 + dd] = W2[j * DD + dd];
    }
    int v = t;
    if (v >= N) return;
    int ei1 = (v + 1 < N) ? start_in[v + 1]  : E;
    int eo1 = (v + 1 < N) ? start_out[v + 1] : E;
    float din  = (float)(ei1 - start_in[v]);
    float dout = (float)(eo1 - start_out[v]);
    float av = 1.0f / sqrtf(dout > 0.f ? dout : 1.f);   // norm_src
    float bv = 1.0f / sqrtf(din  > 0.f ? din  : 1.f);   // norm_dst
    a[v] = av; b[v] = bv;
#pragma unroll
    for (int d = 0; d < DD; d++) {
        float m = M[(size_t)v * DD * DD + d * (DD + 1)];
        __half2 hmv;
        hmv.x = __float2half(0.f);
        hmv.y = __float2half(m);
        hm[(size_t)v * DD + d] = hmv;
        qn[(size_t)v * DD + d] = av * q[(size_t)v * DD + d];
        out[(size_t)v * 2 * DD + DD + d] = p[(size_t)v * DD + d] / m;  // dHdP
    }
}

// ------------------- record unpack/accumulate helpers -----------------------
static __device__ __forceinline__
void acc_h8(uint4 r, float acc[8]) {
    float2 f;
    f = __half22float2(*(__half2*)&r.x); acc[0] += f.x; acc[1] += f.y;
    f = __half22float2(*(__half2*)&r.y); acc[2] += f.x; acc[3] += f.y;
    f = __half22float2(*(__half2*)&r.z); acc[4] += f.x; acc[5] += f.y;
    f = __half22float2(*(__half2*)&r.w); acc[6] += f.x; acc[7] += f.y;
}

static __device__ __forceinline__
void unpack_hm(uint4 r0, uint4 r1, float h[8], float m[8]) {
    float2 f;
    f = __half22float2(*(__half2*)&r0.x); h[0] = f.x; m[0] = f.y;
    f = __half22float2(*(__half2*)&r0.y); h[1] = f.x; m[1] = f.y;
    f = __half22float2(*(__half2*)&r0.z); h[2] = f.x; m[2] = f.y;
    f = __half22float2(*(__half2*)&r0.w); h[3] = f.x; m[3] = f.y;
    f = __half22float2(*(__half2*)&r1.x); h[4] = f.x; m[4] = f.y;
    f = __half22float2(*(__half2*)&r1.y); h[5] = f.x; m[5] = f.y;
    f = __half22float2(*(__half2*)&r1.z); h[6] = f.x; m[6] = f.y;
    f = __half22float2(*(__half2*)&r1.w); h[7] = f.x; m[7] = f.y;
}

// gather full half8 records over csr range into acc[8]
static __device__ __forceinline__
void gather_h8(const int* __restrict__ csr, const __half* __restrict__ x,
               int e, int e1, float acc[8]) {
    for (; e + 3 < e1; e += 4) {
        int u0 = csr[e], u1 = csr[e + 1], u2 = csr[e + 2], u3 = csr[e + 3];
        uint4 r0 = *(const uint4*)(x + (size_t)u0 * DD);
        uint4 r1 = *(const uint4*)(x + (size_t)u1 * DD);
        uint4 r2 = *(const uint4*)(x + (size_t)u2 * DD);
        uint4 r3 = *(const uint4*)(x + (size_t)u3 * DD);
        acc_h8(r0, acc); acc_h8(r1, acc); acc_h8(r2, acc); acc_h8(r3, acc);
    }
    for (; e < e1; e++) {
        uint4 r = *(const uint4*)(x + (size_t)csr[e] * DD);
        acc_h8(r, acc);
    }
}

// ================== per-thread-per-node gather kernels ======================

// agg1[v] = sum of qn records (f32, 32B each)
__launch_bounds__(64)
__global__ void k_agg_node(const int* __restrict__ start, const int* __restrict__ csr,
                           const float* __restrict__ x, float* __restrict__ y, int N) {
    int v = blockIdx.x * 64 + threadIdx.x;
    if (v >= N) return;
    int e = start[v], e1 = start[v + 1];
    float acc[8] = {0.f, 0.f, 0.f, 0.f, 0.f, 0.f, 0.f, 0.f};
    for (; e + 1 < e1; e += 2) {
        int u0 = csr[e], u1 = csr[e + 1];
        const float4* p0 = (const float4*)(x + (size_t)u0 * DD);
        const float4* p1 = (const float4*)(x + (size_t)u1 * DD);
        float4 a0 = p0[0], b0 = p0[1], a1 = p1[0], b1 = p1[1];
        acc[0] += a0.x + a1.x; acc[1] += a0.y + a1.y;
        acc[2] += a0.z + a1.z; acc[3] += a0.w + a1.w;
        acc[4] += b0.x + b1.x; acc[5] += b0.y + b1.y;
        acc[6] += b0.z + b1.z; acc[7] += b0.w + b1.w;
    }
    if (e < e1) {
        const float4* p = (const float4*)(x + (size_t)csr[e] * DD);
        float4 a0 = p[0], b0 = p[1];
        acc[0] += a0.x; acc[1] += a0.y; acc[2] += a0.z; acc[3] += a0.w;
        acc[4] += b0.x; acc[5] += b0.y; acc[6] += b0.z; acc[7] += b0.w;
    }
    float4* yp = (float4*)(y + (size_t)v * DD);
    yp[0] = make_float4(acc[0], acc[1], acc[2], acc[3]);
    yp[1] = make_float4(acc[4], acc[5], acc[6], acc[7]);
}

// h = b*AggIn(ya) + b2 + q  -> .x halves of hm records (RMW)
__launch_bounds__(64)
__global__ void k_h_node(const int* __restrict__ start, const int* __restrict__ csr,
                         const __half* __restrict__ ya, const float* __restrict__ b,
                         const float* __restrict__ q, const float* __restrict__ b2,
                         __half2* __restrict__ hm, int N) {
    int v = blockIdx.x * 64 + threadIdx.x;
    if (v >= N) return;
    float acc[8] = {0.f, 0.f, 0.f, 0.f, 0.f, 0.f, 0.f, 0.f};
    gather_h8(csr, ya, start[v], start[v + 1], acc);
    float bv = b[v];
    const float4* qp = (const float4*)(q + (size_t)v * DD);
    float4 q0 = qp[0], q1 = qp[1];
    float hq[8] = {q0.x, q0.y, q0.z, q0.w, q1.x, q1.y, q1.z, q1.w};
    __half2* hp = hm + (size_t)v * DD;
#pragma unroll
    for (int k = 0; k < DD; k++) {
        float hval = fmaf(bv, acc[k], b2[k] + hq[k]);
        __half2 cur = hp[k];
        cur.x = __float2half(hval);
        hp[k] = cur;
    }
}

// gravity gradient: 2 threads/node (dir halves), full records in-thread,
// no cross-lane reductions except the final pair combine.
__launch_bounds__(64)
__global__ void k_gh2(const int* __restrict__ start_in, const int* __restrict__ csr_in,
                      const int* __restrict__ start_out, const int* __restrict__ csr_out,
                      const __half2* __restrict__ hm,
                      const float* __restrict__ b, const float* __restrict__ grav,
                      float* __restrict__ gh, __half* __restrict__ bgh, int N) {
    int t = blockIdx.x * 64 + threadIdx.x;
    int v = t >> 1, dir = t & 1;
    if (v >= N) return;
    const uint4* srec = (const uint4*)(hm + (size_t)v * DD);
    uint4 s0 = srec[0], s1 = srec[1];
    float hv[8], mv[8];
    unpack_hm(s0, s1, hv, mv);
    const int* start = dir ? start_out : start_in;
    const int* csr   = dir ? csr_out   : csr_in;
    int e = start[v], e1 = start[v + 1];
    float coef = -0.5f * grav[0];
    float acc[8] = {0.f, 0.f, 0.f, 0.f, 0.f, 0.f, 0.f, 0.f};
    for (; e + 1 < e1; e += 2) {
        int u0 = csr[e], u1 = csr[e + 1];
        const uint4* r0p = (const uint4*)(hm + (size_t)u0 * DD);
        const uint4* r1p = (const uint4*)(hm + (size_t)u1 * DD);
        uint4 x0 = r0p[0], x1 = r0p[1], y0 = r1p[0], y1 = r1p[1];
        float hu0[8], mu0[8], hu1[8], mu1[8];
        unpack_hm(x0, x1, hu0, mu0);
        unpack_hm(y0, y1, hu1, mu1);
        float d0[8], d1[8];
        float e20 = 0.f, S0 = 0.f, e21 = 0.f, S1 = 0.f;
#pragma unroll
        for (int k = 0; k < 8; k++) {
            d0[k] = hv[k] - hu0[k];
            d1[k] = hv[k] - hu1[k];
            e20 = fmaf(d0[k], d0[k], e20);
            e21 = fmaf(d1[k], d1[k], e21);
            S0 = fmaf(mv[k], mu0[k], S0);
            S1 = fmaf(mv[k], mu1[k], S1);
        }
        float r0 = rsqrtf(e20), r1 = rsqrtf(e21);
        float c0 = coef * S0 * r0 * r0 * r0;
        float c1 = coef * S1 * r1 * r1 * r1;
#pragma unroll
        for (int k = 0; k < 8; k++)
            acc[k] = fmaf(c0, d0[k], fmaf(c1, d1[k], acc[k]));
    }
    if (e < e1) {
        int u = csr[e];
        const uint4* rp = (const uint4*)(hm + (size_t)u * DD);
        uint4 x0 = rp[0], x1 = rp[1];
        float hu[8], mu[8];
        unpack_hm(x0, x1, hu, mu);
        float df[8];
        float e2 = 0.f, S = 0.f;
#pragma unroll
        for (int k = 0; k < 8; k++) {
            df[k] = hv[k] - hu[k];
            e2 = fmaf(df[k], df[k], e2);
            S = fmaf(mv[k], mu[k], S);
        }
        float r = rsqrtf(e2);
        float c = coef * S * r * r * r;
#pragma unroll
        for (int k = 0; k < 8; k++) acc[k] = fmaf(c, df[k], acc[k]);
    }
    // combine the two direction threads (adjacent lanes)
#pragma unroll
    for (int k = 0; k < 8; k++) acc[k] += __shfl_xor(acc[k], 1);
    if (!dir) {
        float4* gp = (float4*)(gh + (size_t)v * DD);
        gp[0] = make_float4(acc[0], acc[1], acc[2], acc[3]);
        gp[1] = make_float4(acc[4], acc[5], acc[6], acc[7]);
        float bv = b[v];
        __half2* bp = (__half2*)(bgh + (size_t)v * DD);
        bp[0] = __floats2half2_rn(bv * acc[0], bv * acc[1]);
        bp[1] = __floats2half2_rn(bv * acc[2], bv * acc[3]);
        bp[2] = __floats2half2_rn(bv * acc[4], bv * acc[5]);
        bp[3] = __floats2half2_rn(bv * acc[6], bv * acc[7]);
    }
}

// gq2[v] = AggOut(bgh)  (half records -> f32 store)
__launch_bounds__(64)
__global__ void k_bgh_node(const int* __restrict__ start, const int* __restrict__ csr,
                           const __half* __restrict__ bgh, float* __restrict__ gq2, int N) {
    int v = blockIdx.x * 64 + threadIdx.x;
    if (v >= N) return;
    float acc[8] = {0.f, 0.f, 0.f, 0.f, 0.f, 0.f, 0.f, 0.f};
    gather_h8(csr, bgh, start[v], start[v + 1], acc);
    float4* yp = (float4*)(gq2 + (size_t)v * DD);
    yp[0] = make_float4(acc[0], acc[1], acc[2], acc[3]);
    yp[1] = make_float4(acc[4], acc[5], acc[6], acc[7]);
}

// out[:, :D] = gh + a * AggOut(gz1b)
__launch_bounds__(64)
__global__ void k_out_node(const int* __restrict__ start, const int* __restrict__ csr,
                           const __half* __restrict__ gz1b, const float* __restrict__ gh,
                           const float* __restrict__ a, float* __restrict__ out, int N) {
    int v = blockIdx.x * 64 + threadIdx.x;
    if (v >= N) return;
    float acc[8] = {0.f, 0.f, 0.f, 0.f, 0.f, 0.f, 0.f, 0.f};
    gather_h8(csr, gz1b, start[v], start[v + 1], acc);
    float av = a[v];
    const float4* gp = (const float4*)(gh + (size_t)v * DD);
    float4 g0 = gp[0], g1 = gp[1];
    float4* op = (float4*)(out + (size_t)v * 2 * DD);
    op[0] = make_float4(fmaf(av, acc[0], g0.x), fmaf(av, acc[1], g0.y),
                        fmaf(av, acc[2], g0.z), fmaf(av, acc[3], g0.w));
    op[1] = make_float4(fmaf(av, acc[4], g1.x), fmaf(av, acc[5], g1.y),
                        fmaf(av, acc[6], g1.z), fmaf(av, acc[7], g1.w));
}

// ================ MLP kernels: 16 lanes/node, LDS weights ===================

__launch_bounds__(256)
__global__ void k_mlp_fwd(const float* __restrict__ agg1, const float* __restrict__ a,
                          const float* __restrict__ b,
                          const float* __restrict__ W12p, const float* __restrict__ b1,
                          __half* __restrict__ ya, int N) {
    __shared__ float sW[HH * WPITCH];
    __shared__ float sb1[HH];
    for (int i = threadIdx.x; i < HH * WPITCH; i += 256) sW[i] = W12p[i];
    for (int i = threadIdx.x; i < HH; i += 256) sb1[i] = b1[i];
    __syncthreads();
    int t = blockIdx.x * 256 + threadIdx.x;
    int v = t >> 4, l16 = t & 15, sub = (t >> 3) & 1, d = t & 7;
    if (v >= N) return;
    float zl = b[v] * agg1[(size_t)v * DD + d];
    float z[DD];
#pragma unroll
    for (int k = 0; k < DD; k++) z[k] = __shfl(zl, k, 16);
    float acc[DD] = {0.f, 0.f, 0.f, 0.f, 0.f, 0.f, 0.f, 0.f};
    for (int c = 0; c < HH / 16; c += 2) {
        int j0 = (c << 4) | l16, j1 = j0 + 16;
        const float4* w0 = (const float4*)(sW + j0 * WPITCH);
        const float4* w1 = (const float4*)(sW + j1 * WPITCH);
        float4 wa0 = w0[0], wb0 = w0[1], va0 = w0[2], vb0 = w0[3];
        float4 wa1 = w1[0], wb1 = w1[1], va1 = w1[2], vb1 = w1[3];
        float ua0 = fmaf(z[1], wa0.y, fmaf(z[0], wa0.x, sb1[j0]));
        ua0 = fmaf(z[3], wa0.w, fmaf(z[2], wa0.z, ua0));
        float ub0 = fmaf(z[5], wb0.y, z[4] * wb0.x);
        ub0 = fmaf(z[7], wb0.w, fmaf(z[6], wb0.z, ub0));
        float ua1 = fmaf(z[1], wa1.y, fmaf(z[0], wa1.x, sb1[j1]));
        ua1 = fmaf(z[3], wa1.w, fmaf(z[2], wa1.z, ua1));
        float ub1 = fmaf(z[5], wb1.y, z[4] * wb1.x);
        ub1 = fmaf(z[7], wb1.w, fmaf(z[6], wb1.z, ub1));
        float h0 = fmaxf(ua0 + ub0, 0.f);
        float h1 = fmaxf(ua1 + ub1, 0.f);
        acc[0] = fmaf(h0, va0.x, acc[0]); acc[1] = fmaf(h0, va0.y, acc[1]);
        acc[2] = fmaf(h0, va0.z, acc[2]); acc[3] = fmaf(h0, va0.w, acc[3]);
        acc[4] = fmaf(h0, vb0.x, acc[4]); acc[5] = fmaf(h0, vb0.y, acc[5]);
        acc[6] = fmaf(h0, vb0.z, acc[6]); acc[7] = fmaf(h0, vb0.w, acc[7]);
        acc[0] = fmaf(h1, va1.x, acc[0]); acc[1] = fmaf(h1, va1.y, acc[1]);
        acc[2] = fmaf(h1, va1.z, acc[2]); acc[3] = fmaf(h1, va1.w, acc[3]);
        acc[4] = fmaf(h1, vb1.x, acc[4]); acc[5] = fmaf(h1, vb1.y, acc[5]);
        acc[6] = fmaf(h1, vb1.z, acc[6]); acc[7] = fmaf(h1, vb1.w, acc[7]);
    }
#pragma unroll
    for (int m = 1; m < 16; m <<= 1)
#pragma unroll
        for (int k = 0; k < DD; k++) acc[k] += __shfl_xor(acc[k], m);
    float yl = acc[0];
#pragma unroll
    for (int k = 1; k < DD; k++) yl = (d == k) ? acc[k] : yl;
    if (!sub) ya[(size_t)v * DD + d] = __float2half(a[v] * yl);
}

__launch_bounds__(256)
__global__ void k_mlp_bwd(const float* __restrict__ gq2, const float* __restrict__ agg1,
                          const float* __restrict__ a, const float* __restrict__ b,
                          const float* __restrict__ W12p, const float* __restrict__ b1,
                          __half* __restrict__ gz1b, int N) {
    __shared__ float sW[HH * WPITCH];
    __shared__ float sb1[HH];
    for (int i = threadIdx.x; i < HH * WPITCH; i += 256) sW[i] = W12p[i];
    for (int i = threadIdx.x; i < HH; i += 256) sb1[i] = b1[i];
    __syncthreads();
    int t = blockIdx.x * 256 + threadIdx.x;
    int v = t >> 4, l16 = t & 15, sub = (t >> 3) & 1, d = t & 7;
    if (v >= N) return;
    float bv = b[v], av = a[v];
    float zl = bv * agg1[(size_t)v * DD + d];
    float gl = gq2[(size_t)v * DD + d];
    float z[DD], gq[DD];
#pragma unroll
    for (int k = 0; k < DD; k++) { z[k] = __shfl(zl, k, 16); gq[k] = __shfl(gl, k, 16); }
    float gz[DD] = {0.f, 0.f, 0.f, 0.f, 0.f, 0.f, 0.f, 0.f};
    for (int c = 0; c < HH / 16; c += 2) {
        int j0 = (c << 4) | l16, j1 = j0 + 16;
        const float4* w0 = (const float4*)(sW + j0 * WPITCH);
        const float4* w1 = (const float4*)(sW + j1 * WPITCH);
        float4 wa0 = w0[0], wb0 = w0[1], va0 = w0[2], vb0 = w0[3];
        float4 wa1 = w1[0], wb1 = w1[1], va1 = w1[2], vb1 = w1[3];
        float ua0 = fmaf(z[1], wa0.y, fmaf(z[0], wa0.x, sb1[j0]));
        ua0 = fmaf(z[3], wa0.w, fmaf(z[2], wa0.z, ua0));
        float ub0 = fmaf(z[5], wb0.y, z[4] * wb0.x);
        ub0 = fmaf(z[7], wb0.w, fmaf(z[6], wb0.z, ub0));
        float ua1 = fmaf(z[1], wa1.y, fmaf(z[0], wa1.x, sb1[j1]));
        ua1 = fmaf(z[3], wa1.w, fmaf(z[2], wa1.z, ua1));
        float ub1 = fmaf(z[5], wb1.y, z[4] * wb1.x);
        ub1 = fmaf(z[7], wb1.w, fmaf(z[6], wb1.z, ub1));
        float u0 = ua0 + ub0, u1 = ua1 + ub1;
        float ga0 = fmaf(gq[1], va0.y, gq[0] * va0.x);
        ga0 = fmaf(gq[3], va0.w, fmaf(gq[2], va0.z, ga0));
        float gb0 = fmaf(gq[5], vb0.y, gq[4] * vb0.x);
        gb0 = fmaf(gq[7], vb0.w, fmaf(gq[6], vb0.z, gb0));
        float ga1 = fmaf(gq[1], va1.y, gq[0] * va1.x);
        ga1 = fmaf(gq[3], va1.w, fmaf(gq[2], va1.z, ga1));
        float gb1 = fmaf(gq[5], vb1.y, gq[4] * vb1.x);
        gb1 = fmaf(gq[7], vb1.w, fmaf(gq[6], vb1.z, gb1));
        float g0 = (u0 > 0.f) ? av * (ga0 + gb0) : 0.f;
        float g1 = (u1 > 0.f) ? av * (ga1 + gb1) : 0.f;
        gz[0] = fmaf(g0, wa0.x, gz[0]); gz[1] = fmaf(g0, wa0.y, gz[1]);
        gz[2] = fmaf(g0, wa0.z, gz[2]); gz[3] = fmaf(g0, wa0.w, gz[3]);
        gz[4] = fmaf(g0, wb0.x, gz[4]); gz[5] = fmaf(g0, wb0.y, gz[5]);
        gz[6] = fmaf(g0, wb0.z, gz[6]); gz[7] = fmaf(g0, wb0.w, gz[7]);
        gz[0] = fmaf(g1, wa1.x, gz[0]); gz[1] = fmaf(g1, wa1.y, gz[1]);
        gz[2] = fmaf(g1, wa1.z, gz[2]); gz[3] = fmaf(g1, wa1.w, gz[3]);
        gz[4] = fmaf(g1, wb1.x, gz[4]); gz[5] = fmaf(g1, wb1.y, gz[5]);
        gz[6] = fmaf(g1, wb1.z, gz[6]); gz[7] = fmaf(g1, wb1.w, gz[7]);
    }
#pragma unroll
    for (int m = 1; m < 16; m <<= 1)
#pragma unroll
        for (int k = 0; k < DD; k++) gz[k] += __shfl_xor(gz[k], m);
    float out_l = gz[0];
#pragma unroll
    for (int k = 1; k < DD; k++) out_l = (d == k) ? gz[k] : out_l;
    if (!sub) gz1b[(size_t)v * DD + d] = __float2half(bv * out_l);
}

// ============================== launch =====================================

extern "C" void kernel_launch(void* const* d_in, const int* in_sizes, int n_in,
                              void* d_out, int out_size, void* d_ws, size_t ws_size,
                              hipStream_t stream) {
    const float* q    = (const float*)d_in[0];
    const float* p    = (const float*)d_in[1];
    const float* M    = (const float*)d_in[2];
    const int*   src  = (const int*)d_in[3];
    const int*   dst  = (const int*)d_in[4];
    const float* W1   = (const float*)d_in[5];
    const float* b1   = (const float*)d_in[6];
    const float* W2   = (const float*)d_in[7];
    const float* b2   = (const float*)d_in[8];
    const float* grav = (const float*)d_in[9];
    float* out = (float*)d_out;

    int N = in_sizes[0] / DD;
    int E = in_sizes[3];
    size_t n = (size_t)N;
    int NB = (N + 511) >> 9;

    // ---- data region (46N 4-byte words) ----
    float*   ws   = (float*)d_ws;
    float*   a_   = ws;             // N
    float*   b_   = ws + n;         // N
    float*   qn   = ws + 2  * n;    // 8N f32 (reused as gq2 after k_agg_node)
    float*   agg1 = ws + 10 * n;    // 8N f32 (live through bwd)
    float*   gh   = ws + 18 * n;    // 8N f32
    __half2* hm   = (__half2*)(ws + 26 * n);  // 8N half2 (8N words)
    __half*  ya   = (__half*)(ws + 34 * n);   // 8N half (4N words)
    __half*  bgh  = (__half*)(ws + 38 * n);   // 8N half (4N words)
    __half*  gz1b = (__half*)(ws + 42 * n);   // 8N half (4N words)
    float*   gq2  = qn;

    // ---- int region ----
    int* iw        = (int*)(ws + 46 * n);
    int* csr_in    = iw;                       // E
    int* csr_out   = iw + (size_t)E;           // E
    int* start_in  = iw + 2 * (size_t)E;       // N+1
    int* start_out = start_in + n + 1;         // N+1
    int* gHistIn   = start_out + n + 1;        // 256
    int* gHistOut  = gHistIn + 256;            // 256
    int* cStartIn  = gHistOut + 256;           // NB+1
    int* cStartOut = cStartIn + NB + 1;        // NB+1
    int* cCurIn    = cStartOut + NB + 1;       // NB
    int* cCurOut   = cCurIn + NB;              // NB
    int* iwEnd     = cCurOut + NB;
    float* W12p    = (float*)iwEnd;            // HH*WPITCH = 5120 floats
    int* intAfter  = (int*)(W12p + HH * WPITCH);
    // partition scratch: both dirs alias the data region (dead during build)
    int* P_in  = (E <= 16 * (long long)n) ? (int*)ws            : intAfter;
    int* P_out = (E <= 16 * (long long)n) ? (int*)(ws + 16 * n) : intAfter + E;

    hipMemsetAsync(gHistIn, 0, 512 * sizeof(int), stream);

    const int tb = 256;
    int gbN  = (N + tb - 1) / tb;
    int gb1  = (N + 63) / 64;                  // 1 thread/node, block 64
    int gb2  = (2 * N + 63) / 64;              // 2 threads/node, block 64
    int gb16 = (int)((16 * n + tb - 1) / tb);  // 16 lanes/node, block 256
    int gbC  = (E + CH - 1) / CH;

    // CSR build
    k_coarse  <<<gbC, tb, 0, stream>>>(src, dst, gHistIn, gHistOut, NB, E);
    k_cscan   <<<1, 256, 0, stream>>>(gHistIn, gHistOut, cStartIn, cStartOut,
                                      cCurIn, cCurOut, NB, E);
    k_part2   <<<dim3(gbC, 2), tb, 0, stream>>>(src, dst, cCurIn, cCurOut,
                                                P_in, P_out, NB, E);
    k_fine2   <<<dim3(NB, 2), 512, 0, stream>>>(cStartIn, cStartOut, P_in, P_out,
                                                start_in, start_out, csr_in, csr_out, N);
    k_prep    <<<gbN, tb, 0, stream>>>(q, p, M, W1, W2, W12p, start_in, start_out,
                                       a_, b_, hm, qn, out, N, E);

    // forward: agg1 = AggIn(a⊙q); ya = a⊙(relu((b⊙agg1)@W1+b1)@W2)
    k_agg_node<<<gb1, 64, 0, stream>>>(start_in, csr_in, qn, agg1, N);
    k_mlp_fwd <<<gb16, tb, 0, stream>>>(agg1, a_, b_, W12p, b1, ya, N);
    // h = b ⊙ AggIn(ya) + b2 + q  -> .x halves of hm
    k_h_node  <<<gb1, 64, 0, stream>>>(start_in, csr_in, ya, b_, q, b2, hm, N);
    // gravity gradient (2 threads/node, full records in-thread)
    k_gh2     <<<gb2, 64, 0, stream>>>(start_in, csr_in, start_out, csr_out,
                                       hm, b_, grav, gh, bgh, N);
    // gq2 = AggOut(bgh); gz1b = b⊙((a⊙(gq2@W2^T)⊙relu')@W1^T)
    k_bgh_node<<<gb1, 64, 0, stream>>>(start_out, csr_out, bgh, gq2, N);
    k_mlp_bwd <<<gb16, tb, 0, stream>>>(gq2, agg1, a_, b_, W12p, b1, gz1b, N);
    // dHdQ = gh + a ⊙ AggOut(gz1b)
    k_out_node<<<gb1, 64, 0, stream>>>(start_out, csr_out, gz1b, gh, a_, out, N);
}

// Round 12
// 343.569 us; speedup vs baseline: 1.5084x; 1.0189x over previous
//
#include <hip/hip_runtime.h>
#include <hip/hip_fp16.h>

#define DD 8
#define HH 256
#define CH 8192          // edges per chunk in coarse/partition kernels
#define PAYBITS 17       // N <= 131072
#define PAYMASK 0x1FFFF
#define WPITCH 20        // LDS weight row pitch (floats): conflict-free

// ============================ CSR construction ==============================

__global__ void k_coarse(const int* __restrict__ src, const int* __restrict__ dst,
                         int* __restrict__ gHistIn, int* __restrict__ gHistOut,
                         int NB, int E) {
    __shared__ int hIn[256], hOut[256];
    if (threadIdx.x < 256) { hIn[threadIdx.x] = 0; hOut[threadIdx.x] = 0; }
    __syncthreads();
    int lo = blockIdx.x * CH;
    int hi = min(lo + CH, E);
    for (int i = lo + threadIdx.x; i < hi; i += blockDim.x) {
        atomicAdd(&hIn[dst[i] >> 9], 1);
        atomicAdd(&hOut[src[i] >> 9], 1);
    }
    __syncthreads();
    if (threadIdx.x < NB) {
        int ci = hIn[threadIdx.x], co = hOut[threadIdx.x];
        if (ci) atomicAdd(&gHistIn[threadIdx.x], ci);
        if (co) atomicAdd(&gHistOut[threadIdx.x], co);
    }
}

__global__ void k_cscan(const int* __restrict__ gHistIn, const int* __restrict__ gHistOut,
                        int* __restrict__ cStartIn, int* __restrict__ cStartOut,
                        int* __restrict__ cCurIn, int* __restrict__ cCurOut,
                        int NB, int E) {
    __shared__ int s[256];
#pragma unroll
    for (int dir = 0; dir < 2; dir++) {
        const int* gh = dir ? gHistOut : gHistIn;
        int* cs = dir ? cStartOut : cStartIn;
        int* cc = dir ? cCurOut : cCurIn;
        int v = (threadIdx.x < NB) ? gh[threadIdx.x] : 0;
        s[threadIdx.x] = v;
        __syncthreads();
        for (int off = 1; off < 256; off <<= 1) {
            int t = (threadIdx.x >= off) ? s[threadIdx.x - off] : 0;
            __syncthreads();
            s[threadIdx.x] += t;
            __syncthreads();
        }
        if (threadIdx.x < NB) {
            int ex = s[threadIdx.x] - v;
            cs[threadIdx.x] = ex;
            cc[threadIdx.x] = ex;
        }
        if (threadIdx.x == 0) cs[NB] = E;
        __syncthreads();
    }
}

__global__ void k_part2(const int* __restrict__ src, const int* __restrict__ dst,
                        int* __restrict__ cCurIn, int* __restrict__ cCurOut,
                        int* __restrict__ P_in, int* __restrict__ P_out,
                        int NB, int E) {
    int dir = blockIdx.y;
    const int* key = dir ? src : dst;
    const int* pay = dir ? dst : src;
    int* cCur = dir ? cCurOut : cCurIn;
    int* P    = dir ? P_out   : P_in;
    __shared__ int h[256];
    if (threadIdx.x < 256) h[threadIdx.x] = 0;
    __syncthreads();
    int lo = blockIdx.x * CH;
    int hi = min(lo + CH, E);
    for (int i = lo + threadIdx.x; i < hi; i += blockDim.x)
        atomicAdd(&h[key[i] >> 9], 1);
    __syncthreads();
    if (threadIdx.x < NB) {
        int c = h[threadIdx.x];
        h[threadIdx.x] = c ? atomicAdd(&cCur[threadIdx.x], c) : 0;
    }
    __syncthreads();
    for (int i = lo + threadIdx.x; i < hi; i += blockDim.x) {
        int k = key[i];
        int pos = atomicAdd(&h[k >> 9], 1);
        P[pos] = ((k & 511) << PAYBITS) | pay[i];
    }
}

__launch_bounds__(512)
__global__ void k_fine2(const int* __restrict__ cStartIn, const int* __restrict__ cStartOut,
                        const int* __restrict__ P_in, const int* __restrict__ P_out,
                        int* __restrict__ start_in, int* __restrict__ start_out,
                        int* __restrict__ csr_in, int* __restrict__ csr_out, int N) {
    int dir = blockIdx.y;
    const int* cStart = dir ? cStartOut : cStartIn;
    const int* P      = dir ? P_out     : P_in;
    int* start        = dir ? start_out : start_in;
    int* csr          = dir ? csr_out   : csr_in;
    __shared__ int cnt[512], scn[512];
    int b = blockIdx.x;
    int lo = cStart[b], hi = cStart[b + 1];
    cnt[threadIdx.x] = 0;
    __syncthreads();
    for (int i = lo + threadIdx.x; i < hi; i += 512)
        atomicAdd(&cnt[P[i] >> PAYBITS], 1);
    __syncthreads();
    int own = cnt[threadIdx.x];
    scn[threadIdx.x] = own;
    __syncthreads();
    for (int off = 1; off < 512; off <<= 1) {
        int t = (threadIdx.x >= off) ? scn[threadIdx.x - off] : 0;
        __syncthreads();
        scn[threadIdx.x] += t;
        __syncthreads();
    }
    int base = lo + scn[threadIdx.x] - own;
    int node = (b << 9) + threadIdx.x;
    if (node < N) start[node] = base;
    cnt[threadIdx.x] = base;   // reuse as cursor
    __syncthreads();
    for (int i = lo + threadIdx.x; i < hi; i += 512) {
        int p = P[i];
        int pos = atomicAdd(&cnt[p >> PAYBITS], 1);
        csr[pos] = p & PAYMASK;
    }
}

// ========== per-node prep (norms, masses, dHdP) + weight pack ===============
// hm[v*8+d] = __half2{h (filled later by k_h_node), m}
__global__ void k_prep(const float* __restrict__ q, const float* __restrict__ p,
                       const float* __restrict__ M,
                       const float* __restrict__ W1, const float* __restrict__ W2,
                       float* __restrict__ W12p,
                       int* __restrict__ start_in, int* __restrict__ start_out,
                       float* __restrict__ a, float* __restrict__ b,
                       __half2* __restrict__ hm, float* __restrict__ qn,
                       float* __restrict__ out, int N, int E) {
    int t = blockIdx.x * blockDim.x + threadIdx.x;
    if (t == 0) { start_in[N] = E; start_out[N] = E; }
    if (t < HH * DD) {                      // weight pack
        int j = t >> 3, dd = t & 7;
        W12p[j * WPITCH + dd]     = W1[dd * HH + j];
        W12p[j * WPITCH + 8 + dd] = W2[j * DD + dd];
    }
    int v = t;
    if (v >= N) return;
    int ei1 = (v + 1 < N) ? start_in[v + 1]  : E;
    int eo1 = (v + 1 < N) ? start_out[v + 1] : E;
    float din  = (float)(ei1 - start_in[v]);
    float dout = (float)(eo1 - start_out[v]);
    float av = 1.0f / sqrtf(dout > 0.f ? dout : 1.f);   // norm_src
    float bv = 1.0f / sqrtf(din  > 0.f ? din  : 1.f);   // norm_dst
    a[v] = av; b[v] = bv;
#pragma unroll
    for (int d = 0; d < DD; d++) {
        float m = M[(size_t)v * DD * DD + d * (DD + 1)];
        __half2 hmv;
        hmv.x = __float2half(0.f);
        hmv.y = __float2half(m);
        hm[(size_t)v * DD + d] = hmv;
        qn[(size_t)v * DD + d] = av * q[(size_t)v * DD + d];
        out[(size_t)v * 2 * DD + DD + d] = p[(size_t)v * DD + d] / m;  // dHdP
    }
}

// ------------------- record unpack/accumulate helpers -----------------------
static __device__ __forceinline__
void acc_h8(uint4 r, float acc[8]) {
    float2 f;
    f = __half22float2(*(__half2*)&r.x); acc[0] += f.x; acc[1] += f.y;
    f = __half22float2(*(__half2*)&r.y); acc[2] += f.x; acc[3] += f.y;
    f = __half22float2(*(__half2*)&r.z); acc[4] += f.x; acc[5] += f.y;
    f = __half22float2(*(__half2*)&r.w); acc[6] += f.x; acc[7] += f.y;
}

static __device__ __forceinline__
void unpack_hm(uint4 r0, uint4 r1, float h[8], float m[8]) {
    float2 f;
    f = __half22float2(*(__half2*)&r0.x); h[0] = f.x; m[0] = f.y;
    f = __half22float2(*(__half2*)&r0.y); h[1] = f.x; m[1] = f.y;
    f = __half22float2(*(__half2*)&r0.z); h[2] = f.x; m[2] = f.y;
    f = __half22float2(*(__half2*)&r0.w); h[3] = f.x; m[3] = f.y;
    f = __half22float2(*(__half2*)&r1.x); h[4] = f.x; m[4] = f.y;
    f = __half22float2(*(__half2*)&r1.y); h[5] = f.x; m[5] = f.y;
    f = __half22float2(*(__half2*)&r1.z); h[6] = f.x; m[6] = f.y;
    f = __half22float2(*(__half2*)&r1.w); h[7] = f.x; m[7] = f.y;
}

// gather full half8 records over csr range into acc[8]
static __device__ __forceinline__
void gather_h8(const int* __restrict__ csr, const __half* __restrict__ x,
               int e, int e1, float acc[8]) {
    for (; e + 3 < e1; e += 4) {
        int u0 = csr[e], u1 = csr[e + 1], u2 = csr[e + 2], u3 = csr[e + 3];
        uint4 r0 = *(const uint4*)(x + (size_t)u0 * DD);
        uint4 r1 = *(const uint4*)(x + (size_t)u1 * DD);
        uint4 r2 = *(const uint4*)(x + (size_t)u2 * DD);
        uint4 r3 = *(const uint4*)(x + (size_t)u3 * DD);
        acc_h8(r0, acc); acc_h8(r1, acc); acc_h8(r2, acc); acc_h8(r3, acc);
    }
    for (; e < e1; e++) {
        uint4 r = *(const uint4*)(x + (size_t)csr[e] * DD);
        acc_h8(r, acc);
    }
}

// ============ sweep kernels: in-thread records, 2 threads/node ==============

// agg1[v] = sum of qn records (f32, 32B each); 2 thr/node split the range
__launch_bounds__(256)
__global__ void k_agg_node(const int* __restrict__ start, const int* __restrict__ csr,
                           const float* __restrict__ x, float* __restrict__ y, int N) {
    int t = blockIdx.x * 256 + threadIdx.x;
    int v = t >> 1, half = t & 1;
    if (v >= N) return;
    int e0 = start[v], e1 = start[v + 1];
    int mid = e0 + ((e1 - e0) >> 1);
    int e = half ? mid : e0, hi = half ? e1 : mid;
    float acc[8] = {0.f, 0.f, 0.f, 0.f, 0.f, 0.f, 0.f, 0.f};
    for (; e + 1 < hi; e += 2) {
        int u0 = csr[e], u1 = csr[e + 1];
        const float4* p0 = (const float4*)(x + (size_t)u0 * DD);
        const float4* p1 = (const float4*)(x + (size_t)u1 * DD);
        float4 a0 = p0[0], b0 = p0[1], a1 = p1[0], b1 = p1[1];
        acc[0] += a0.x + a1.x; acc[1] += a0.y + a1.y;
        acc[2] += a0.z + a1.z; acc[3] += a0.w + a1.w;
        acc[4] += b0.x + b1.x; acc[5] += b0.y + b1.y;
        acc[6] += b0.z + b1.z; acc[7] += b0.w + b1.w;
    }
    if (e < hi) {
        const float4* p = (const float4*)(x + (size_t)csr[e] * DD);
        float4 a0 = p[0], b0 = p[1];
        acc[0] += a0.x; acc[1] += a0.y; acc[2] += a0.z; acc[3] += a0.w;
        acc[4] += b0.x; acc[5] += b0.y; acc[6] += b0.z; acc[7] += b0.w;
    }
#pragma unroll
    for (int k = 0; k < 8; k++) acc[k] += __shfl_xor(acc[k], 1);
    if (!half) {
        float4* yp = (float4*)(y + (size_t)v * DD);
        yp[0] = make_float4(acc[0], acc[1], acc[2], acc[3]);
        yp[1] = make_float4(acc[4], acc[5], acc[6], acc[7]);
    }
}

// h = b*AggIn(ya) + b2 + q  -> .x halves of hm records; 2 thr/node
__launch_bounds__(256)
__global__ void k_h_node(const int* __restrict__ start, const int* __restrict__ csr,
                         const __half* __restrict__ ya, const float* __restrict__ b,
                         const float* __restrict__ q, const float* __restrict__ b2,
                         __half2* __restrict__ hm, int N) {
    int t = blockIdx.x * 256 + threadIdx.x;
    int v = t >> 1, half = t & 1;
    if (v >= N) return;
    int e0 = start[v], e1 = start[v + 1];
    int mid = e0 + ((e1 - e0) >> 1);
    float acc[8] = {0.f, 0.f, 0.f, 0.f, 0.f, 0.f, 0.f, 0.f};
    gather_h8(csr, ya, half ? mid : e0, half ? e1 : mid, acc);
#pragma unroll
    for (int k = 0; k < 8; k++) acc[k] += __shfl_xor(acc[k], 1);
    if (!half) {
        float bv = b[v];
        const float4* qp = (const float4*)(q + (size_t)v * DD);
        float4 q0 = qp[0], q1 = qp[1];
        float hq[8] = {q0.x, q0.y, q0.z, q0.w, q1.x, q1.y, q1.z, q1.w};
        __half2* hp = hm + (size_t)v * DD;
#pragma unroll
        for (int k = 0; k < DD; k++) {
            float hval = fmaf(bv, acc[k], b2[k] + hq[k]);
            __half2 cur = hp[k];
            cur.x = __float2half(hval);
            hp[k] = cur;
        }
    }
}

// gravity gradient: 4 threads/node (dir x half-range), full records in-thread
__launch_bounds__(256)
__global__ void k_gh4(const int* __restrict__ start_in, const int* __restrict__ csr_in,
                      const int* __restrict__ start_out, const int* __restrict__ csr_out,
                      const __half2* __restrict__ hm,
                      const float* __restrict__ b, const float* __restrict__ grav,
                      float* __restrict__ gh, __half* __restrict__ bgh, int N) {
    int t = blockIdx.x * 256 + threadIdx.x;
    int v = t >> 2, sub = t & 3, dir = sub >> 1, half = sub & 1;
    if (v >= N) return;
    const uint4* srec = (const uint4*)(hm + (size_t)v * DD);
    uint4 s0 = srec[0], s1 = srec[1];
    float hv[8], mv[8];
    unpack_hm(s0, s1, hv, mv);
    const int* start = dir ? start_out : start_in;
    const int* csr   = dir ? csr_out   : csr_in;
    int e0 = start[v], e1 = start[v + 1];
    int mid = e0 + ((e1 - e0) >> 1);
    int e = half ? mid : e0, hi = half ? e1 : mid;
    float coef = -0.5f * grav[0];
    float acc[8] = {0.f, 0.f, 0.f, 0.f, 0.f, 0.f, 0.f, 0.f};
    for (; e + 1 < hi; e += 2) {
        int u0 = csr[e], u1 = csr[e + 1];
        const uint4* r0p = (const uint4*)(hm + (size_t)u0 * DD);
        const uint4* r1p = (const uint4*)(hm + (size_t)u1 * DD);
        uint4 x0 = r0p[0], x1 = r0p[1], y0 = r1p[0], y1 = r1p[1];
        float hu0[8], mu0[8], hu1[8], mu1[8];
        unpack_hm(x0, x1, hu0, mu0);
        unpack_hm(y0, y1, hu1, mu1);
        float d0[8], d1[8];
        float e20 = 0.f, S0 = 0.f, e21 = 0.f, S1 = 0.f;
#pragma unroll
        for (int k = 0; k < 8; k++) {
            d0[k] = hv[k] - hu0[k];
            d1[k] = hv[k] - hu1[k];
            e20 = fmaf(d0[k], d0[k], e20);
            e21 = fmaf(d1[k], d1[k], e21);
            S0 = fmaf(mv[k], mu0[k], S0);
            S1 = fmaf(mv[k], mu1[k], S1);
        }
        float r0 = rsqrtf(e20), r1 = rsqrtf(e21);
        float c0 = coef * S0 * r0 * r0 * r0;
        float c1 = coef * S1 * r1 * r1 * r1;
#pragma unroll
        for (int k = 0; k < 8; k++)
            acc[k] = fmaf(c0, d0[k], fmaf(c1, d1[k], acc[k]));
    }
    if (e < hi) {
        int u = csr[e];
        const uint4* rp = (const uint4*)(hm + (size_t)u * DD);
        uint4 x0 = rp[0], x1 = rp[1];
        float hu[8], mu[8];
        unpack_hm(x0, x1, hu, mu);
        float df[8];
        float e2 = 0.f, S = 0.f;
#pragma unroll
        for (int k = 0; k < 8; k++) {
            df[k] = hv[k] - hu[k];
            e2 = fmaf(df[k], df[k], e2);
            S = fmaf(mv[k], mu[k], S);
        }
        float r = rsqrtf(e2);
        float c = coef * S * r * r * r;
#pragma unroll
        for (int k = 0; k < 8; k++) acc[k] = fmaf(c, df[k], acc[k]);
    }
    // combine the 4 subset threads (adjacent lanes)
#pragma unroll
    for (int k = 0; k < 8; k++) acc[k] += __shfl_xor(acc[k], 1);
#pragma unroll
    for (int k = 0; k < 8; k++) acc[k] += __shfl_xor(acc[k], 2);
    if (sub == 0) {
        float4* gp = (float4*)(gh + (size_t)v * DD);
        gp[0] = make_float4(acc[0], acc[1], acc[2], acc[3]);
        gp[1] = make_float4(acc[4], acc[5], acc[6], acc[7]);
        float bv = b[v];
        __half2* bp = (__half2*)(bgh + (size_t)v * DD);
        bp[0] = __floats2half2_rn(bv * acc[0], bv * acc[1]);
        bp[1] = __floats2half2_rn(bv * acc[2], bv * acc[3]);
        bp[2] = __floats2half2_rn(bv * acc[4], bv * acc[5]);
        bp[3] = __floats2half2_rn(bv * acc[6], bv * acc[7]);
    }
}

// gq2[v] = AggOut(bgh); 2 thr/node
__launch_bounds__(256)
__global__ void k_bgh_node(const int* __restrict__ start, const int* __restrict__ csr,
                           const __half* __restrict__ bgh, float* __restrict__ gq2, int N) {
    int t = blockIdx.x * 256 + threadIdx.x;
    int v = t >> 1, half = t & 1;
    if (v >= N) return;
    int e0 = start[v], e1 = start[v + 1];
    int mid = e0 + ((e1 - e0) >> 1);
    float acc[8] = {0.f, 0.f, 0.f, 0.f, 0.f, 0.f, 0.f, 0.f};
    gather_h8(csr, bgh, half ? mid : e0, half ? e1 : mid, acc);
#pragma unroll
    for (int k = 0; k < 8; k++) acc[k] += __shfl_xor(acc[k], 1);
    if (!half) {
        float4* yp = (float4*)(gq2 + (size_t)v * DD);
        yp[0] = make_float4(acc[0], acc[1], acc[2], acc[3]);
        yp[1] = make_float4(acc[4], acc[5], acc[6], acc[7]);
    }
}

// out[:, :D] = gh + a * AggOut(gz1b); 2 thr/node
__launch_bounds__(256)
__global__ void k_out_node(const int* __restrict__ start, const int* __restrict__ csr,
                           const __half* __restrict__ gz1b, const float* __restrict__ gh,
                           const float* __restrict__ a, float* __restrict__ out, int N) {
    int t = blockIdx.x * 256 + threadIdx.x;
    int v = t >> 1, half = t & 1;
    if (v >= N) return;
    int e0 = start[v], e1 = start[v + 1];
    int mid = e0 + ((e1 - e0) >> 1);
    float acc[8] = {0.f, 0.f, 0.f, 0.f, 0.f, 0.f, 0.f, 0.f};
    gather_h8(csr, gz1b, half ? mid : e0, half ? e1 : mid, acc);
#pragma unroll
    for (int k = 0; k < 8; k++) acc[k] += __shfl_xor(acc[k], 1);
    if (!half) {
        float av = a[v];
        const float4* gp = (const float4*)(gh + (size_t)v * DD);
        float4 g0 = gp[0], g1 = gp[1];
        float4* op = (float4*)(out + (size_t)v * 2 * DD);
        op[0] = make_float4(fmaf(av, acc[0], g0.x), fmaf(av, acc[1], g0.y),
                            fmaf(av, acc[2], g0.z), fmaf(av, acc[3], g0.w));
        op[1] = make_float4(fmaf(av, acc[4], g1.x), fmaf(av, acc[5], g1.y),
                            fmaf(av, acc[6], g1.z), fmaf(av, acc[7], g1.w));
    }
}

// ================ MLP kernels: 16 lanes/node, LDS weights ===================

__launch_bounds__(256)
__global__ void k_mlp_fwd(const float* __restrict__ agg1, const float* __restrict__ a,
                          const float* __restrict__ b,
                          const float* __restrict__ W12p, const float* __restrict__ b1,
                          __half* __restrict__ ya, int N) {
    __shared__ float sW[HH * WPITCH];
    __shared__ float sb1[HH];
    for (int i = threadIdx.x; i < HH * WPITCH; i += 256) sW[i] = W12p[i];
    for (int i = threadIdx.x; i < HH; i += 256) sb1[i] = b1[i];
    __syncthreads();
    int t = blockIdx.x * 256 + threadIdx.x;
    int v = t >> 4, l16 = t & 15, sub = (t >> 3) & 1, d = t & 7;
    if (v >= N) return;
    float zl = b[v] * agg1[(size_t)v * DD + d];
    float z[DD];
#pragma unroll
    for (int k = 0; k < DD; k++) z[k] = __shfl(zl, k, 16);
    float acc[DD] = {0.f, 0.f, 0.f, 0.f, 0.f, 0.f, 0.f, 0.f};
    for (int c = 0; c < HH / 16; c += 2) {
        int j0 = (c << 4) | l16, j1 = j0 + 16;
        const float4* w0 = (const float4*)(sW + j0 * WPITCH);
        const float4* w1 = (const float4*)(sW + j1 * WPITCH);
        float4 wa0 = w0[0], wb0 = w0[1], va0 = w0[2], vb0 = w0[3];
        float4 wa1 = w1[0], wb1 = w1[1], va1 = w1[2], vb1 = w1[3];
        float ua0 = fmaf(z[1], wa0.y, fmaf(z[0], wa0.x, sb1[j0]));
        ua0 = fmaf(z[3], wa0.w, fmaf(z[2], wa0.z, ua0));
        float ub0 = fmaf(z[5], wb0.y, z[4] * wb0.x);
        ub0 = fmaf(z[7], wb0.w, fmaf(z[6], wb0.z, ub0));
        float ua1 = fmaf(z[1], wa1.y, fmaf(z[0], wa1.x, sb1[j1]));
        ua1 = fmaf(z[3], wa1.w, fmaf(z[2], wa1.z, ua1));
        float ub1 = fmaf(z[5], wb1.y, z[4] * wb1.x);
        ub1 = fmaf(z[7], wb1.w, fmaf(z[6], wb1.z, ub1));
        float h0 = fmaxf(ua0 + ub0, 0.f);
        float h1 = fmaxf(ua1 + ub1, 0.f);
        acc[0] = fmaf(h0, va0.x, acc[0]); acc[1] = fmaf(h0, va0.y, acc[1]);
        acc[2] = fmaf(h0, va0.z, acc[2]); acc[3] = fmaf(h0, va0.w, acc[3]);
        acc[4] = fmaf(h0, vb0.x, acc[4]); acc[5] = fmaf(h0, vb0.y, acc[5]);
        acc[6] = fmaf(h0, vb0.z, acc[6]); acc[7] = fmaf(h0, vb0.w, acc[7]);
        acc[0] = fmaf(h1, va1.x, acc[0]); acc[1] = fmaf(h1, va1.y, acc[1]);
        acc[2] = fmaf(h1, va1.z, acc[2]); acc[3] = fmaf(h1, va1.w, acc[3]);
        acc[4] = fmaf(h1, vb1.x, acc[4]); acc[5] = fmaf(h1, vb1.y, acc[5]);
        acc[6] = fmaf(h1, vb1.z, acc[6]); acc[7] = fmaf(h1, vb1.w, acc[7]);
    }
#pragma unroll
    for (int m = 1; m < 16; m <<= 1)
#pragma unroll
        for (int k = 0; k < DD; k++) acc[k] += __shfl_xor(acc[k], m);
    float yl = acc[0];
#pragma unroll
    for (int k = 1; k < DD; k++) yl = (d == k) ? acc[k] : yl;
    if (!sub) ya[(size_t)v * DD + d] = __float2half(a[v] * yl);
}

__launch_bounds__(256)
__global__ void k_mlp_bwd(const float* __restrict__ gq2, const float* __restrict__ agg1,
                          const float* __restrict__ a, const float* __restrict__ b,
                          const float* __restrict__ W12p, const float* __restrict__ b1,
                          __half* __restrict__ gz1b, int N) {
    __shared__ float sW[HH * WPITCH];
    __shared__ float sb1[HH];
    for (int i = threadIdx.x; i < HH * WPITCH; i += 256) sW[i] = W12p[i];
    for (int i = threadIdx.x; i < HH; i += 256) sb1[i] = b1[i];
    __syncthreads();
    int t = blockIdx.x * 256 + threadIdx.x;
    int v = t >> 4, l16 = t & 15, sub = (t >> 3) & 1, d = t & 7;
    if (v >= N) return;
    float bv = b[v], av = a[v];
    float zl = bv * agg1[(size_t)v * DD + d];
    float gl = gq2[(size_t)v * DD + d];
    float z[DD], gq[DD];
#pragma unroll
    for (int k = 0; k < DD; k++) { z[k] = __shfl(zl, k, 16); gq[k] = __shfl(gl, k, 16); }
    float gz[DD] = {0.f, 0.f, 0.f, 0.f, 0.f, 0.f, 0.f, 0.f};
    for (int c = 0; c < HH / 16; c += 2) {
        int j0 = (c << 4) | l16, j1 = j0 + 16;
        const float4* w0 = (const float4*)(sW + j0 * WPITCH);
        const float4* w1 = (const float4*)(sW + j1 * WPITCH);
        float4 wa0 = w0[0], wb0 = w0[1], va0 = w0[2], vb0 = w0[3];
        float4 wa1 = w1[0], wb1 = w1[1], va1 = w1[2], vb1 = w1[3];
        float ua0 = fmaf(z[1], wa0.y, fmaf(z[0], wa0.x, sb1[j0]));
        ua0 = fmaf(z[3], wa0.w, fmaf(z[2], wa0.z, ua0));
        float ub0 = fmaf(z[5], wb0.y, z[4] * wb0.x);
        ub0 = fmaf(z[7], wb0.w, fmaf(z[6], wb0.z, ub0));
        float ua1 = fmaf(z[1], wa1.y, fmaf(z[0], wa1.x, sb1[j1]));
        ua1 = fmaf(z[3], wa1.w, fmaf(z[2], wa1.z, ua1));
        float ub1 = fmaf(z[5], wb1.y, z[4] * wb1.x);
        ub1 = fmaf(z[7], wb1.w, fmaf(z[6], wb1.z, ub1));
        float u0 = ua0 + ub0, u1 = ua1 + ub1;
        float ga0 = fmaf(gq[1], va0.y, gq[0] * va0.x);
        ga0 = fmaf(gq[3], va0.w, fmaf(gq[2], va0.z, ga0));
        float gb0 = fmaf(gq[5], vb0.y, gq[4] * vb0.x);
        gb0 = fmaf(gq[7], vb0.w, fmaf(gq[6], vb0.z, gb0));
        float ga1 = fmaf(gq[1], va1.y, gq[0] * va1.x);
        ga1 = fmaf(gq[3], va1.w, fmaf(gq[2], va1.z, ga1));
        float gb1 = fmaf(gq[5], vb1.y, gq[4] * vb1.x);
        gb1 = fmaf(gq[7], vb1.w, fmaf(gq[6], vb1.z, gb1));
        float g0 = (u0 > 0.f) ? av * (ga0 + gb0) : 0.f;
        float g1 = (u1 > 0.f) ? av * (ga1 + gb1) : 0.f;
        gz[0] = fmaf(g0, wa0.x, gz[0]); gz[1] = fmaf(g0, wa0.y, gz[1]);
        gz[2] = fmaf(g0, wa0.z, gz[2]); gz[3] = fmaf(g0, wa0.w, gz[3]);
        gz[4] = fmaf(g0, wb0.x, gz[4]); gz[5] = fmaf(g0, wb0.y, gz[5]);
        gz[6] = fmaf(g0, wb0.z, gz[6]); gz[7] = fmaf(g0, wb0.w, gz[7]);
        gz[0] = fmaf(g1, wa1.x, gz[0]); gz[1] = fmaf(g1, wa1.y, gz[1]);
        gz[2] = fmaf(g1, wa1.z, gz[2]); gz[3] = fmaf(g1, wa1.w, gz[3]);
        gz[4] = fmaf(g1, wb1.x, gz[4]); gz[5] = fmaf(g1, wb1.y, gz[5]);
        gz[6] = fmaf(g1, wb1.z, gz[6]); gz[7] = fmaf(g1, wb1.w, gz[7]);
    }
#pragma unroll
    for (int m = 1; m < 16; m <<= 1)
#pragma unroll
        for (int k = 0; k < DD; k++) gz[k] += __shfl_xor(gz[k], m);
    float out_l = gz[0];
#pragma unroll
    for (int k = 1; k < DD; k++) out_l = (d == k) ? gz[k] : out_l;
    if (!sub) gz1b[(size_t)v * DD + d] = __float2half(bv * out_l);
}

// ============================== launch =====================================

extern "C" void kernel_launch(void* const* d_in, const int* in_sizes, int n_in,
                              void* d_out, int out_size, void* d_ws, size_t ws_size,
                              hipStream_t stream) {
    const float* q    = (const float*)d_in[0];
    const float* p    = (const float*)d_in[1];
    const float* M    = (const float*)d_in[2];
    const int*   src  = (const int*)d_in[3];
    const int*   dst  = (const int*)d_in[4];
    const float* W1   = (const float*)d_in[5];
    const float* b1   = (const float*)d_in[6];
    const float* W2   = (const float*)d_in[7];
    const float* b2   = (const float*)d_in[8];
    const float* grav = (const float*)d_in[9];
    float* out = (float*)d_out;

    int N = in_sizes[0] / DD;
    int E = in_sizes[3];
    size_t n = (size_t)N;
    int NB = (N + 511) >> 9;

    // ---- data region (46N 4-byte words) ----
    float*   ws   = (float*)d_ws;
    float*   a_   = ws;             // N
    float*   b_   = ws + n;         // N
    float*   qn   = ws + 2  * n;    // 8N f32 (reused as gq2 after k_agg_node)
    float*   agg1 = ws + 10 * n;    // 8N f32 (live through bwd)
    float*   gh   = ws + 18 * n;    // 8N f32
    __half2* hm   = (__half2*)(ws + 26 * n);  // 8N half2 (8N words)
    __half*  ya   = (__half*)(ws + 34 * n);   // 8N half (4N words)
    __half*  bgh  = (__half*)(ws + 38 * n);   // 8N half (4N words)
    __half*  gz1b = (__half*)(ws + 42 * n);   // 8N half (4N words)
    float*   gq2  = qn;

    // ---- int region ----
    int* iw        = (int*)(ws + 46 * n);
    int* csr_in    = iw;                       // E
    int* csr_out   = iw + (size_t)E;           // E
    int* start_in  = iw + 2 * (size_t)E;       // N+1
    int* start_out = start_in + n + 1;         // N+1
    int* gHistIn   = start_out + n + 1;        // 256
    int* gHistOut  = gHistIn + 256;            // 256
    int* cStartIn  = gHistOut + 256;           // NB+1
    int* cStartOut = cStartIn + NB + 1;        // NB+1
    int* cCurIn    = cStartOut + NB + 1;       // NB
    int* cCurOut   = cCurIn + NB;              // NB
    int* iwEnd     = cCurOut + NB;
    float* W12p    = (float*)iwEnd;            // HH*WPITCH = 5120 floats
    int* intAfter  = (int*)(W12p + HH * WPITCH);
    // partition scratch: both dirs alias the data region (dead during build)
    int* P_in  = (E <= 16 * (long long)n) ? (int*)ws            : intAfter;
    int* P_out = (E <= 16 * (long long)n) ? (int*)(ws + 16 * n) : intAfter + E;

    hipMemsetAsync(gHistIn, 0, 512 * sizeof(int), stream);

    const int tb = 256;
    int gbN  = (N + tb - 1) / tb;
    int gb2  = (2 * N + tb - 1) / tb;          // 2 threads/node
    int gb4  = (4 * N + tb - 1) / tb;          // 4 threads/node
    int gb16 = (int)((16 * n + tb - 1) / tb);  // 16 lanes/node
    int gbC  = (E + CH - 1) / CH;

    // CSR build
    k_coarse  <<<gbC, tb, 0, stream>>>(src, dst, gHistIn, gHistOut, NB, E);
    k_cscan   <<<1, 256, 0, stream>>>(gHistIn, gHistOut, cStartIn, cStartOut,
                                      cCurIn, cCurOut, NB, E);
    k_part2   <<<dim3(gbC, 2), tb, 0, stream>>>(src, dst, cCurIn, cCurOut,
                                                P_in, P_out, NB, E);
    k_fine2   <<<dim3(NB, 2), 512, 0, stream>>>(cStartIn, cStartOut, P_in, P_out,
                                                start_in, start_out, csr_in, csr_out, N);
    k_prep    <<<gbN, tb, 0, stream>>>(q, p, M, W1, W2, W12p, start_in, start_out,
                                       a_, b_, hm, qn, out, N, E);

    // forward: agg1 = AggIn(a⊙q); ya = a⊙(relu((b⊙agg1)@W1+b1)@W2)
    k_agg_node<<<gb2, tb, 0, stream>>>(start_in, csr_in, qn, agg1, N);
    k_mlp_fwd <<<gb16, tb, 0, stream>>>(agg1, a_, b_, W12p, b1, ya, N);
    // h = b ⊙ AggIn(ya) + b2 + q  -> .x halves of hm
    k_h_node  <<<gb2, tb, 0, stream>>>(start_in, csr_in, ya, b_, q, b2, hm, N);
    // gravity gradient (4 threads/node, full records in-thread)
    k_gh4     <<<gb4, tb, 0, stream>>>(start_in, csr_in, start_out, csr_out,
                                       hm, b_, grav, gh, bgh, N);
    // gq2 = AggOut(bgh); gz1b = b⊙((a⊙(gq2@W2^T)⊙relu')@W1^T)
    k_bgh_node<<<gb2, tb, 0, stream>>>(start_out, csr_out, bgh, gq2, N);
    k_mlp_bwd <<<gb16, tb, 0, stream>>>(gq2, agg1, a_, b_, W12p, b1, gz1b, N);
    // dHdQ = gh + a ⊙ AggOut(gz1b)
    k_out_node<<<gb2, tb, 0, stream>>>(start_out, csr_out, gz1b, gh, a_, out, N);
}